// Round 9
// baseline (621.981 us; speedup 1.0000x reference)
//
#include <hip/hip_runtime.h>

// RWKV6Attention forward — round 9: kD1 v5 (54.25KB LDS + VGPR<=85 -> 3 blocks/CU,
// qeT dropped via qeG re-read, inline diag, gload_lds staging), kB/kBg split,
// kA2m5 grid reorder for L2 reuse.

#define DEVI __device__ __forceinline__

namespace {

typedef unsigned short u16;
typedef unsigned int u32;
typedef __attribute__((ext_vector_type(8))) short short8;   // 8 bf16 (4 VGPRs)
typedef __attribute__((ext_vector_type(4))) float f32x4;

typedef __attribute__((address_space(1))) const u32 gu32;
typedef __attribute__((address_space(3))) u32 lu32;

constexpr int Lc = 2048;
constexpr int Tc = 4096;   // B*L

// ---- workspace layout (byte offsets), lifetime-safe aliasing (same as R8).
constexpr size_t OFF_WKV   = 0;
constexpr size_t OFF_XM0   = 0;
constexpr size_t OFF_DELTA = 16777216;
constexpr size_t OFF_T160  = 33554432;
constexpr size_t OFF_XMW   = 36175872;
constexpr size_t OFF_YW    = 52953088;
constexpr size_t OFF_X0WHI = 54001664;
constexpr size_t OFF_X0WLO = 54329344;
constexpr size_t OFF_XMHI  = 67108864;
constexpr size_t OFF_XM0HI = 67108864;
constexpr size_t OFF_XM0LO = 75497472;
constexpr size_t OFF_WFIN  = 67108864;
constexpr size_t OFF_GATE  = 75497472;
constexpr size_t OFF_XMLO  = 100663296;
constexpr size_t OFF_QE    = 100663296;
constexpr size_t OFF_OO    = 109051904;
constexpr size_t OFF_WHI   = 125829120;
constexpr size_t OFF_WLO   = 132120576;
constexpr size_t OFF_DECAY = 132120576;
constexpr size_t OFF_OWB   = 136314880;
constexpr size_t OFF_RG    = 138412032;
constexpr size_t OFF_KG    = 146800640;
constexpr size_t OFF_VG    = 155189248;
constexpr size_t OFF_GG    = 171966464;
constexpr size_t WS_NEED   = 180355072;

DEVI float4 ld4(const float* p) { return *reinterpret_cast<const float4*>(p); }
DEVI void   st4(float* p, float4 v) { *reinterpret_cast<float4*>(p) = v; }
DEVI float2 ld2(const float* p) { return *reinterpret_cast<const float2*>(p); }
DEVI void   st2(float* p, float2 v) { *reinterpret_cast<float2*>(p) = v; }
DEVI u16 f2bf(float f) {
  u32 u = __float_as_uint(f);
  return (u16)((u + 0x7FFFu + ((u >> 16) & 1u)) >> 16);
}
DEVI float bf2f(u16 u) { return __uint_as_float((u32)u << 16); }

// ---- BK=64 swizzled staging helpers (kA2f, kB, kBg, kF)
DEVI void stage_swz(const u16* __restrict__ src, u16* __restrict__ dstBase,
                    int srow8, int k0, int lane) {
  const int rr = srow8 + (lane >> 3);
  const int ss = (lane & 7) ^ ((lane >> 3) & 7);
  __builtin_amdgcn_global_load_lds(
      (gu32*)(const void*)(src + (size_t)rr * 1024 + k0 + ss * 8),
      (lu32*)(void*)(dstBase + srow8 * 64), 16, 0, 0);
}
DEVI short8 read_swz(const u16* __restrict__ buf, int row, int slot_lin) {
  return *reinterpret_cast<const short8*>(buf + row * 64 + ((slot_lin ^ (row & 7)) * 8));
}

// ---------------------------------------------------------------- kernel W
__global__ void kW(const float* __restrict__ r_w, const float* __restrict__ k_w,
                   const float* __restrict__ v_w, const float* __restrict__ g_w,
                   const float* __restrict__ o_w, const float* __restrict__ x0_w,
                   u16* __restrict__ Whi, u16* __restrict__ Wlo,
                   u16* __restrict__ owb, u16* __restrict__ x0whi,
                   u16* __restrict__ x0wlo) {
  const size_t i = ((size_t)blockIdx.x * 256 + threadIdx.x) * 4;
  if (i < 3145728) {
    const float* src = (i < 524288)  ? r_w + i
                     : (i < 1048576) ? k_w + (i - 524288)
                     : (i < 2097152) ? v_w + (i - 1048576)
                                     : g_w + (i - 2097152);
    float4 v = ld4(src);
    ushort4 h;
    h.x = f2bf(v.x); h.y = f2bf(v.y); h.z = f2bf(v.z); h.w = f2bf(v.w);
    *reinterpret_cast<ushort4*>(Whi + i) = h;
    if (i < 2097152) {
      ushort4 l;
      l.x = f2bf(v.x - bf2f(h.x)); l.y = f2bf(v.y - bf2f(h.y));
      l.z = f2bf(v.z - bf2f(h.z)); l.w = f2bf(v.w - bf2f(h.w));
      *reinterpret_cast<ushort4*>(Wlo + i) = l;
    }
  } else if (i < 4194304) {
    float4 v = ld4(o_w + (i - 3145728));
    ushort4 h;
    h.x = f2bf(v.x); h.y = f2bf(v.y); h.z = f2bf(v.z); h.w = f2bf(v.w);
    *reinterpret_cast<ushort4*>(owb + (i - 3145728)) = h;
  } else {
    const size_t j = i - 4194304;
    float4 v = ld4(x0_w + j);
    ushort4 h, l;
    h.x = f2bf(v.x); h.y = f2bf(v.y); h.z = f2bf(v.z); h.w = f2bf(v.w);
    l.x = f2bf(v.x - bf2f(h.x)); l.y = f2bf(v.y - bf2f(h.y));
    l.z = f2bf(v.z - bf2f(h.z)); l.w = f2bf(v.w - bf2f(h.w));
    *reinterpret_cast<ushort4*>(x0whi + j) = h;
    *reinterpret_cast<ushort4*>(x0wlo + j) = l;
  }
}

// ---------------------------------------------------------------- kernel A1
__global__ void kA1(const float* __restrict__ x, const float* __restrict__ x0_mu,
                    float* __restrict__ xm0, float* __restrict__ delta,
                    u16* __restrict__ xm0hi, u16* __restrict__ xm0lo) {
  const size_t i4 = (size_t)blockIdx.x * 256 + threadIdx.x;
  const int t = (int)(i4 >> 8);
  const int h4 = (int)(i4 & 255) * 4;
  float4 xv = ld4(x + (size_t)t * 1024 + h4);
  float4 xp = make_float4(0.f, 0.f, 0.f, 0.f);
  if (t & (Lc - 1)) xp = ld4(x + (size_t)(t - 1) * 1024 + h4);
  float4 mu = ld4(x0_mu + h4);
  float4 d;
  d.x = xp.x - xv.x; d.y = xp.y - xv.y; d.z = xp.z - xv.z; d.w = xp.w - xv.w;
  st4(delta + (size_t)t * 1024 + h4, d);
  float4 m0;
  m0.x = xv.x + d.x * mu.x; m0.y = xv.y + d.y * mu.y;
  m0.z = xv.z + d.z * mu.z; m0.w = xv.w + d.w * mu.w;
  st4(xm0 + (size_t)t * 1024 + h4, m0);
  ushort4 h, l;
  h.x = f2bf(m0.x); h.y = f2bf(m0.y); h.z = f2bf(m0.z); h.w = f2bf(m0.w);
  l.x = f2bf(m0.x - bf2f(h.x)); l.y = f2bf(m0.y - bf2f(h.y));
  l.z = f2bf(m0.z - bf2f(h.z)); l.w = f2bf(m0.w - bf2f(h.w));
  *reinterpret_cast<ushort4*>(xm0hi + (size_t)t * 1024 + h4) = h;
  *reinterpret_cast<ushort4*>(xm0lo + (size_t)t * 1024 + h4) = l;
}

// ---------------------------------------------------------------- kernel A2f
__global__ __launch_bounds__(256) void kA2f(
    const u16* __restrict__ xm0hi, const u16* __restrict__ xm0lo,
    const u16* __restrict__ x0whi, const u16* __restrict__ x0wlo,
    float* __restrict__ t160) {
  __shared__ __align__(16) u16 sAh[128 * 64];
  __shared__ __align__(16) u16 sAl[128 * 64];
  __shared__ __align__(16) u16 sBh[128 * 64];
  __shared__ __align__(16) u16 sBl[128 * 64];
  const int mt = blockIdx.x, nt = blockIdx.y;
  const int ncols = nt ? 32 : 128;
  const int wcol0 = nt * 128;
  const u16* Ah = xm0hi + (size_t)mt * 128 * 1024;
  const u16* Al = xm0lo + (size_t)mt * 128 * 1024;
  const u16* Bh = x0whi + (size_t)wcol0 * 1024;
  const u16* Bl = x0wlo + (size_t)wcol0 * 1024;
  const int tid = threadIdx.x;
  const int lane = tid & 63;
  const int wv = tid >> 6;
  const int wr = wv >> 1, wc = wv & 1;
  const int srow = wv * 32;
  f32x4 acc[4][4];
  #pragma unroll
  for (int i = 0; i < 4; ++i)
    #pragma unroll
    for (int j = 0; j < 4; ++j) acc[i][j] = {0.f, 0.f, 0.f, 0.f};

  for (int k0 = 0; k0 < 1024; k0 += 64) {
    #pragma unroll
    for (int c = 0; c < 4; ++c) {
      const int s8 = srow + c * 8;
      stage_swz(Ah, sAh, s8, k0, lane);
      stage_swz(Al, sAl, s8, k0, lane);
      {
        const int rr = (s8 + (lane >> 3)) & (ncols - 1);
        const int ss = (lane & 7) ^ ((lane >> 3) & 7);
        __builtin_amdgcn_global_load_lds(
            (gu32*)(const void*)(Bh + (size_t)rr * 1024 + k0 + ss * 8),
            (lu32*)(void*)(sBh + s8 * 64), 16, 0, 0);
        __builtin_amdgcn_global_load_lds(
            (gu32*)(const void*)(Bl + (size_t)rr * 1024 + k0 + ss * 8),
            (lu32*)(void*)(sBl + s8 * 64), 16, 0, 0);
      }
    }
    __syncthreads();
    #pragma unroll
    for (int kk = 0; kk < 2; ++kk) {
      const int sl = kk * 4 + (lane >> 4);
      short8 ah[4], al[4], bh[4], bl[4];
      #pragma unroll
      for (int m = 0; m < 4; ++m) {
        int row = wr * 64 + m * 16 + (lane & 15);
        ah[m] = read_swz(sAh, row, sl);
        al[m] = read_swz(sAl, row, sl);
      }
      #pragma unroll
      for (int j = 0; j < 4; ++j) {
        int row = wc * 64 + j * 16 + (lane & 15);
        bh[j] = read_swz(sBh, row, sl);
        bl[j] = read_swz(sBl, row, sl);
      }
      #pragma unroll
      for (int m = 0; m < 4; ++m)
        #pragma unroll
        for (int j = 0; j < 4; ++j) {
          acc[m][j] = __builtin_amdgcn_mfma_f32_16x16x32_bf16(ah[m], bh[j], acc[m][j], 0, 0, 0);
          acc[m][j] = __builtin_amdgcn_mfma_f32_16x16x32_bf16(al[m], bh[j], acc[m][j], 0, 0, 0);
          acc[m][j] = __builtin_amdgcn_mfma_f32_16x16x32_bf16(ah[m], bl[j], acc[m][j], 0, 0, 0);
        }
    }
    __syncthreads();
  }
  #pragma unroll
  for (int m = 0; m < 4; ++m)
    #pragma unroll
    for (int r = 0; r < 4; ++r) {
      const int row = wr * 64 + m * 16 + (lane >> 4) * 4 + r;
      #pragma unroll
      for (int j = 0; j < 4; ++j) {
        const int col = wc * 64 + j * 16 + (lane & 15);
        if (col < ncols)
          t160[(size_t)(mt * 128 + row) * 160 + wcol0 + col] = tanhf(acc[m][j][r]);
      }
    }
}

// ---------------------------------------------------------------- kernel A2m5
// grid (5, 64, 16): n fastest so the 5 planes of one (m,h) tile run adjacently.
__global__ __launch_bounds__(256) void kA2m5(
    const float* __restrict__ t160G, const float* __restrict__ x2_w,
    const float* __restrict__ x_bias, const float* __restrict__ xm0,
    const float* __restrict__ delta, const float* __restrict__ x0_mu,
    u16* __restrict__ xmhi, u16* __restrict__ xmlo, float* __restrict__ xmw) {
  __shared__ float As[64 * 33];
  __shared__ float Ws[64 * 33];
  const int tid = threadIdx.x;
  const int n = blockIdx.x, m0 = blockIdx.y * 64, h0 = blockIdx.z * 64;
  #pragma unroll
  for (int c = 0; c < 2; ++c) {
    int r = c * 32 + (tid >> 3);
    int col = (tid & 7) * 4;
    float4 a4 = ld4(t160G + (size_t)(m0 + r) * 160 + n * 32 + col);
    As[r * 33 + col + 0] = a4.x; As[r * 33 + col + 1] = a4.y;
    As[r * 33 + col + 2] = a4.z; As[r * 33 + col + 3] = a4.w;
    float4 w4 = ld4(x2_w + (size_t)(h0 + r) * 160 + n * 32 + col);
    Ws[r * 33 + col + 0] = w4.x; Ws[r * 33 + col + 1] = w4.y;
    Ws[r * 33 + col + 2] = w4.z; Ws[r * 33 + col + 3] = w4.w;
  }
  __syncthreads();
  const int rm = (tid >> 4) * 4, cn = (tid & 15) * 4;
  float acc[4][4] = {};
  #pragma unroll
  for (int kk = 0; kk < 32; ++kk) {
    float a[4], w[4];
    #pragma unroll
    for (int i = 0; i < 4; ++i) a[i] = As[(rm + i) * 33 + kk];
    #pragma unroll
    for (int j = 0; j < 4; ++j) w[j] = Ws[(cn + j) * 33 + kk];
    #pragma unroll
    for (int i = 0; i < 4; ++i)
      #pragma unroll
      for (int j = 0; j < 4; ++j) acc[i][j] += a[i] * w[j];
  }
  const float4 b4 = ld4(x_bias + n * 1024 + h0 + cn);
  const float4 mu4 = ld4(x0_mu + h0 + cn);
  const int pi = (n == 0) ? 0 : (n == 2) ? 1 : (n == 3) ? 2 : 3;
  #pragma unroll
  for (int i = 0; i < 4; ++i) {
    const size_t rowo = (size_t)(m0 + rm + i) * 1024 + h0 + cn;
    float4 xm4 = ld4(xm0 + rowo);
    float4 dv4 = ld4(delta + rowo);
    float4 o;
    o.x = xm4.x + dv4.x * (acc[i][0] + b4.x - mu4.x);
    o.y = xm4.y + dv4.y * (acc[i][1] + b4.y - mu4.y);
    o.z = xm4.z + dv4.z * (acc[i][2] + b4.z - mu4.z);
    o.w = xm4.w + dv4.w * (acc[i][3] + b4.w - mu4.w);
    if (n == 1) {
      st4(xmw + rowo, o);
    } else {
      ushort4 h;
      h.x = f2bf(o.x); h.y = f2bf(o.y); h.z = f2bf(o.z); h.w = f2bf(o.w);
      *reinterpret_cast<ushort4*>(xmhi + (size_t)pi * Tc * 1024 + rowo) = h;
      if (n != 4) {
        ushort4 l;
        l.x = f2bf(o.x - bf2f(h.x)); l.y = f2bf(o.y - bf2f(h.y));
        l.z = f2bf(o.z - bf2f(h.z)); l.w = f2bf(o.w - bf2f(h.w));
        *reinterpret_cast<ushort4*>(xmlo + (size_t)pi * Tc * 1024 + rowo) = l;
      }
    }
  }
}

// ---------------------------------------------------------------- kernel WL
__global__ __launch_bounds__(256) void kWL(
    const float* __restrict__ xmw, const float* __restrict__ w_w1,
    float* __restrict__ yw) {
  __shared__ float As[32 * 33];
  __shared__ float Ws[64 * 33];
  const int tid = threadIdx.x;
  const int t0 = blockIdx.x * 32;
  const int rg = tid >> 5;
  const int cg = tid & 31;
  float acc[4][2] = {};
  for (int k0 = 0; k0 < 1024; k0 += 32) {
    __syncthreads();
    {
      int r = tid >> 3, c4 = (tid & 7) * 4;
      float4 a4 = ld4(xmw + (size_t)(t0 + r) * 1024 + k0 + c4);
      As[r * 33 + c4 + 0] = a4.x; As[r * 33 + c4 + 1] = a4.y;
      As[r * 33 + c4 + 2] = a4.z; As[r * 33 + c4 + 3] = a4.w;
    }
    #pragma unroll
    for (int c = 0; c < 2; ++c) {
      int r = c * 32 + (tid >> 3), c4 = (tid & 7) * 4;
      float4 w4 = ld4(w_w1 + (size_t)r * 1024 + k0 + c4);
      Ws[r * 33 + c4 + 0] = w4.x; Ws[r * 33 + c4 + 1] = w4.y;
      Ws[r * 33 + c4 + 2] = w4.z; Ws[r * 33 + c4 + 3] = w4.w;
    }
    __syncthreads();
    #pragma unroll
    for (int kk = 0; kk < 32; ++kk) {
      float a[4];
      #pragma unroll
      for (int i = 0; i < 4; ++i) a[i] = As[(rg * 4 + i) * 33 + kk];
      float w0 = Ws[cg * 33 + kk], w1 = Ws[(cg + 32) * 33 + kk];
      #pragma unroll
      for (int i = 0; i < 4; ++i) { acc[i][0] += a[i] * w0; acc[i][1] += a[i] * w1; }
    }
  }
  #pragma unroll
  for (int i = 0; i < 4; ++i) {
    yw[(size_t)(t0 + rg * 4 + i) * 64 + cg]      = tanhf(acc[i][0]);
    yw[(size_t)(t0 + rg * 4 + i) * 64 + cg + 32] = tanhf(acc[i][1]);
  }
}

// ---------------------- bf16x3 MFMA GEMM (r,k,v only; 3-pass, BK=64 swizzled)
__global__ __launch_bounds__(256) void kB(
    const u16* __restrict__ xmhi, const u16* __restrict__ xmlo,
    const u16* __restrict__ Whi, const u16* __restrict__ Wlo,
    float* __restrict__ rG, float* __restrict__ kG, float* __restrict__ vG) {
  __shared__ __align__(16) u16 sAh[128 * 64];
  __shared__ __align__(16) u16 sAl[128 * 64];
  __shared__ __align__(16) u16 sBh[128 * 64];
  __shared__ __align__(16) u16 sBl[128 * 64];
  const int mt = blockIdx.x, nt = blockIdx.y;  // nt 0..15
  int plane, col0, ldc;
  float* Cf;
  if (nt < 4)       { plane = 0; Cf = rG; ldc = 512;  col0 = nt * 128; }
  else if (nt < 8)  { plane = 1; Cf = kG; ldc = 512;  col0 = (nt - 4) * 128; }
  else              { plane = 2; Cf = vG; ldc = 1024; col0 = (nt - 8) * 128; }
  const u16* Ah = xmhi + ((size_t)plane * Tc + (size_t)mt * 128) * 1024;
  const u16* Al = xmlo + ((size_t)plane * Tc + (size_t)mt * 128) * 1024;
  const u16* Bh = Whi + (size_t)nt * 128 * 1024;
  const u16* Bl = Wlo + (size_t)nt * 128 * 1024;

  const int tid = threadIdx.x;
  const int lane = tid & 63;
  const int wv = tid >> 6;
  const int wr = wv >> 1, wc = wv & 1;
  const int srow = wv * 32;
  f32x4 acc[4][4];
  #pragma unroll
  for (int i = 0; i < 4; ++i)
    #pragma unroll
    for (int j = 0; j < 4; ++j) acc[i][j] = {0.f, 0.f, 0.f, 0.f};

  for (int k0 = 0; k0 < 1024; k0 += 64) {
    #pragma unroll
    for (int c = 0; c < 4; ++c) {
      const int s8 = srow + c * 8;
      stage_swz(Ah, sAh, s8, k0, lane);
      stage_swz(Bh, sBh, s8, k0, lane);
      stage_swz(Al, sAl, s8, k0, lane);
      stage_swz(Bl, sBl, s8, k0, lane);
    }
    __syncthreads();
    #pragma unroll
    for (int kk = 0; kk < 2; ++kk) {
      const int sl = kk * 4 + (lane >> 4);
      short8 ah[4], al[4], bh[4], bl[4];
      #pragma unroll
      for (int m = 0; m < 4; ++m) {
        int row = wr * 64 + m * 16 + (lane & 15);
        ah[m] = read_swz(sAh, row, sl);
        al[m] = read_swz(sAl, row, sl);
      }
      #pragma unroll
      for (int j = 0; j < 4; ++j) {
        int row = wc * 64 + j * 16 + (lane & 15);
        bh[j] = read_swz(sBh, row, sl);
        bl[j] = read_swz(sBl, row, sl);
      }
      #pragma unroll
      for (int m = 0; m < 4; ++m)
        #pragma unroll
        for (int j = 0; j < 4; ++j) {
          acc[m][j] = __builtin_amdgcn_mfma_f32_16x16x32_bf16(ah[m], bh[j], acc[m][j], 0, 0, 0);
          acc[m][j] = __builtin_amdgcn_mfma_f32_16x16x32_bf16(al[m], bh[j], acc[m][j], 0, 0, 0);
          acc[m][j] = __builtin_amdgcn_mfma_f32_16x16x32_bf16(ah[m], bl[j], acc[m][j], 0, 0, 0);
        }
    }
    __syncthreads();
  }
  #pragma unroll
  for (int m = 0; m < 4; ++m)
    #pragma unroll
    for (int r = 0; r < 4; ++r) {
      const int row = wr * 64 + m * 16 + (lane >> 4) * 4 + r;
      #pragma unroll
      for (int j = 0; j < 4; ++j) {
        const int col = wc * 64 + j * 16 + (lane & 15);
        Cf[(size_t)(mt * 128 + row) * ldc + col0 + col] = acc[m][j][r];
      }
    }
}

// ---------------------- kernel Bg: g projection, single-pass bf16, 32KB LDS
__global__ __launch_bounds__(256) void kBg(
    const u16* __restrict__ xmhi, const u16* __restrict__ Whi,
    u16* __restrict__ gG) {
  __shared__ __align__(16) u16 Abuf[128 * 64];
  __shared__ __align__(16) u16 Bbuf[128 * 64];
  const int mt = blockIdx.x, ntg = blockIdx.y;  // ntg 0..7
  const u16* A = xmhi + ((size_t)3 * Tc + (size_t)mt * 128) * 1024;
  const u16* W = Whi + (size_t)(2048 + ntg * 128) * 1024;
  const int tid = threadIdx.x;
  const int lane = tid & 63;
  const int wv = tid >> 6;
  const int wr = wv >> 1, wc = wv & 1;
  const int srow = wv * 32;
  f32x4 acc[4][4];
  #pragma unroll
  for (int i = 0; i < 4; ++i)
    #pragma unroll
    for (int j = 0; j < 4; ++j) acc[i][j] = {0.f, 0.f, 0.f, 0.f};
  for (int k0 = 0; k0 < 1024; k0 += 64) {
    #pragma unroll
    for (int c = 0; c < 4; ++c) {
      const int s8 = srow + c * 8;
      stage_swz(A, Abuf, s8, k0, lane);
      stage_swz(W, Bbuf, s8, k0, lane);
    }
    __syncthreads();
    #pragma unroll
    for (int kk = 0; kk < 2; ++kk) {
      const int sl = kk * 4 + (lane >> 4);
      short8 af[4], bfr[4];
      #pragma unroll
      for (int m = 0; m < 4; ++m) {
        int row = wr * 64 + m * 16 + (lane & 15);
        af[m] = read_swz(Abuf, row, sl);
      }
      #pragma unroll
      for (int j = 0; j < 4; ++j) {
        int row = wc * 64 + j * 16 + (lane & 15);
        bfr[j] = read_swz(Bbuf, row, sl);
      }
      #pragma unroll
      for (int m = 0; m < 4; ++m)
        #pragma unroll
        for (int j = 0; j < 4; ++j)
          acc[m][j] = __builtin_amdgcn_mfma_f32_16x16x32_bf16(af[m], bfr[j], acc[m][j], 0, 0, 0);
    }
    __syncthreads();
  }
  #pragma unroll
  for (int m = 0; m < 4; ++m)
    #pragma unroll
    for (int r = 0; r < 4; ++r) {
      const int row = wr * 64 + m * 16 + (lane >> 4) * 4 + r;
      #pragma unroll
      for (int j = 0; j < 4; ++j) {
        const int col = wc * 64 + j * 16 + (lane & 15);
        gG[(size_t)(mt * 128 + row) * 1024 + ntg * 128 + col] = f2bf(acc[m][j][r]);
      }
    }
}

// ---------------------------------------------------------------- kernel C
__global__ __launch_bounds__(256) void kC(
    const float* __restrict__ yw, const float* __restrict__ w_w2,
    const float* __restrict__ w_b2, float* __restrict__ wfin) {
  __shared__ float th[32 * 68];
  const int tid = threadIdx.x;
  const int t0 = blockIdx.x * 32;
  for (int idx = tid; idx < 32 * 64; idx += 256) {
    int i = idx >> 6, j = idx & 63;
    th[i * 68 + j] = yw[(size_t)(t0 + i) * 64 + j];
  }
  __syncthreads();
  const int c = blockIdx.y * 256 + tid;
  float acc[32] = {};
  const float* w2 = w_w2 + (size_t)c * 64;
  for (int k = 0; k < 64; k += 4) {
    float4 wv = ld4(w2 + k);
    #pragma unroll
    for (int i = 0; i < 32; ++i) {
      float4 t4 = ld4(th + i * 68 + k);
      acc[i] += t4.x * wv.x + t4.y * wv.y + t4.z * wv.z + t4.w * wv.w;
    }
  }
  const float b = w_b2[c];
  #pragma unroll
  for (int i = 0; i < 32; ++i)
    wfin[(size_t)(t0 + i) * 512 + c] = -__expf(acc[i] + b);
}

// ---------------------------------------------------------------- kernel D1 v5
// LDS 54,272B (3 blocks/CU) + launch_bounds(512,6) VGPR cap.
//   vl[32][256] (wcl[32][128] aliases head) | kwT[128][33] | Al[32][32] | elast[128]
// qeT eliminated: A phase reads qe rows from qeG (global, same-block visible)
// times elast[d]=exp(-wlast). diag computed inline by diagonal threads.
__global__ __launch_bounds__(512, 6) void kD1(
    const float* __restrict__ rG, const float* __restrict__ kG,
    const float* __restrict__ vG, const float* __restrict__ wfin,
    const float* __restrict__ bonus, float* __restrict__ wkvG,
    float* __restrict__ decayG, float* __restrict__ qeG, float* __restrict__ oG) {
  __shared__ __align__(16) float smem[8192 + 4224 + 1024 + 128];
  float* vl    = smem;            // [32][256]
  float* wcl   = smem;            // [32][128] alias (dead before vl staged)
  float* kwT   = smem + 8192;     // [128][33]
  float* Al    = kwT + 4224;      // [32][32]
  float* elast = Al + 1024;       // [128]
  const int tid = threadIdx.x;
  const int lane = tid & 63;
  const int wv8 = tid >> 6;       // wave 0..7
  const int bid = blockIdx.x;
  const int nc = bid & 63, h = (bid >> 6) & 3, b = bid >> 8;
  const int tb = b * Lc + nc * 32;

  // front-load r/k into registers (only reg-resident staging)
  float rreg[8], kreg[8];
  #pragma unroll
  for (int it = 0; it < 8; ++it) {
    int idx = it * 512 + tid;
    int c = idx >> 7, d = idx & 127;
    rreg[it] = rG[(size_t)(tb + c) * 512 + h * 128 + d];
    kreg[it] = kG[(size_t)(tb + c) * 512 + h * 128 + d];
  }
  // stage wfin -> wcl via global_load_lds (each wave: 2 instrs x 2 rows)
  #pragma unroll
  for (int g2 = 0; g2 < 2; ++g2) {
    const int c0 = wv8 * 4 + g2 * 2;
    const int cc = c0 + (lane >> 5);
    __builtin_amdgcn_global_load_lds(
        (gu32*)(const void*)(wfin + (size_t)(tb + cc) * 512 + h * 128 + (lane & 31) * 4),
        (lu32*)(void*)(wcl + c0 * 128), 16, 0, 0);
  }
  __syncthreads();  // B1 (drains staging)
  // cumsum along chunk dim
  if (tid < 128) {
    const int d = tid;
    float wv_[32];
    #pragma unroll
    for (int c = 0; c < 32; ++c) wv_[c] = wcl[c * 128 + d];
    float run = 0.f;
    #pragma unroll
    for (int c = 0; c < 32; ++c) { run += wv_[c]; wcl[c * 128 + d] = run; }
  }
  __syncthreads();  // B2
  // elementwise: kwT (kv), qeG, decay, elast
  #pragma unroll
  for (int it = 0; it < 8; ++it) {
    int idx = it * 512 + tid;
    int c = idx >> 7, d = idx & 127;
    int t = tb + c;
    float q = rreg[it];
    float k = kreg[it];
    float wcc = wcl[c * 128 + d];
    float wcp = (c > 0) ? wcl[(c - 1) * 128 + d] : 0.f;
    float wlast = wcl[31 * 128 + d];
    kwT[d * 33 + c] = k * __expf(wlast - wcc);
    qeG[(size_t)t * 512 + h * 128 + d] = q * __expf(wcp);
    if (c == 31) {
      decayG[(size_t)bid * 128 + d] = __expf(wlast);
      elast[d] = __expf(-wlast);
    }
  }
  __syncthreads();  // B3 (wcl reads done; kwT/elast/qeG visible)
  // stage v -> vl via global_load_lds (overwrites wcl region); latency hides
  // under the A-phase below, drained at B4.
  #pragma unroll
  for (int c8 = 0; c8 < 4; ++c8) {
    const int c = wv8 * 4 + c8;
    __builtin_amdgcn_global_load_lds(
        (gu32*)(const void*)(vG + (size_t)(tb + c) * 1024 + h * 256 + lane * 4),
        (lu32*)(void*)(vl + c * 256), 16, 0, 0);
  }
  // A[i][j] = sum_d qe[i,d]*elast[d]*kv[j,d]; diag inline on diagonal threads
  {
    const int j = tid & 31, i2 = tid >> 5;  // i2 0..15 -> rows i2, i2+16
    const float* qrow0 = qeG + (size_t)(tb + i2) * 512 + h * 128;
    const float* qrow1 = qeG + (size_t)(tb + i2 + 16) * 512 + h * 128;
    float a0 = 0.f, a1 = 0.f;
    for (int d4 = 0; d4 < 32; ++d4) {
      float4 q0 = ld4(qrow0 + d4 * 4);
      float4 q1 = ld4(qrow1 + d4 * 4);
      float4 el = *reinterpret_cast<const float4*>(elast + d4 * 4);
      #pragma unroll
      for (int dd = 0; dd < 4; ++dd) {
        float kv = kwT[(d4 * 4 + dd) * 33 + j];
        float e = ((const float*)&el)[dd];
        a0 += ((const float*)&q0)[dd] * e * kv;
        a1 += ((const float*)&q1)[dd] * e * kv;
      }
    }
    float dg0 = 0.f, dg1 = 0.f;
    if (j == i2) {
      const float* qr = rG + (size_t)(tb + i2) * 512 + h * 128;
      const float* kr = kG + (size_t)(tb + i2) * 512 + h * 128;
      for (int d4 = 0; d4 < 32; ++d4) {
        float4 q4 = ld4(qr + d4 * 4), k4 = ld4(kr + d4 * 4);
        float4 u4 = ld4(bonus + h * 128 + d4 * 4);
        dg0 += q4.x * u4.x * k4.x + q4.y * u4.y * k4.y +
               q4.z * u4.z * k4.z + q4.w * u4.w * k4.w;
      }
    }
    if (j == i2 + 16) {
      const float* qr = rG + (size_t)(tb + j) * 512 + h * 128;
      const float* kr = kG + (size_t)(tb + j) * 512 + h * 128;
      for (int d4 = 0; d4 < 32; ++d4) {
        float4 q4 = ld4(qr + d4 * 4), k4 = ld4(kr + d4 * 4);
        float4 u4 = ld4(bonus + h * 128 + d4 * 4);
        dg1 += q4.x * u4.x * k4.x + q4.y * u4.y * k4.y +
               q4.z * u4.z * k4.z + q4.w * u4.w * k4.w;
      }
    }
    Al[i2 * 32 + j] = (j < i2) ? a0 : ((j == i2) ? dg0 : 0.f);
    Al[(i2 + 16) * 32 + j] = (j < i2 + 16) ? a1 : ((j == i2 + 16) ? dg1 : 0.f);
  }
  __syncthreads();  // B4 (vl staged + Al visible)
  const int pid = tid & 63, wvx = tid >> 6;
  const int p4 = pid * 4;
  {  // wkv[d][p] = sum_c kv[c][d]*v[c][p]
    float* wkvB = wkvG + (size_t)bid * (128 * 256);
    #pragma unroll
    for (int pp = 0; pp < 2; ++pp) {
      const int d0 = pp * 64 + wvx * 8;
      float4 acc[8];
      #pragma unroll
      for (int q = 0; q < 8; ++q) acc[q] = make_float4(0, 0, 0, 0);
      for (int c = 0; c < 32; ++c) {
        float4 v4 = ld4(vl + c * 256 + p4);
        #pragma unroll
        for (int q = 0; q < 8; ++q) {
          float s = kwT[(d0 + q) * 33 + c];
          acc[q].x += v4.x * s; acc[q].y += v4.y * s;
          acc[q].z += v4.z * s; acc[q].w += v4.w * s;
        }
      }
      #pragma unroll
      for (int q = 0; q < 8; ++q)
        st4(wkvB + (size_t)(d0 + q) * 256 + p4, acc[q]);
    }
  }
  {  // o_intra = A @ v
    float4 acc[4];
    #pragma unroll
    for (int q = 0; q < 4; ++q) acc[q] = make_float4(0, 0, 0, 0);
    for (int c = 0; c < 32; ++c) {
      float4 v4 = ld4(vl + c * 256 + p4);
      #pragma unroll
      for (int q = 0; q < 4; ++q) {
        float a = Al[(wvx * 4 + q) * 32 + c];
        acc[q].x += v4.x * a; acc[q].y += v4.y * a;
        acc[q].z += v4.z * a; acc[q].w += v4.w * a;
      }
    }
    #pragma unroll
    for (int q = 0; q < 4; ++q)
      st4(oG + (size_t)(tb + wvx * 4 + q) * 1024 + h * 256 + p4, acc[q]);
  }
}

// ---------------------------------------------------------------- kernel D2
__global__ __launch_bounds__(256) void kD2(float* __restrict__ wkvG,
                                           const float* __restrict__ decayG) {
  const int wvid = (blockIdx.x * 256 + threadIdx.x) >> 6;  // 0..2047
  const int lane = threadIdx.x & 63;
  const int half = wvid & 1;
  const int d = (wvid >> 1) & 127;
  const int bh = wvid >> 8;
  const int p2 = half * 128 + lane * 2;
  float* base = wkvG + ((size_t)bh * 64 * 128 + d) * 256 + p2;
  const float* dbase = decayG + (size_t)bh * 64 * 128 + d;
  float2 kvb[4];
  float decb[4];
  #pragma unroll
  for (int i = 0; i < 4; ++i) {
    kvb[i] = ld2(base + (size_t)i * 32768);
    decb[i] = dbase[(size_t)i * 128];
  }
  float2 S = make_float2(0.f, 0.f);
  #pragma unroll
  for (int nc = 0; nc < 64; ++nc) {
    const int sl = nc & 3;
    float2 kv = kvb[sl];
    float dec = decb[sl];
    if (nc + 4 < 64) {
      kvb[sl] = ld2(base + (size_t)(nc + 4) * 32768);
      decb[sl] = dbase[(size_t)(nc + 4) * 128];
    }
    st2(base + (size_t)nc * 32768, S);
    S.x = S.x * dec + kv.x;
    S.y = S.y * dec + kv.y;
  }
}

// ---------------------------------------------------------------- kernel D3
__global__ __launch_bounds__(256) void kD3(
    const float* __restrict__ qeG, const float* __restrict__ wkvG,
    float* __restrict__ oG) {
  __shared__ float qel[32 * 129];
  const int tid = threadIdx.x;
  const int bid = blockIdx.x;
  const int nc = bid & 63, h = (bid >> 6) & 3, b = bid >> 8;
  const int tb = b * Lc + nc * 32;
  for (int it = 0; it < 16; ++it) {
    int idx = it * 256 + tid;
    int c = idx >> 7, d = idx & 127;
    qel[c * 129 + d] = qeG[(size_t)(tb + c) * 512 + h * 128 + d];
  }
  __syncthreads();
  const int pid = tid & 63, wvx = tid >> 6;
  const int p4 = pid * 4;
  const float* Sb = wkvG + (size_t)bid * (128 * 256);
  float4 acc[8];
  #pragma unroll
  for (int q = 0; q < 8; ++q) acc[q] = make_float4(0, 0, 0, 0);
  for (int d = 0; d < 128; ++d) {
    float4 s4 = ld4(Sb + (size_t)d * 256 + p4);
    #pragma unroll
    for (int q = 0; q < 8; ++q) {
      float qv = qel[(wvx * 8 + q) * 129 + d];
      acc[q].x += s4.x * qv; acc[q].y += s4.y * qv;
      acc[q].z += s4.z * qv; acc[q].w += s4.w * qv;
    }
  }
  #pragma unroll
  for (int q = 0; q < 8; ++q) {
    float* op = oG + (size_t)(tb + wvx * 8 + q) * 1024 + h * 256 + p4;
    float4 cur = ld4(op);
    cur.x += acc[q].x; cur.y += acc[q].y; cur.z += acc[q].z; cur.w += acc[q].w;
    st4(op, cur);
  }
}

// ---------------------------------------------------------------- kernel E
__global__ __launch_bounds__(256) void kE(
    const float* __restrict__ oG, const u16* __restrict__ gG,
    const float* __restrict__ gn_w, const float* __restrict__ gn_b,
    u16* __restrict__ gate) {
  const int t = blockIdx.x;
  const int h = threadIdx.x >> 6, lane = threadIdx.x & 63;
  const int p4 = lane * 4;
  const int vd = h * 256 + p4;
  float4 v = ld4(oG + (size_t)t * 1024 + vd);
  float s = v.x + v.y + v.z + v.w;
  float ss = v.x * v.x + v.y * v.y + v.z * v.z + v.w * v.w;
  for (int m = 1; m < 64; m <<= 1) {
    s += __shfl_xor(s, m, 64);
    ss += __shfl_xor(ss, m, 64);
  }
  const float mean = s * (1.f / 256.f);
  const float var = ss * (1.f / 256.f) - mean * mean;
  const float rs = rsqrtf(var + 1e-5f);
  float4 gw = ld4(gn_w + vd), gb = ld4(gn_b + vd);
  float4 on;
  on.x = (v.x - mean) * rs * gw.x + gb.x;
  on.y = (v.y - mean) * rs * gw.y + gb.y;
  on.z = (v.z - mean) * rs * gw.z + gb.z;
  on.w = (v.w - mean) * rs * gw.w + gb.w;
  ushort4 g4 = *reinterpret_cast<const ushort4*>(gG + (size_t)t * 1024 + vd);
  float gx = bf2f(g4.x), gy = bf2f(g4.y), gz = bf2f(g4.z), gw_ = bf2f(g4.w);
  float4 sw;
  sw.x = gx / (1.f + __expf(-gx));
  sw.y = gy / (1.f + __expf(-gy));
  sw.z = gz / (1.f + __expf(-gz));
  sw.w = gw_ / (1.f + __expf(-gw_));
  ushort4 ob;
  ob.x = f2bf(on.x * sw.x); ob.y = f2bf(on.y * sw.y);
  ob.z = f2bf(on.z * sw.z); ob.w = f2bf(on.w * sw.w);
  *reinterpret_cast<ushort4*>(gate + (size_t)t * 1024 + vd) = ob;
}

// ---------------------------------------------------------------- kernel F
__global__ __launch_bounds__(256) void kF(
    const u16* __restrict__ gate, const u16* __restrict__ owb,
    float* __restrict__ out) {
  __shared__ __align__(16) u16 Abuf[128 * 64];
  __shared__ __align__(16) u16 Bbuf[128 * 64];
  const int mt = blockIdx.x, nt = blockIdx.y;
  const u16* A = gate + (size_t)mt * 128 * 1024;
  const u16* W = owb + (size_t)nt * 128 * 1024;
  float* C = out + (size_t)mt * 128 * 1024 + nt * 128;
  const int tid = threadIdx.x;
  const int lane = tid & 63;
  const int wv = tid >> 6;
  const int wr = wv >> 1, wc = wv & 1;
  const int srow = wv * 32;
  f32x4 acc[4][4];
  #pragma unroll
  for (int i = 0; i < 4; ++i)
    #pragma unroll
    for (int j = 0; j < 4; ++j) acc[i][j] = {0.f, 0.f, 0.f, 0.f};
  for (int k0 = 0; k0 < 1024; k0 += 64) {
    #pragma unroll
    for (int c = 0; c < 4; ++c) {
      const int s8 = srow + c * 8;
      stage_swz(A, Abuf, s8, k0, lane);
      stage_swz(W, Bbuf, s8, k0, lane);
    }
    __syncthreads();
    #pragma unroll
    for (int kk = 0; kk < 2; ++kk) {
      const int sl = kk * 4 + (lane >> 4);
      short8 af[4], bfr[4];
      #pragma unroll
      for (int m = 0; m < 4; ++m) {
        int row = wr * 64 + m * 16 + (lane & 15);
        af[m] = read_swz(Abuf, row, sl);
      }
      #pragma unroll
      for (int j = 0; j < 4; ++j) {
        int row = wc * 64 + j * 16 + (lane & 15);
        bfr[j] = read_swz(Bbuf, row, sl);
      }
      #pragma unroll
      for (int m = 0; m < 4; ++m)
        #pragma unroll
        for (int j = 0; j < 4; ++j)
          acc[m][j] = __builtin_amdgcn_mfma_f32_16x16x32_bf16(af[m], bfr[j], acc[m][j], 0, 0, 0);
    }
    __syncthreads();
  }
  #pragma unroll
  for (int m = 0; m < 4; ++m)
    #pragma unroll
    for (int r = 0; r < 4; ++r) {
      const int row = wr * 64 + m * 16 + (lane >> 4) * 4 + r;
      #pragma unroll
      for (int j = 0; j < 4; ++j) {
        const int col = wc * 64 + j * 16 + (lane & 15);
        C[(size_t)row * 1024 + col] = acc[m][j][r];
      }
    }
}

}  // namespace

extern "C" void kernel_launch(void* const* d_in, const int* in_sizes, int n_in,
                              void* d_out, int out_size, void* d_ws, size_t ws_size,
                              hipStream_t stream) {
  (void)in_sizes; (void)n_in; (void)out_size;
  if (ws_size < WS_NEED) return;

  const float* x      = (const float*)d_in[0];
  const float* x0_mu  = (const float*)d_in[1];
  const float* x0_w   = (const float*)d_in[2];
  const float* x2_w   = (const float*)d_in[3];
  const float* x_bias = (const float*)d_in[4];
  const float* r_w    = (const float*)d_in[5];
  const float* w_w1   = (const float*)d_in[6];
  const float* w_w2   = (const float*)d_in[7];
  const float* w_b2   = (const float*)d_in[8];
  const float* k_w    = (const float*)d_in[9];
  const float* v_w    = (const float*)d_in[10];
  const float* g_w    = (const float*)d_in[11];
  const float* bonus  = (const float*)d_in[12];
  const float* gn_w   = (const float*)d_in[13];
  const float* gn_b   = (const float*)d_in[14];
  const float* o_w    = (const float*)d_in[15];
  float* out = (float*)d_out;
  char* ws = (char*)d_ws;

  float* wkvG   = (float*)(ws + OFF_WKV);
  float* xm0    = (float*)(ws + OFF_XM0);
  float* delta  = (float*)(ws + OFF_DELTA);
  float* t160   = (float*)(ws + OFF_T160);
  float* xmw    = (float*)(ws + OFF_XMW);
  float* yw     = (float*)(ws + OFF_YW);
  u16*   x0whi  = (u16*)(ws + OFF_X0WHI);
  u16*   x0wlo  = (u16*)(ws + OFF_X0WLO);
  u16*   xm0hi  = (u16*)(ws + OFF_XM0HI);
  u16*   xm0lo  = (u16*)(ws + OFF_XM0LO);
  u16*   xmhi   = (u16*)(ws + OFF_XMHI);
  float* wfin   = (float*)(ws + OFF_WFIN);
  u16*   gate   = (u16*)(ws + OFF_GATE);
  u16*   xmlo   = (u16*)(ws + OFF_XMLO);
  float* qeG    = (float*)(ws + OFF_QE);
  float* oG     = (float*)(ws + OFF_OO);
  u16*   Whi    = (u16*)(ws + OFF_WHI);
  u16*   Wlo    = (u16*)(ws + OFF_WLO);
  float* decayG = (float*)(ws + OFF_DECAY);
  u16*   owb    = (u16*)(ws + OFF_OWB);
  float* rG     = (float*)(ws + OFF_RG);
  float* kG     = (float*)(ws + OFF_KG);
  float* vG     = (float*)(ws + OFF_VG);
  u16*   gG     = (u16*)(ws + OFF_GG);

  kW   <<<dim3(4256),        dim3(256), 0, stream>>>(r_w, k_w, v_w, g_w, o_w, x0_w,
                                                     Whi, Wlo, owb, x0whi, x0wlo);
  kA1  <<<dim3(4096),        dim3(256), 0, stream>>>(x, x0_mu, xm0, delta, xm0hi, xm0lo);
  kA2f <<<dim3(32, 2),       dim3(256), 0, stream>>>(xm0hi, xm0lo, x0whi, x0wlo, t160);
  kA2m5<<<dim3(5, 64, 16),   dim3(256), 0, stream>>>(t160, x2_w, x_bias, xm0, delta,
                                                     x0_mu, xmhi, xmlo, xmw);
  kWL  <<<dim3(128),         dim3(256), 0, stream>>>(xmw, w_w1, yw);
  kB   <<<dim3(32, 16),      dim3(256), 0, stream>>>(xmhi, xmlo, Whi, Wlo, rG, kG, vG);
  kBg  <<<dim3(32, 8),       dim3(256), 0, stream>>>(xmhi, Whi, gG);
  kC   <<<dim3(128, 2),      dim3(256), 0, stream>>>(yw, w_w2, w_b2, wfin);
  kD1  <<<dim3(512),         dim3(512), 0, stream>>>(rG, kG, vG, wfin, bonus,
                                                     wkvG, decayG, qeG, oG);
  kD2  <<<dim3(512),         dim3(256), 0, stream>>>(wkvG, decayG);
  kD3  <<<dim3(512),         dim3(256), 0, stream>>>(qeG, wkvG, oG);
  kE   <<<dim3(4096),        dim3(256), 0, stream>>>(oG, gG, gn_w, gn_b, gate);
  kF   <<<dim3(32, 8),       dim3(256), 0, stream>>>(gate, owb, out);
}

// Round 10
// 409.959 us; speedup vs baseline: 1.5172x; 1.5172x over previous
//
#include <hip/hip_runtime.h>

// RWKV6Attention forward — round 10: exact R8 base (402.8us proven) +
// (a) kE fused into kD3 (kD3E: GroupNorm+gate in the o_inter kernel),
// (b) kD2 4 waves/row for more scan TLP. No other changes.

#define DEVI __device__ __forceinline__

namespace {

typedef unsigned short u16;
typedef unsigned int u32;
typedef __attribute__((ext_vector_type(8))) short short8;   // 8 bf16 (4 VGPRs)
typedef __attribute__((ext_vector_type(4))) float f32x4;

typedef __attribute__((address_space(1))) const u32 gu32;
typedef __attribute__((address_space(3))) u32 lu32;

constexpr int Lc = 2048;
constexpr int Tc = 4096;   // B*L

// ---- workspace layout (byte offsets), lifetime-safe aliasing (same as R8).
constexpr size_t OFF_WKV   = 0;
constexpr size_t OFF_XM0   = 0;
constexpr size_t OFF_DELTA = 16777216;
constexpr size_t OFF_T160  = 33554432;
constexpr size_t OFF_XMW   = 36175872;
constexpr size_t OFF_YW    = 52953088;
constexpr size_t OFF_X0WHI = 54001664;
constexpr size_t OFF_X0WLO = 54329344;
constexpr size_t OFF_XMHI  = 67108864;
constexpr size_t OFF_XM0HI = 67108864;
constexpr size_t OFF_XM0LO = 75497472;
constexpr size_t OFF_WFIN  = 67108864;
constexpr size_t OFF_GATE  = 75497472;
constexpr size_t OFF_XMLO  = 100663296;
constexpr size_t OFF_QE    = 100663296;
constexpr size_t OFF_OO    = 109051904;
constexpr size_t OFF_WHI   = 125829120;
constexpr size_t OFF_WLO   = 132120576;
constexpr size_t OFF_DECAY = 132120576;
constexpr size_t OFF_OWB   = 136314880;
constexpr size_t OFF_RG    = 138412032;
constexpr size_t OFF_KG    = 146800640;
constexpr size_t OFF_VG    = 155189248;
constexpr size_t OFF_GG    = 171966464;
constexpr size_t WS_NEED   = 180355072;

DEVI float4 ld4(const float* p) { return *reinterpret_cast<const float4*>(p); }
DEVI void   st4(float* p, float4 v) { *reinterpret_cast<float4*>(p) = v; }
DEVI u16 f2bf(float f) {
  u32 u = __float_as_uint(f);
  return (u16)((u + 0x7FFFu + ((u >> 16) & 1u)) >> 16);
}
DEVI float bf2f(u16 u) { return __uint_as_float((u32)u << 16); }

// ---- BK=64 swizzled staging helpers (kA2f, kB, kF)
DEVI void stage_swz(const u16* __restrict__ src, u16* __restrict__ dstBase,
                    int srow8, int k0, int lane) {
  const int rr = srow8 + (lane >> 3);
  const int ss = (lane & 7) ^ ((lane >> 3) & 7);
  __builtin_amdgcn_global_load_lds(
      (gu32*)(const void*)(src + (size_t)rr * 1024 + k0 + ss * 8),
      (lu32*)(void*)(dstBase + srow8 * 64), 16, 0, 0);
}
DEVI short8 read_swz(const u16* __restrict__ buf, int row, int slot_lin) {
  return *reinterpret_cast<const short8*>(buf + row * 64 + ((slot_lin ^ (row & 7)) * 8));
}

// ---------------------------------------------------------------- kernel W
__global__ void kW(const float* __restrict__ r_w, const float* __restrict__ k_w,
                   const float* __restrict__ v_w, const float* __restrict__ g_w,
                   const float* __restrict__ o_w, const float* __restrict__ x0_w,
                   u16* __restrict__ Whi, u16* __restrict__ Wlo,
                   u16* __restrict__ owb, u16* __restrict__ x0whi,
                   u16* __restrict__ x0wlo) {
  const size_t i = ((size_t)blockIdx.x * 256 + threadIdx.x) * 4;
  if (i < 3145728) {
    const float* src = (i < 524288)  ? r_w + i
                     : (i < 1048576) ? k_w + (i - 524288)
                     : (i < 2097152) ? v_w + (i - 1048576)
                                     : g_w + (i - 2097152);
    float4 v = ld4(src);
    ushort4 h;
    h.x = f2bf(v.x); h.y = f2bf(v.y); h.z = f2bf(v.z); h.w = f2bf(v.w);
    *reinterpret_cast<ushort4*>(Whi + i) = h;
    if (i < 2097152) {
      ushort4 l;
      l.x = f2bf(v.x - bf2f(h.x)); l.y = f2bf(v.y - bf2f(h.y));
      l.z = f2bf(v.z - bf2f(h.z)); l.w = f2bf(v.w - bf2f(h.w));
      *reinterpret_cast<ushort4*>(Wlo + i) = l;
    }
  } else if (i < 4194304) {
    float4 v = ld4(o_w + (i - 3145728));
    ushort4 h;
    h.x = f2bf(v.x); h.y = f2bf(v.y); h.z = f2bf(v.z); h.w = f2bf(v.w);
    *reinterpret_cast<ushort4*>(owb + (i - 3145728)) = h;
  } else {
    const size_t j = i - 4194304;
    float4 v = ld4(x0_w + j);
    ushort4 h, l;
    h.x = f2bf(v.x); h.y = f2bf(v.y); h.z = f2bf(v.z); h.w = f2bf(v.w);
    l.x = f2bf(v.x - bf2f(h.x)); l.y = f2bf(v.y - bf2f(h.y));
    l.z = f2bf(v.z - bf2f(h.z)); l.w = f2bf(v.w - bf2f(h.w));
    *reinterpret_cast<ushort4*>(x0whi + j) = h;
    *reinterpret_cast<ushort4*>(x0wlo + j) = l;
  }
}

// ---------------------------------------------------------------- kernel A1
__global__ void kA1(const float* __restrict__ x, const float* __restrict__ x0_mu,
                    float* __restrict__ xm0, float* __restrict__ delta,
                    u16* __restrict__ xm0hi, u16* __restrict__ xm0lo) {
  const size_t i4 = (size_t)blockIdx.x * 256 + threadIdx.x;
  const int t = (int)(i4 >> 8);
  const int h4 = (int)(i4 & 255) * 4;
  float4 xv = ld4(x + (size_t)t * 1024 + h4);
  float4 xp = make_float4(0.f, 0.f, 0.f, 0.f);
  if (t & (Lc - 1)) xp = ld4(x + (size_t)(t - 1) * 1024 + h4);
  float4 mu = ld4(x0_mu + h4);
  float4 d;
  d.x = xp.x - xv.x; d.y = xp.y - xv.y; d.z = xp.z - xv.z; d.w = xp.w - xv.w;
  st4(delta + (size_t)t * 1024 + h4, d);
  float4 m0;
  m0.x = xv.x + d.x * mu.x; m0.y = xv.y + d.y * mu.y;
  m0.z = xv.z + d.z * mu.z; m0.w = xv.w + d.w * mu.w;
  st4(xm0 + (size_t)t * 1024 + h4, m0);
  ushort4 h, l;
  h.x = f2bf(m0.x); h.y = f2bf(m0.y); h.z = f2bf(m0.z); h.w = f2bf(m0.w);
  l.x = f2bf(m0.x - bf2f(h.x)); l.y = f2bf(m0.y - bf2f(h.y));
  l.z = f2bf(m0.z - bf2f(h.z)); l.w = f2bf(m0.w - bf2f(h.w));
  *reinterpret_cast<ushort4*>(xm0hi + (size_t)t * 1024 + h4) = h;
  *reinterpret_cast<ushort4*>(xm0lo + (size_t)t * 1024 + h4) = l;
}

// ---------------------------------------------------------------- kernel A2f
__global__ __launch_bounds__(256) void kA2f(
    const u16* __restrict__ xm0hi, const u16* __restrict__ xm0lo,
    const u16* __restrict__ x0whi, const u16* __restrict__ x0wlo,
    float* __restrict__ t160) {
  __shared__ __align__(16) u16 sAh[128 * 64];
  __shared__ __align__(16) u16 sAl[128 * 64];
  __shared__ __align__(16) u16 sBh[128 * 64];
  __shared__ __align__(16) u16 sBl[128 * 64];
  const int mt = blockIdx.x, nt = blockIdx.y;
  const int ncols = nt ? 32 : 128;
  const int wcol0 = nt * 128;
  const u16* Ah = xm0hi + (size_t)mt * 128 * 1024;
  const u16* Al = xm0lo + (size_t)mt * 128 * 1024;
  const u16* Bh = x0whi + (size_t)wcol0 * 1024;
  const u16* Bl = x0wlo + (size_t)wcol0 * 1024;
  const int tid = threadIdx.x;
  const int lane = tid & 63;
  const int wv = tid >> 6;
  const int wr = wv >> 1, wc = wv & 1;
  const int srow = wv * 32;
  f32x4 acc[4][4];
  #pragma unroll
  for (int i = 0; i < 4; ++i)
    #pragma unroll
    for (int j = 0; j < 4; ++j) acc[i][j] = {0.f, 0.f, 0.f, 0.f};

  for (int k0 = 0; k0 < 1024; k0 += 64) {
    #pragma unroll
    for (int c = 0; c < 4; ++c) {
      const int s8 = srow + c * 8;
      stage_swz(Ah, sAh, s8, k0, lane);
      stage_swz(Al, sAl, s8, k0, lane);
      {
        const int rr = (s8 + (lane >> 3)) & (ncols - 1);
        const int ss = (lane & 7) ^ ((lane >> 3) & 7);
        __builtin_amdgcn_global_load_lds(
            (gu32*)(const void*)(Bh + (size_t)rr * 1024 + k0 + ss * 8),
            (lu32*)(void*)(sBh + s8 * 64), 16, 0, 0);
        __builtin_amdgcn_global_load_lds(
            (gu32*)(const void*)(Bl + (size_t)rr * 1024 + k0 + ss * 8),
            (lu32*)(void*)(sBl + s8 * 64), 16, 0, 0);
      }
    }
    __syncthreads();
    #pragma unroll
    for (int kk = 0; kk < 2; ++kk) {
      const int sl = kk * 4 + (lane >> 4);
      short8 ah[4], al[4], bh[4], bl[4];
      #pragma unroll
      for (int m = 0; m < 4; ++m) {
        int row = wr * 64 + m * 16 + (lane & 15);
        ah[m] = read_swz(sAh, row, sl);
        al[m] = read_swz(sAl, row, sl);
      }
      #pragma unroll
      for (int j = 0; j < 4; ++j) {
        int row = wc * 64 + j * 16 + (lane & 15);
        bh[j] = read_swz(sBh, row, sl);
        bl[j] = read_swz(sBl, row, sl);
      }
      #pragma unroll
      for (int m = 0; m < 4; ++m)
        #pragma unroll
        for (int j = 0; j < 4; ++j) {
          acc[m][j] = __builtin_amdgcn_mfma_f32_16x16x32_bf16(ah[m], bh[j], acc[m][j], 0, 0, 0);
          acc[m][j] = __builtin_amdgcn_mfma_f32_16x16x32_bf16(al[m], bh[j], acc[m][j], 0, 0, 0);
          acc[m][j] = __builtin_amdgcn_mfma_f32_16x16x32_bf16(ah[m], bl[j], acc[m][j], 0, 0, 0);
        }
    }
    __syncthreads();
  }
  #pragma unroll
  for (int m = 0; m < 4; ++m)
    #pragma unroll
    for (int r = 0; r < 4; ++r) {
      const int row = wr * 64 + m * 16 + (lane >> 4) * 4 + r;
      #pragma unroll
      for (int j = 0; j < 4; ++j) {
        const int col = wc * 64 + j * 16 + (lane & 15);
        if (col < ncols)
          t160[(size_t)(mt * 128 + row) * 160 + wcol0 + col] = tanhf(acc[m][j][r]);
      }
    }
}

// ---------------------------------------------------------------- kernel A2m5
__global__ __launch_bounds__(256) void kA2m5(
    const float* __restrict__ t160G, const float* __restrict__ x2_w,
    const float* __restrict__ x_bias, const float* __restrict__ xm0,
    const float* __restrict__ delta, const float* __restrict__ x0_mu,
    u16* __restrict__ xmhi, u16* __restrict__ xmlo, float* __restrict__ xmw) {
  __shared__ float As[64 * 33];
  __shared__ float Ws[64 * 33];
  const int tid = threadIdx.x;
  const int m0 = blockIdx.x * 64, h0 = blockIdx.y * 64, n = blockIdx.z;
  #pragma unroll
  for (int c = 0; c < 2; ++c) {
    int r = c * 32 + (tid >> 3);
    int col = (tid & 7) * 4;
    float4 a4 = ld4(t160G + (size_t)(m0 + r) * 160 + n * 32 + col);
    As[r * 33 + col + 0] = a4.x; As[r * 33 + col + 1] = a4.y;
    As[r * 33 + col + 2] = a4.z; As[r * 33 + col + 3] = a4.w;
    float4 w4 = ld4(x2_w + (size_t)(h0 + r) * 160 + n * 32 + col);
    Ws[r * 33 + col + 0] = w4.x; Ws[r * 33 + col + 1] = w4.y;
    Ws[r * 33 + col + 2] = w4.z; Ws[r * 33 + col + 3] = w4.w;
  }
  __syncthreads();
  const int rm = (tid >> 4) * 4, cn = (tid & 15) * 4;
  float acc[4][4] = {};
  #pragma unroll
  for (int kk = 0; kk < 32; ++kk) {
    float a[4], w[4];
    #pragma unroll
    for (int i = 0; i < 4; ++i) a[i] = As[(rm + i) * 33 + kk];
    #pragma unroll
    for (int j = 0; j < 4; ++j) w[j] = Ws[(cn + j) * 33 + kk];
    #pragma unroll
    for (int i = 0; i < 4; ++i)
      #pragma unroll
      for (int j = 0; j < 4; ++j) acc[i][j] += a[i] * w[j];
  }
  const float4 b4 = ld4(x_bias + n * 1024 + h0 + cn);
  const float4 mu4 = ld4(x0_mu + h0 + cn);
  const int pi = (n == 0) ? 0 : (n == 2) ? 1 : (n == 3) ? 2 : 3;
  #pragma unroll
  for (int i = 0; i < 4; ++i) {
    const size_t rowo = (size_t)(m0 + rm + i) * 1024 + h0 + cn;
    float4 xm4 = ld4(xm0 + rowo);
    float4 dv4 = ld4(delta + rowo);
    float4 o;
    o.x = xm4.x + dv4.x * (acc[i][0] + b4.x - mu4.x);
    o.y = xm4.y + dv4.y * (acc[i][1] + b4.y - mu4.y);
    o.z = xm4.z + dv4.z * (acc[i][2] + b4.z - mu4.z);
    o.w = xm4.w + dv4.w * (acc[i][3] + b4.w - mu4.w);
    if (n == 1) {
      st4(xmw + rowo, o);
    } else {
      ushort4 h;
      h.x = f2bf(o.x); h.y = f2bf(o.y); h.z = f2bf(o.z); h.w = f2bf(o.w);
      *reinterpret_cast<ushort4*>(xmhi + (size_t)pi * Tc * 1024 + rowo) = h;
      if (n != 4) {
        ushort4 l;
        l.x = f2bf(o.x - bf2f(h.x)); l.y = f2bf(o.y - bf2f(h.y));
        l.z = f2bf(o.z - bf2f(h.z)); l.w = f2bf(o.w - bf2f(h.w));
        *reinterpret_cast<ushort4*>(xmlo + (size_t)pi * Tc * 1024 + rowo) = l;
      }
    }
  }
}

// ---------------------------------------------------------------- kernel WL
__global__ __launch_bounds__(256) void kWL(
    const float* __restrict__ xmw, const float* __restrict__ w_w1,
    float* __restrict__ yw) {
  __shared__ float As[32 * 33];
  __shared__ float Ws[64 * 33];
  const int tid = threadIdx.x;
  const int t0 = blockIdx.x * 32;
  const int rg = tid >> 5;
  const int cg = tid & 31;
  float acc[4][2] = {};
  for (int k0 = 0; k0 < 1024; k0 += 32) {
    __syncthreads();
    {
      int r = tid >> 3, c4 = (tid & 7) * 4;
      float4 a4 = ld4(xmw + (size_t)(t0 + r) * 1024 + k0 + c4);
      As[r * 33 + c4 + 0] = a4.x; As[r * 33 + c4 + 1] = a4.y;
      As[r * 33 + c4 + 2] = a4.z; As[r * 33 + c4 + 3] = a4.w;
    }
    #pragma unroll
    for (int c = 0; c < 2; ++c) {
      int r = c * 32 + (tid >> 3), c4 = (tid & 7) * 4;
      float4 w4 = ld4(w_w1 + (size_t)r * 1024 + k0 + c4);
      Ws[r * 33 + c4 + 0] = w4.x; Ws[r * 33 + c4 + 1] = w4.y;
      Ws[r * 33 + c4 + 2] = w4.z; Ws[r * 33 + c4 + 3] = w4.w;
    }
    __syncthreads();
    #pragma unroll
    for (int kk = 0; kk < 32; ++kk) {
      float a[4];
      #pragma unroll
      for (int i = 0; i < 4; ++i) a[i] = As[(rg * 4 + i) * 33 + kk];
      float w0 = Ws[cg * 33 + kk], w1 = Ws[(cg + 32) * 33 + kk];
      #pragma unroll
      for (int i = 0; i < 4; ++i) { acc[i][0] += a[i] * w0; acc[i][1] += a[i] * w1; }
    }
  }
  #pragma unroll
  for (int i = 0; i < 4; ++i) {
    yw[(size_t)(t0 + rg * 4 + i) * 64 + cg]      = tanhf(acc[i][0]);
    yw[(size_t)(t0 + rg * 4 + i) * 64 + cg + 32] = tanhf(acc[i][1]);
  }
}

// -------------------------------------------- bf16x3 MFMA GEMM (R6/R8 version)
__global__ __launch_bounds__(256) void kB(
    const u16* __restrict__ xmhi, const u16* __restrict__ xmlo,
    const u16* __restrict__ Whi, const u16* __restrict__ Wlo,
    float* __restrict__ rG, float* __restrict__ kG,
    float* __restrict__ vG, u16* __restrict__ gG) {
  __shared__ __align__(16) u16 sAh[128 * 64];
  __shared__ __align__(16) u16 sAl[128 * 64];
  __shared__ __align__(16) u16 sBh[128 * 64];
  __shared__ __align__(16) u16 sBl[128 * 64];
  const int mt = blockIdx.x, nt = blockIdx.y;
  int plane, col0, ldc;
  float* Cf = nullptr;
  u16* Cb = nullptr;
  bool three = true;
  if (nt < 4)       { plane = 0; Cf = rG; ldc = 512;  col0 = nt * 128; }
  else if (nt < 8)  { plane = 1; Cf = kG; ldc = 512;  col0 = (nt - 4) * 128; }
  else if (nt < 16) { plane = 2; Cf = vG; ldc = 1024; col0 = (nt - 8) * 128; }
  else              { plane = 3; Cb = gG; ldc = 1024; col0 = (nt - 16) * 128; three = false; }
  const u16* Ah = xmhi + ((size_t)plane * Tc + (size_t)mt * 128) * 1024;
  const u16* Al = xmlo + ((size_t)plane * Tc + (size_t)mt * 128) * 1024;
  const u16* Bh = Whi + (size_t)nt * 128 * 1024;
  const u16* Bl = Wlo + (size_t)nt * 128 * 1024;

  const int tid = threadIdx.x;
  const int lane = tid & 63;
  const int wv = tid >> 6;
  const int wr = wv >> 1, wc = wv & 1;
  const int srow = wv * 32;
  f32x4 acc[4][4];
  #pragma unroll
  for (int i = 0; i < 4; ++i)
    #pragma unroll
    for (int j = 0; j < 4; ++j) acc[i][j] = {0.f, 0.f, 0.f, 0.f};

  for (int k0 = 0; k0 < 1024; k0 += 64) {
    #pragma unroll
    for (int c = 0; c < 4; ++c) {
      const int s8 = srow + c * 8;
      stage_swz(Ah, sAh, s8, k0, lane);
      stage_swz(Bh, sBh, s8, k0, lane);
      if (three) {
        stage_swz(Al, sAl, s8, k0, lane);
        stage_swz(Bl, sBl, s8, k0, lane);
      }
    }
    __syncthreads();
    #pragma unroll
    for (int kk = 0; kk < 2; ++kk) {
      const int sl = kk * 4 + (lane >> 4);
      short8 ah[4], al[4], bh[4], bl[4];
      #pragma unroll
      for (int m = 0; m < 4; ++m) {
        int row = wr * 64 + m * 16 + (lane & 15);
        ah[m] = read_swz(sAh, row, sl);
        if (three) al[m] = read_swz(sAl, row, sl);
      }
      #pragma unroll
      for (int j = 0; j < 4; ++j) {
        int row = wc * 64 + j * 16 + (lane & 15);
        bh[j] = read_swz(sBh, row, sl);
        if (three) bl[j] = read_swz(sBl, row, sl);
      }
      #pragma unroll
      for (int m = 0; m < 4; ++m)
        #pragma unroll
        for (int j = 0; j < 4; ++j) {
          acc[m][j] = __builtin_amdgcn_mfma_f32_16x16x32_bf16(ah[m], bh[j], acc[m][j], 0, 0, 0);
          if (three) {
            acc[m][j] = __builtin_amdgcn_mfma_f32_16x16x32_bf16(al[m], bh[j], acc[m][j], 0, 0, 0);
            acc[m][j] = __builtin_amdgcn_mfma_f32_16x16x32_bf16(ah[m], bl[j], acc[m][j], 0, 0, 0);
          }
        }
    }
    __syncthreads();
  }
  #pragma unroll
  for (int m = 0; m < 4; ++m)
    #pragma unroll
    for (int r = 0; r < 4; ++r) {
      const int row = wr * 64 + m * 16 + (lane >> 4) * 4 + r;
      #pragma unroll
      for (int j = 0; j < 4; ++j) {
        const int col = wc * 64 + j * 16 + (lane & 15);
        float v = acc[m][j][r];
        if (Cf) Cf[(size_t)(mt * 128 + row) * ldc + col0 + col] = v;
        else    Cb[(size_t)(mt * 128 + row) * ldc + col0 + col] = f2bf(v);
      }
    }
}

// ---------------------------------------------------------------- kernel C
__global__ __launch_bounds__(256) void kC(
    const float* __restrict__ yw, const float* __restrict__ w_w2,
    const float* __restrict__ w_b2, float* __restrict__ wfin) {
  __shared__ float th[32 * 68];
  const int tid = threadIdx.x;
  const int t0 = blockIdx.x * 32;
  for (int idx = tid; idx < 32 * 64; idx += 256) {
    int i = idx >> 6, j = idx & 63;
    th[i * 68 + j] = yw[(size_t)(t0 + i) * 64 + j];
  }
  __syncthreads();
  const int c = blockIdx.y * 256 + tid;
  float acc[32] = {};
  const float* w2 = w_w2 + (size_t)c * 64;
  for (int k = 0; k < 64; k += 4) {
    float4 wv = ld4(w2 + k);
    #pragma unroll
    for (int i = 0; i < 32; ++i) {
      float4 t4 = ld4(th + i * 68 + k);
      acc[i] += t4.x * wv.x + t4.y * wv.y + t4.z * wv.z + t4.w * wv.w;
    }
  }
  const float b = w_b2[c];
  #pragma unroll
  for (int i = 0; i < 32; ++i)
    wfin[(size_t)(t0 + i) * 512 + c] = -__expf(acc[i] + b);
}

// ---------------------------------------------------------------- kernel D1 (R8 v3)
__global__ __launch_bounds__(512) void kD1(
    const float* __restrict__ rG, const float* __restrict__ kG,
    const float* __restrict__ vG, const float* __restrict__ wfin,
    const float* __restrict__ bonus, float* __restrict__ wkvG,
    float* __restrict__ decayG, float* __restrict__ qeG, float* __restrict__ oG) {
  __shared__ float smem[4224 + 4224 + 8192 + 1056 + 64];
  float* kwT   = smem;            // [128][33]
  float* qeT   = kwT + 4224;      // [128][33]
  float* vl    = qeT + 4224;      // [32][256]
  float* wcl   = vl;              // [32][128] alias (dead before vl written)
  float* Al    = vl + 8192;       // [32][33]
  float* diag2 = Al + 1056;       // [32][2]
  const int tid = threadIdx.x;
  const int bid = blockIdx.x;
  const int nc = bid & 63, h = (bid >> 6) & 3, b = bid >> 8;
  const int tb = b * Lc + nc * 32;

  float4 wf[2];
  #pragma unroll
  for (int it = 0; it < 2; ++it) {
    int idx = it * 512 + tid;
    int c = idx >> 5, d4 = (idx & 31) * 4;
    wf[it] = ld4(wfin + (size_t)(tb + c) * 512 + h * 128 + d4);
  }
  float4 vreg[4];
  #pragma unroll
  for (int it = 0; it < 4; ++it) {
    int idx = it * 512 + tid;
    int c = idx >> 6, p4 = (idx & 63) * 4;
    vreg[it] = ld4(vG + (size_t)(tb + c) * 1024 + h * 256 + p4);
  }
  float rreg[8], kreg[8];
  #pragma unroll
  for (int it = 0; it < 8; ++it) {
    int idx = it * 512 + tid;
    int c = idx >> 7, d = idx & 127;
    rreg[it] = rG[(size_t)(tb + c) * 512 + h * 128 + d];
    kreg[it] = kG[(size_t)(tb + c) * 512 + h * 128 + d];
  }
  const float ureg = bonus[h * 128 + (tid & 127)];

  #pragma unroll
  for (int it = 0; it < 2; ++it) {
    int idx = it * 512 + tid;
    int c = idx >> 5, d4 = (idx & 31) * 4;
    st4(wcl + c * 128 + d4, wf[it]);
  }
  __syncthreads();  // B1
  if (tid < 128) {
    const int d = tid;
    float wv_[32];
    #pragma unroll
    for (int c = 0; c < 32; ++c) wv_[c] = wcl[c * 128 + d];
    float run = 0.f;
    #pragma unroll
    for (int c = 0; c < 32; ++c) { run += wv_[c]; wcl[c * 128 + d] = run; }
  }
  __syncthreads();  // B2
  #pragma unroll
  for (int it = 0; it < 8; ++it) {
    int idx = it * 512 + tid;
    int c = idx >> 7, d = idx & 127;
    int t = tb + c;
    float q = rreg[it];
    float k = kreg[it];
    float wcc = wcl[c * 128 + d];
    float wcp = (c > 0) ? wcl[(c - 1) * 128 + d] : 0.f;
    float wlast = wcl[31 * 128 + d];
    float qe = q * __expf(wcp);
    qeT[d * 33 + c] = q * __expf(wcp - wlast);
    kwT[d * 33 + c] = k * __expf(wlast - wcc);
    qeG[(size_t)t * 512 + h * 128 + d] = qe;
    if (c == 31) decayG[(size_t)bid * 128 + d] = __expf(wlast);
    float dv = q * k * ureg;
    #pragma unroll
    for (int m = 1; m < 64; m <<= 1) dv += __shfl_xor(dv, m, 64);
    if ((tid & 63) == 0) diag2[c * 2 + ((tid >> 6) & 1)] = dv;
  }
  __syncthreads();  // B3
  #pragma unroll
  for (int it = 0; it < 4; ++it) {
    int idx = it * 512 + tid;
    int c = idx >> 6, p4 = (idx & 63) * 4;
    st4(vl + c * 256 + p4, vreg[it]);
  }
  {
    const int j = tid & 31, i2 = tid >> 5;
    float a0 = 0.f, a1 = 0.f;
    for (int d = 0; d < 128; ++d) {
      float kv = kwT[d * 33 + j];
      a0 += qeT[d * 33 + i2] * kv;
      a1 += qeT[d * 33 + i2 + 16] * kv;
    }
    float dg0 = diag2[i2 * 2] + diag2[i2 * 2 + 1];
    float dg1 = diag2[(i2 + 16) * 2] + diag2[(i2 + 16) * 2 + 1];
    Al[i2 * 33 + j] = (j < i2) ? a0 : ((j == i2) ? dg0 : 0.f);
    Al[(i2 + 16) * 33 + j] = (j < i2 + 16) ? a1 : ((j == i2 + 16) ? dg1 : 0.f);
  }
  __syncthreads();  // B4
  const int pid = tid & 63, wvx = tid >> 6;
  const int p4 = pid * 4;
  {
    float* wkvB = wkvG + (size_t)bid * (128 * 256);
    #pragma unroll
    for (int pp = 0; pp < 2; ++pp) {
      const int d0 = pp * 64 + wvx * 8;
      float4 acc[8];
      #pragma unroll
      for (int q = 0; q < 8; ++q) acc[q] = make_float4(0, 0, 0, 0);
      for (int c = 0; c < 32; ++c) {
        float4 v4 = ld4(vl + c * 256 + p4);
        #pragma unroll
        for (int q = 0; q < 8; ++q) {
          float s = kwT[(d0 + q) * 33 + c];
          acc[q].x += v4.x * s; acc[q].y += v4.y * s;
          acc[q].z += v4.z * s; acc[q].w += v4.w * s;
        }
      }
      #pragma unroll
      for (int q = 0; q < 8; ++q)
        st4(wkvB + (size_t)(d0 + q) * 256 + p4, acc[q]);
    }
  }
  {
    float4 acc[4];
    #pragma unroll
    for (int q = 0; q < 4; ++q) acc[q] = make_float4(0, 0, 0, 0);
    for (int c = 0; c < 32; ++c) {
      float4 v4 = ld4(vl + c * 256 + p4);
      #pragma unroll
      for (int q = 0; q < 4; ++q) {
        float a = Al[(wvx * 4 + q) * 33 + c];
        acc[q].x += v4.x * a; acc[q].y += v4.y * a;
        acc[q].z += v4.z * a; acc[q].w += v4.w * a;
      }
    }
    #pragma unroll
    for (int q = 0; q < 4; ++q)
      st4(oG + (size_t)(tb + wvx * 4 + q) * 1024 + h * 256 + p4, acc[q]);
  }
}

// ---------------------------------------------------------------- kernel D2
// inter-chunk scan, 4 waves per (b,h,d)-row (scalar f32 lanes), 4-deep prefetch.
__global__ __launch_bounds__(256) void kD2(float* __restrict__ wkvG,
                                           const float* __restrict__ decayG) {
  const int wvid = (blockIdx.x * 256 + threadIdx.x) >> 6;  // 0..4095
  const int lane = threadIdx.x & 63;
  const int quarter = wvid & 3;
  const int d = (wvid >> 2) & 127;
  const int bh = wvid >> 9;
  const int p = quarter * 64 + lane;
  float* base = wkvG + ((size_t)bh * 64 * 128 + d) * 256 + p;
  const float* dbase = decayG + (size_t)bh * 64 * 128 + d;
  float kvb[4];
  float decb[4];
  #pragma unroll
  for (int i = 0; i < 4; ++i) {
    kvb[i] = base[(size_t)i * 32768];
    decb[i] = dbase[(size_t)i * 128];
  }
  float S = 0.f;
  #pragma unroll
  for (int nc = 0; nc < 64; ++nc) {
    const int sl = nc & 3;
    float kv = kvb[sl];
    float dec = decb[sl];
    if (nc + 4 < 64) {
      kvb[sl] = base[(size_t)(nc + 4) * 32768];
      decb[sl] = dbase[(size_t)(nc + 4) * 128];
    }
    base[(size_t)nc * 32768] = S;
    S = S * dec + kv;
  }
}

// ------------------------------------------- kernel D3E (o_inter + GroupNorm + gate)
// o = o_intra(oG) + qe @ S_before; per-row (token,head) GroupNorm over 256 ch;
// gate_out = on * swish(g). Replaces old kD3 + kE.
__global__ __launch_bounds__(256) void kD3E(
    const float* __restrict__ qeG, const float* __restrict__ wkvG,
    const float* __restrict__ oG, const u16* __restrict__ gG,
    const float* __restrict__ gn_w, const float* __restrict__ gn_b,
    u16* __restrict__ gate) {
  __shared__ float qel[32 * 129];
  const int tid = threadIdx.x;
  const int bid = blockIdx.x;
  const int nc = bid & 63, h = (bid >> 6) & 3, b = bid >> 8;
  const int tb = b * Lc + nc * 32;
  for (int it = 0; it < 16; ++it) {
    int idx = it * 256 + tid;
    int c = idx >> 7, d = idx & 127;
    qel[c * 129 + d] = qeG[(size_t)(tb + c) * 512 + h * 128 + d];
  }
  __syncthreads();
  const int pid = tid & 63, wvx = tid >> 6;
  const int p4 = pid * 4;
  const float* Sb = wkvG + (size_t)bid * (128 * 256);
  float4 acc[8];
  #pragma unroll
  for (int q = 0; q < 8; ++q) acc[q] = make_float4(0, 0, 0, 0);
  for (int d = 0; d < 128; ++d) {
    float4 s4 = ld4(Sb + (size_t)d * 256 + p4);
    #pragma unroll
    for (int q = 0; q < 8; ++q) {
      float qv = qel[(wvx * 8 + q) * 129 + d];
      acc[q].x += s4.x * qv; acc[q].y += s4.y * qv;
      acc[q].z += s4.z * qv; acc[q].w += s4.w * qv;
    }
  }
  // add o_intra, then per-row GroupNorm (row = one token, this head's 256 ch)
  #pragma unroll
  for (int q = 0; q < 8; ++q) {
    const int t = tb + wvx * 8 + q;
    float4 cur = ld4(oG + (size_t)t * 1024 + h * 256 + p4);
    float4 o;
    o.x = cur.x + acc[q].x; o.y = cur.y + acc[q].y;
    o.z = cur.z + acc[q].z; o.w = cur.w + acc[q].w;
    float s = o.x + o.y + o.z + o.w;
    float ss = o.x * o.x + o.y * o.y + o.z * o.z + o.w * o.w;
    #pragma unroll
    for (int m = 1; m < 64; m <<= 1) {
      s += __shfl_xor(s, m, 64);
      ss += __shfl_xor(ss, m, 64);
    }
    const float mean = s * (1.f / 256.f);
    const float var = ss * (1.f / 256.f) - mean * mean;
    const float rs = rsqrtf(var + 1e-5f);
    const int vd = h * 256 + p4;
    float4 gw = ld4(gn_w + vd), gb = ld4(gn_b + vd);
    float4 on;
    on.x = (o.x - mean) * rs * gw.x + gb.x;
    on.y = (o.y - mean) * rs * gw.y + gb.y;
    on.z = (o.z - mean) * rs * gw.z + gb.z;
    on.w = (o.w - mean) * rs * gw.w + gb.w;
    ushort4 g4 = *reinterpret_cast<const ushort4*>(gG + (size_t)t * 1024 + vd);
    float gx = bf2f(g4.x), gy = bf2f(g4.y), gz = bf2f(g4.z), gw_ = bf2f(g4.w);
    float4 sw;
    sw.x = gx / (1.f + __expf(-gx));
    sw.y = gy / (1.f + __expf(-gy));
    sw.z = gz / (1.f + __expf(-gz));
    sw.w = gw_ / (1.f + __expf(-gw_));
    ushort4 ob;
    ob.x = f2bf(on.x * sw.x); ob.y = f2bf(on.y * sw.y);
    ob.z = f2bf(on.z * sw.z); ob.w = f2bf(on.w * sw.w);
    *reinterpret_cast<ushort4*>(gate + (size_t)t * 1024 + vd) = ob;
  }
}

// ---------------------------------------------------------------- kernel F
__global__ __launch_bounds__(256) void kF(
    const u16* __restrict__ gate, const u16* __restrict__ owb,
    float* __restrict__ out) {
  __shared__ __align__(16) u16 Abuf[128 * 64];
  __shared__ __align__(16) u16 Bbuf[128 * 64];
  const int mt = blockIdx.x, nt = blockIdx.y;
  const u16* A = gate + (size_t)mt * 128 * 1024;
  const u16* W = owb + (size_t)nt * 128 * 1024;
  float* C = out + (size_t)mt * 128 * 1024 + nt * 128;
  const int tid = threadIdx.x;
  const int lane = tid & 63;
  const int wv = tid >> 6;
  const int wr = wv >> 1, wc = wv & 1;
  const int srow = wv * 32;
  f32x4 acc[4][4];
  #pragma unroll
  for (int i = 0; i < 4; ++i)
    #pragma unroll
    for (int j = 0; j < 4; ++j) acc[i][j] = {0.f, 0.f, 0.f, 0.f};
  for (int k0 = 0; k0 < 1024; k0 += 64) {
    #pragma unroll
    for (int c = 0; c < 4; ++c) {
      const int s8 = srow + c * 8;
      stage_swz(A, Abuf, s8, k0, lane);
      stage_swz(W, Bbuf, s8, k0, lane);
    }
    __syncthreads();
    #pragma unroll
    for (int kk = 0; kk < 2; ++kk) {
      const int sl = kk * 4 + (lane >> 4);
      short8 af[4], bfr[4];
      #pragma unroll
      for (int m = 0; m < 4; ++m) {
        int row = wr * 64 + m * 16 + (lane & 15);
        af[m] = read_swz(Abuf, row, sl);
      }
      #pragma unroll
      for (int j = 0; j < 4; ++j) {
        int row = wc * 64 + j * 16 + (lane & 15);
        bfr[j] = read_swz(Bbuf, row, sl);
      }
      #pragma unroll
      for (int m = 0; m < 4; ++m)
        #pragma unroll
        for (int j = 0; j < 4; ++j)
          acc[m][j] = __builtin_amdgcn_mfma_f32_16x16x32_bf16(af[m], bfr[j], acc[m][j], 0, 0, 0);
    }
    __syncthreads();
  }
  #pragma unroll
  for (int m = 0; m < 4; ++m)
    #pragma unroll
    for (int r = 0; r < 4; ++r) {
      const int row = wr * 64 + m * 16 + (lane >> 4) * 4 + r;
      #pragma unroll
      for (int j = 0; j < 4; ++j) {
        const int col = wc * 64 + j * 16 + (lane & 15);
        C[(size_t)row * 1024 + col] = acc[m][j][r];
      }
    }
}

}  // namespace

extern "C" void kernel_launch(void* const* d_in, const int* in_sizes, int n_in,
                              void* d_out, int out_size, void* d_ws, size_t ws_size,
                              hipStream_t stream) {
  (void)in_sizes; (void)n_in; (void)out_size;
  if (ws_size < WS_NEED) return;

  const float* x      = (const float*)d_in[0];
  const float* x0_mu  = (const float*)d_in[1];
  const float* x0_w   = (const float*)d_in[2];
  const float* x2_w   = (const float*)d_in[3];
  const float* x_bias = (const float*)d_in[4];
  const float* r_w    = (const float*)d_in[5];
  const float* w_w1   = (const float*)d_in[6];
  const float* w_w2   = (const float*)d_in[7];
  const float* w_b2   = (const float*)d_in[8];
  const float* k_w    = (const float*)d_in[9];
  const float* v_w    = (const float*)d_in[10];
  const float* g_w    = (const float*)d_in[11];
  const float* bonus  = (const float*)d_in[12];
  const float* gn_w   = (const float*)d_in[13];
  const float* gn_b   = (const float*)d_in[14];
  const float* o_w    = (const float*)d_in[15];
  float* out = (float*)d_out;
  char* ws = (char*)d_ws;

  float* wkvG   = (float*)(ws + OFF_WKV);
  float* xm0    = (float*)(ws + OFF_XM0);
  float* delta  = (float*)(ws + OFF_DELTA);
  float* t160   = (float*)(ws + OFF_T160);
  float* xmw    = (float*)(ws + OFF_XMW);
  float* yw     = (float*)(ws + OFF_YW);
  u16*   x0whi  = (u16*)(ws + OFF_X0WHI);
  u16*   x0wlo  = (u16*)(ws + OFF_X0WLO);
  u16*   xm0hi  = (u16*)(ws + OFF_XM0HI);
  u16*   xm0lo  = (u16*)(ws + OFF_XM0LO);
  u16*   xmhi   = (u16*)(ws + OFF_XMHI);
  float* wfin   = (float*)(ws + OFF_WFIN);
  u16*   gate   = (u16*)(ws + OFF_GATE);
  u16*   xmlo   = (u16*)(ws + OFF_XMLO);
  float* qeG    = (float*)(ws + OFF_QE);
  float* oG     = (float*)(ws + OFF_OO);
  u16*   Whi    = (u16*)(ws + OFF_WHI);
  u16*   Wlo    = (u16*)(ws + OFF_WLO);
  float* decayG = (float*)(ws + OFF_DECAY);
  u16*   owb    = (u16*)(ws + OFF_OWB);
  float* rG     = (float*)(ws + OFF_RG);
  float* kG     = (float*)(ws + OFF_KG);
  float* vG     = (float*)(ws + OFF_VG);
  u16*   gG     = (u16*)(ws + OFF_GG);

  kW   <<<dim3(4256),        dim3(256), 0, stream>>>(r_w, k_w, v_w, g_w, o_w, x0_w,
                                                     Whi, Wlo, owb, x0whi, x0wlo);
  kA1  <<<dim3(4096),        dim3(256), 0, stream>>>(x, x0_mu, xm0, delta, xm0hi, xm0lo);
  kA2f <<<dim3(32, 2),       dim3(256), 0, stream>>>(xm0hi, xm0lo, x0whi, x0wlo, t160);
  kA2m5<<<dim3(64, 16, 5),   dim3(256), 0, stream>>>(t160, x2_w, x_bias, xm0, delta,
                                                     x0_mu, xmhi, xmlo, xmw);
  kWL  <<<dim3(128),         dim3(256), 0, stream>>>(xmw, w_w1, yw);
  kB   <<<dim3(32, 24),      dim3(256), 0, stream>>>(xmhi, xmlo, Whi, Wlo, rG, kG, vG, gG);
  kC   <<<dim3(128, 2),      dim3(256), 0, stream>>>(yw, w_w2, w_b2, wfin);
  kD1  <<<dim3(512),         dim3(512), 0, stream>>>(rG, kG, vG, wfin, bonus,
                                                     wkvG, decayG, qeG, oG);
  kD2  <<<dim3(1024),        dim3(256), 0, stream>>>(wkvG, decayG);
  kD3E <<<dim3(512),         dim3(256), 0, stream>>>(qeG, wkvG, oG, gG, gn_w, gn_b, gate);
  kF   <<<dim3(32, 8),       dim3(256), 0, stream>>>(gate, owb, out);
}

// Round 11
// 405.683 us; speedup vs baseline: 1.5332x; 1.0105x over previous
//
#include <hip/hip_runtime.h>

// RWKV6Attention forward — round 11: R8 base (402.8us proven) with
// (a) kD1 v6: wfin+v staged via global_load_lds (R9-proven addressing, NO reg
//     cap) to cut ~24 staged VGPRs -> 2 resident blocks/CU,
// (b) kF BM=64 tiles (512 blocks = 2/CU instead of 1/CU).
// kD2/kD3/kE exactly as R8.

#define DEVI __device__ __forceinline__

namespace {

typedef unsigned short u16;
typedef unsigned int u32;
typedef __attribute__((ext_vector_type(8))) short short8;   // 8 bf16 (4 VGPRs)
typedef __attribute__((ext_vector_type(4))) float f32x4;

typedef __attribute__((address_space(1))) const u32 gu32;
typedef __attribute__((address_space(3))) u32 lu32;

constexpr int Lc = 2048;
constexpr int Tc = 4096;   // B*L

// ---- workspace layout (byte offsets), lifetime-safe aliasing (same as R8).
constexpr size_t OFF_WKV   = 0;
constexpr size_t OFF_XM0   = 0;
constexpr size_t OFF_DELTA = 16777216;
constexpr size_t OFF_T160  = 33554432;
constexpr size_t OFF_XMW   = 36175872;
constexpr size_t OFF_YW    = 52953088;
constexpr size_t OFF_X0WHI = 54001664;
constexpr size_t OFF_X0WLO = 54329344;
constexpr size_t OFF_XMHI  = 67108864;
constexpr size_t OFF_XM0HI = 67108864;
constexpr size_t OFF_XM0LO = 75497472;
constexpr size_t OFF_WFIN  = 67108864;
constexpr size_t OFF_GATE  = 75497472;
constexpr size_t OFF_XMLO  = 100663296;
constexpr size_t OFF_QE    = 100663296;
constexpr size_t OFF_OO    = 109051904;
constexpr size_t OFF_WHI   = 125829120;
constexpr size_t OFF_WLO   = 132120576;
constexpr size_t OFF_DECAY = 132120576;
constexpr size_t OFF_OWB   = 136314880;
constexpr size_t OFF_RG    = 138412032;
constexpr size_t OFF_KG    = 146800640;
constexpr size_t OFF_VG    = 155189248;
constexpr size_t OFF_GG    = 171966464;
constexpr size_t WS_NEED   = 180355072;

DEVI float4 ld4(const float* p) { return *reinterpret_cast<const float4*>(p); }
DEVI void   st4(float* p, float4 v) { *reinterpret_cast<float4*>(p) = v; }
DEVI float2 ld2(const float* p) { return *reinterpret_cast<const float2*>(p); }
DEVI void   st2(float* p, float2 v) { *reinterpret_cast<float2*>(p) = v; }
DEVI u16 f2bf(float f) {
  u32 u = __float_as_uint(f);
  return (u16)((u + 0x7FFFu + ((u >> 16) & 1u)) >> 16);
}
DEVI float bf2f(u16 u) { return __uint_as_float((u32)u << 16); }

// ---- BK=64 swizzled staging helpers (kA2f, kB, kF)
DEVI void stage_swz(const u16* __restrict__ src, u16* __restrict__ dstBase,
                    int srow8, int k0, int lane) {
  const int rr = srow8 + (lane >> 3);
  const int ss = (lane & 7) ^ ((lane >> 3) & 7);
  __builtin_amdgcn_global_load_lds(
      (gu32*)(const void*)(src + (size_t)rr * 1024 + k0 + ss * 8),
      (lu32*)(void*)(dstBase + srow8 * 64), 16, 0, 0);
}
DEVI short8 read_swz(const u16* __restrict__ buf, int row, int slot_lin) {
  return *reinterpret_cast<const short8*>(buf + row * 64 + ((slot_lin ^ (row & 7)) * 8));
}

// ---------------------------------------------------------------- kernel W
__global__ void kW(const float* __restrict__ r_w, const float* __restrict__ k_w,
                   const float* __restrict__ v_w, const float* __restrict__ g_w,
                   const float* __restrict__ o_w, const float* __restrict__ x0_w,
                   u16* __restrict__ Whi, u16* __restrict__ Wlo,
                   u16* __restrict__ owb, u16* __restrict__ x0whi,
                   u16* __restrict__ x0wlo) {
  const size_t i = ((size_t)blockIdx.x * 256 + threadIdx.x) * 4;
  if (i < 3145728) {
    const float* src = (i < 524288)  ? r_w + i
                     : (i < 1048576) ? k_w + (i - 524288)
                     : (i < 2097152) ? v_w + (i - 1048576)
                                     : g_w + (i - 2097152);
    float4 v = ld4(src);
    ushort4 h;
    h.x = f2bf(v.x); h.y = f2bf(v.y); h.z = f2bf(v.z); h.w = f2bf(v.w);
    *reinterpret_cast<ushort4*>(Whi + i) = h;
    if (i < 2097152) {
      ushort4 l;
      l.x = f2bf(v.x - bf2f(h.x)); l.y = f2bf(v.y - bf2f(h.y));
      l.z = f2bf(v.z - bf2f(h.z)); l.w = f2bf(v.w - bf2f(h.w));
      *reinterpret_cast<ushort4*>(Wlo + i) = l;
    }
  } else if (i < 4194304) {
    float4 v = ld4(o_w + (i - 3145728));
    ushort4 h;
    h.x = f2bf(v.x); h.y = f2bf(v.y); h.z = f2bf(v.z); h.w = f2bf(v.w);
    *reinterpret_cast<ushort4*>(owb + (i - 3145728)) = h;
  } else {
    const size_t j = i - 4194304;
    float4 v = ld4(x0_w + j);
    ushort4 h, l;
    h.x = f2bf(v.x); h.y = f2bf(v.y); h.z = f2bf(v.z); h.w = f2bf(v.w);
    l.x = f2bf(v.x - bf2f(h.x)); l.y = f2bf(v.y - bf2f(h.y));
    l.z = f2bf(v.z - bf2f(h.z)); l.w = f2bf(v.w - bf2f(h.w));
    *reinterpret_cast<ushort4*>(x0whi + j) = h;
    *reinterpret_cast<ushort4*>(x0wlo + j) = l;
  }
}

// ---------------------------------------------------------------- kernel A1
__global__ void kA1(const float* __restrict__ x, const float* __restrict__ x0_mu,
                    float* __restrict__ xm0, float* __restrict__ delta,
                    u16* __restrict__ xm0hi, u16* __restrict__ xm0lo) {
  const size_t i4 = (size_t)blockIdx.x * 256 + threadIdx.x;
  const int t = (int)(i4 >> 8);
  const int h4 = (int)(i4 & 255) * 4;
  float4 xv = ld4(x + (size_t)t * 1024 + h4);
  float4 xp = make_float4(0.f, 0.f, 0.f, 0.f);
  if (t & (Lc - 1)) xp = ld4(x + (size_t)(t - 1) * 1024 + h4);
  float4 mu = ld4(x0_mu + h4);
  float4 d;
  d.x = xp.x - xv.x; d.y = xp.y - xv.y; d.z = xp.z - xv.z; d.w = xp.w - xv.w;
  st4(delta + (size_t)t * 1024 + h4, d);
  float4 m0;
  m0.x = xv.x + d.x * mu.x; m0.y = xv.y + d.y * mu.y;
  m0.z = xv.z + d.z * mu.z; m0.w = xv.w + d.w * mu.w;
  st4(xm0 + (size_t)t * 1024 + h4, m0);
  ushort4 h, l;
  h.x = f2bf(m0.x); h.y = f2bf(m0.y); h.z = f2bf(m0.z); h.w = f2bf(m0.w);
  l.x = f2bf(m0.x - bf2f(h.x)); l.y = f2bf(m0.y - bf2f(h.y));
  l.z = f2bf(m0.z - bf2f(h.z)); l.w = f2bf(m0.w - bf2f(h.w));
  *reinterpret_cast<ushort4*>(xm0hi + (size_t)t * 1024 + h4) = h;
  *reinterpret_cast<ushort4*>(xm0lo + (size_t)t * 1024 + h4) = l;
}

// ---------------------------------------------------------------- kernel A2f
__global__ __launch_bounds__(256) void kA2f(
    const u16* __restrict__ xm0hi, const u16* __restrict__ xm0lo,
    const u16* __restrict__ x0whi, const u16* __restrict__ x0wlo,
    float* __restrict__ t160) {
  __shared__ __align__(16) u16 sAh[128 * 64];
  __shared__ __align__(16) u16 sAl[128 * 64];
  __shared__ __align__(16) u16 sBh[128 * 64];
  __shared__ __align__(16) u16 sBl[128 * 64];
  const int mt = blockIdx.x, nt = blockIdx.y;
  const int ncols = nt ? 32 : 128;
  const int wcol0 = nt * 128;
  const u16* Ah = xm0hi + (size_t)mt * 128 * 1024;
  const u16* Al = xm0lo + (size_t)mt * 128 * 1024;
  const u16* Bh = x0whi + (size_t)wcol0 * 1024;
  const u16* Bl = x0wlo + (size_t)wcol0 * 1024;
  const int tid = threadIdx.x;
  const int lane = tid & 63;
  const int wv = tid >> 6;
  const int wr = wv >> 1, wc = wv & 1;
  const int srow = wv * 32;
  f32x4 acc[4][4];
  #pragma unroll
  for (int i = 0; i < 4; ++i)
    #pragma unroll
    for (int j = 0; j < 4; ++j) acc[i][j] = {0.f, 0.f, 0.f, 0.f};

  for (int k0 = 0; k0 < 1024; k0 += 64) {
    #pragma unroll
    for (int c = 0; c < 4; ++c) {
      const int s8 = srow + c * 8;
      stage_swz(Ah, sAh, s8, k0, lane);
      stage_swz(Al, sAl, s8, k0, lane);
      {
        const int rr = (s8 + (lane >> 3)) & (ncols - 1);
        const int ss = (lane & 7) ^ ((lane >> 3) & 7);
        __builtin_amdgcn_global_load_lds(
            (gu32*)(const void*)(Bh + (size_t)rr * 1024 + k0 + ss * 8),
            (lu32*)(void*)(sBh + s8 * 64), 16, 0, 0);
        __builtin_amdgcn_global_load_lds(
            (gu32*)(const void*)(Bl + (size_t)rr * 1024 + k0 + ss * 8),
            (lu32*)(void*)(sBl + s8 * 64), 16, 0, 0);
      }
    }
    __syncthreads();
    #pragma unroll
    for (int kk = 0; kk < 2; ++kk) {
      const int sl = kk * 4 + (lane >> 4);
      short8 ah[4], al[4], bh[4], bl[4];
      #pragma unroll
      for (int m = 0; m < 4; ++m) {
        int row = wr * 64 + m * 16 + (lane & 15);
        ah[m] = read_swz(sAh, row, sl);
        al[m] = read_swz(sAl, row, sl);
      }
      #pragma unroll
      for (int j = 0; j < 4; ++j) {
        int row = wc * 64 + j * 16 + (lane & 15);
        bh[j] = read_swz(sBh, row, sl);
        bl[j] = read_swz(sBl, row, sl);
      }
      #pragma unroll
      for (int m = 0; m < 4; ++m)
        #pragma unroll
        for (int j = 0; j < 4; ++j) {
          acc[m][j] = __builtin_amdgcn_mfma_f32_16x16x32_bf16(ah[m], bh[j], acc[m][j], 0, 0, 0);
          acc[m][j] = __builtin_amdgcn_mfma_f32_16x16x32_bf16(al[m], bh[j], acc[m][j], 0, 0, 0);
          acc[m][j] = __builtin_amdgcn_mfma_f32_16x16x32_bf16(ah[m], bl[j], acc[m][j], 0, 0, 0);
        }
    }
    __syncthreads();
  }
  #pragma unroll
  for (int m = 0; m < 4; ++m)
    #pragma unroll
    for (int r = 0; r < 4; ++r) {
      const int row = wr * 64 + m * 16 + (lane >> 4) * 4 + r;
      #pragma unroll
      for (int j = 0; j < 4; ++j) {
        const int col = wc * 64 + j * 16 + (lane & 15);
        if (col < ncols)
          t160[(size_t)(mt * 128 + row) * 160 + wcol0 + col] = tanhf(acc[m][j][r]);
      }
    }
}

// ---------------------------------------------------------------- kernel A2m5
__global__ __launch_bounds__(256) void kA2m5(
    const float* __restrict__ t160G, const float* __restrict__ x2_w,
    const float* __restrict__ x_bias, const float* __restrict__ xm0,
    const float* __restrict__ delta, const float* __restrict__ x0_mu,
    u16* __restrict__ xmhi, u16* __restrict__ xmlo, float* __restrict__ xmw) {
  __shared__ float As[64 * 33];
  __shared__ float Ws[64 * 33];
  const int tid = threadIdx.x;
  const int m0 = blockIdx.x * 64, h0 = blockIdx.y * 64, n = blockIdx.z;
  #pragma unroll
  for (int c = 0; c < 2; ++c) {
    int r = c * 32 + (tid >> 3);
    int col = (tid & 7) * 4;
    float4 a4 = ld4(t160G + (size_t)(m0 + r) * 160 + n * 32 + col);
    As[r * 33 + col + 0] = a4.x; As[r * 33 + col + 1] = a4.y;
    As[r * 33 + col + 2] = a4.z; As[r * 33 + col + 3] = a4.w;
    float4 w4 = ld4(x2_w + (size_t)(h0 + r) * 160 + n * 32 + col);
    Ws[r * 33 + col + 0] = w4.x; Ws[r * 33 + col + 1] = w4.y;
    Ws[r * 33 + col + 2] = w4.z; Ws[r * 33 + col + 3] = w4.w;
  }
  __syncthreads();
  const int rm = (tid >> 4) * 4, cn = (tid & 15) * 4;
  float acc[4][4] = {};
  #pragma unroll
  for (int kk = 0; kk < 32; ++kk) {
    float a[4], w[4];
    #pragma unroll
    for (int i = 0; i < 4; ++i) a[i] = As[(rm + i) * 33 + kk];
    #pragma unroll
    for (int j = 0; j < 4; ++j) w[j] = Ws[(cn + j) * 33 + kk];
    #pragma unroll
    for (int i = 0; i < 4; ++i)
      #pragma unroll
      for (int j = 0; j < 4; ++j) acc[i][j] += a[i] * w[j];
  }
  const float4 b4 = ld4(x_bias + n * 1024 + h0 + cn);
  const float4 mu4 = ld4(x0_mu + h0 + cn);
  const int pi = (n == 0) ? 0 : (n == 2) ? 1 : (n == 3) ? 2 : 3;
  #pragma unroll
  for (int i = 0; i < 4; ++i) {
    const size_t rowo = (size_t)(m0 + rm + i) * 1024 + h0 + cn;
    float4 xm4 = ld4(xm0 + rowo);
    float4 dv4 = ld4(delta + rowo);
    float4 o;
    o.x = xm4.x + dv4.x * (acc[i][0] + b4.x - mu4.x);
    o.y = xm4.y + dv4.y * (acc[i][1] + b4.y - mu4.y);
    o.z = xm4.z + dv4.z * (acc[i][2] + b4.z - mu4.z);
    o.w = xm4.w + dv4.w * (acc[i][3] + b4.w - mu4.w);
    if (n == 1) {
      st4(xmw + rowo, o);
    } else {
      ushort4 h;
      h.x = f2bf(o.x); h.y = f2bf(o.y); h.z = f2bf(o.z); h.w = f2bf(o.w);
      *reinterpret_cast<ushort4*>(xmhi + (size_t)pi * Tc * 1024 + rowo) = h;
      if (n != 4) {
        ushort4 l;
        l.x = f2bf(o.x - bf2f(h.x)); l.y = f2bf(o.y - bf2f(h.y));
        l.z = f2bf(o.z - bf2f(h.z)); l.w = f2bf(o.w - bf2f(h.w));
        *reinterpret_cast<ushort4*>(xmlo + (size_t)pi * Tc * 1024 + rowo) = l;
      }
    }
  }
}

// ---------------------------------------------------------------- kernel WL
__global__ __launch_bounds__(256) void kWL(
    const float* __restrict__ xmw, const float* __restrict__ w_w1,
    float* __restrict__ yw) {
  __shared__ float As[32 * 33];
  __shared__ float Ws[64 * 33];
  const int tid = threadIdx.x;
  const int t0 = blockIdx.x * 32;
  const int rg = tid >> 5;
  const int cg = tid & 31;
  float acc[4][2] = {};
  for (int k0 = 0; k0 < 1024; k0 += 32) {
    __syncthreads();
    {
      int r = tid >> 3, c4 = (tid & 7) * 4;
      float4 a4 = ld4(xmw + (size_t)(t0 + r) * 1024 + k0 + c4);
      As[r * 33 + c4 + 0] = a4.x; As[r * 33 + c4 + 1] = a4.y;
      As[r * 33 + c4 + 2] = a4.z; As[r * 33 + c4 + 3] = a4.w;
    }
    #pragma unroll
    for (int c = 0; c < 2; ++c) {
      int r = c * 32 + (tid >> 3), c4 = (tid & 7) * 4;
      float4 w4 = ld4(w_w1 + (size_t)r * 1024 + k0 + c4);
      Ws[r * 33 + c4 + 0] = w4.x; Ws[r * 33 + c4 + 1] = w4.y;
      Ws[r * 33 + c4 + 2] = w4.z; Ws[r * 33 + c4 + 3] = w4.w;
    }
    __syncthreads();
    #pragma unroll
    for (int kk = 0; kk < 32; ++kk) {
      float a[4];
      #pragma unroll
      for (int i = 0; i < 4; ++i) a[i] = As[(rg * 4 + i) * 33 + kk];
      float w0 = Ws[cg * 33 + kk], w1 = Ws[(cg + 32) * 33 + kk];
      #pragma unroll
      for (int i = 0; i < 4; ++i) { acc[i][0] += a[i] * w0; acc[i][1] += a[i] * w1; }
    }
  }
  #pragma unroll
  for (int i = 0; i < 4; ++i) {
    yw[(size_t)(t0 + rg * 4 + i) * 64 + cg]      = tanhf(acc[i][0]);
    yw[(size_t)(t0 + rg * 4 + i) * 64 + cg + 32] = tanhf(acc[i][1]);
  }
}

// -------------------------------------------- bf16x3 MFMA GEMM (R6/R8 version)
__global__ __launch_bounds__(256) void kB(
    const u16* __restrict__ xmhi, const u16* __restrict__ xmlo,
    const u16* __restrict__ Whi, const u16* __restrict__ Wlo,
    float* __restrict__ rG, float* __restrict__ kG,
    float* __restrict__ vG, u16* __restrict__ gG) {
  __shared__ __align__(16) u16 sAh[128 * 64];
  __shared__ __align__(16) u16 sAl[128 * 64];
  __shared__ __align__(16) u16 sBh[128 * 64];
  __shared__ __align__(16) u16 sBl[128 * 64];
  const int mt = blockIdx.x, nt = blockIdx.y;
  int plane, col0, ldc;
  float* Cf = nullptr;
  u16* Cb = nullptr;
  bool three = true;
  if (nt < 4)       { plane = 0; Cf = rG; ldc = 512;  col0 = nt * 128; }
  else if (nt < 8)  { plane = 1; Cf = kG; ldc = 512;  col0 = (nt - 4) * 128; }
  else if (nt < 16) { plane = 2; Cf = vG; ldc = 1024; col0 = (nt - 8) * 128; }
  else              { plane = 3; Cb = gG; ldc = 1024; col0 = (nt - 16) * 128; three = false; }
  const u16* Ah = xmhi + ((size_t)plane * Tc + (size_t)mt * 128) * 1024;
  const u16* Al = xmlo + ((size_t)plane * Tc + (size_t)mt * 128) * 1024;
  const u16* Bh = Whi + (size_t)nt * 128 * 1024;
  const u16* Bl = Wlo + (size_t)nt * 128 * 1024;

  const int tid = threadIdx.x;
  const int lane = tid & 63;
  const int wv = tid >> 6;
  const int wr = wv >> 1, wc = wv & 1;
  const int srow = wv * 32;
  f32x4 acc[4][4];
  #pragma unroll
  for (int i = 0; i < 4; ++i)
    #pragma unroll
    for (int j = 0; j < 4; ++j) acc[i][j] = {0.f, 0.f, 0.f, 0.f};

  for (int k0 = 0; k0 < 1024; k0 += 64) {
    #pragma unroll
    for (int c = 0; c < 4; ++c) {
      const int s8 = srow + c * 8;
      stage_swz(Ah, sAh, s8, k0, lane);
      stage_swz(Bh, sBh, s8, k0, lane);
      if (three) {
        stage_swz(Al, sAl, s8, k0, lane);
        stage_swz(Bl, sBl, s8, k0, lane);
      }
    }
    __syncthreads();
    #pragma unroll
    for (int kk = 0; kk < 2; ++kk) {
      const int sl = kk * 4 + (lane >> 4);
      short8 ah[4], al[4], bh[4], bl[4];
      #pragma unroll
      for (int m = 0; m < 4; ++m) {
        int row = wr * 64 + m * 16 + (lane & 15);
        ah[m] = read_swz(sAh, row, sl);
        if (three) al[m] = read_swz(sAl, row, sl);
      }
      #pragma unroll
      for (int j = 0; j < 4; ++j) {
        int row = wc * 64 + j * 16 + (lane & 15);
        bh[j] = read_swz(sBh, row, sl);
        if (three) bl[j] = read_swz(sBl, row, sl);
      }
      #pragma unroll
      for (int m = 0; m < 4; ++m)
        #pragma unroll
        for (int j = 0; j < 4; ++j) {
          acc[m][j] = __builtin_amdgcn_mfma_f32_16x16x32_bf16(ah[m], bh[j], acc[m][j], 0, 0, 0);
          if (three) {
            acc[m][j] = __builtin_amdgcn_mfma_f32_16x16x32_bf16(al[m], bh[j], acc[m][j], 0, 0, 0);
            acc[m][j] = __builtin_amdgcn_mfma_f32_16x16x32_bf16(ah[m], bl[j], acc[m][j], 0, 0, 0);
          }
        }
    }
    __syncthreads();
  }
  #pragma unroll
  for (int m = 0; m < 4; ++m)
    #pragma unroll
    for (int r = 0; r < 4; ++r) {
      const int row = wr * 64 + m * 16 + (lane >> 4) * 4 + r;
      #pragma unroll
      for (int j = 0; j < 4; ++j) {
        const int col = wc * 64 + j * 16 + (lane & 15);
        float v = acc[m][j][r];
        if (Cf) Cf[(size_t)(mt * 128 + row) * ldc + col0 + col] = v;
        else    Cb[(size_t)(mt * 128 + row) * ldc + col0 + col] = f2bf(v);
      }
    }
}

// ---------------------------------------------------------------- kernel C
__global__ __launch_bounds__(256) void kC(
    const float* __restrict__ yw, const float* __restrict__ w_w2,
    const float* __restrict__ w_b2, float* __restrict__ wfin) {
  __shared__ float th[32 * 68];
  const int tid = threadIdx.x;
  const int t0 = blockIdx.x * 32;
  for (int idx = tid; idx < 32 * 64; idx += 256) {
    int i = idx >> 6, j = idx & 63;
    th[i * 68 + j] = yw[(size_t)(t0 + i) * 64 + j];
  }
  __syncthreads();
  const int c = blockIdx.y * 256 + tid;
  float acc[32] = {};
  const float* w2 = w_w2 + (size_t)c * 64;
  for (int k = 0; k < 64; k += 4) {
    float4 wv = ld4(w2 + k);
    #pragma unroll
    for (int i = 0; i < 32; ++i) {
      float4 t4 = ld4(th + i * 68 + k);
      acc[i] += t4.x * wv.x + t4.y * wv.y + t4.z * wv.z + t4.w * wv.w;
    }
  }
  const float b = w_b2[c];
  #pragma unroll
  for (int i = 0; i < 32; ++i)
    wfin[(size_t)(t0 + i) * 512 + c] = -__expf(acc[i] + b);
}

// ---------------------------------------------------------------- kernel D1 v6
// R8 v3 numerics; wfin and v staged via global_load_lds (R9-proven addressing)
// to cut ~24 staged VGPRs. r/k stay in regs. NO launch_bounds min-wave cap.
__global__ __launch_bounds__(512) void kD1(
    const float* __restrict__ rG, const float* __restrict__ kG,
    const float* __restrict__ vG, const float* __restrict__ wfin,
    const float* __restrict__ bonus, float* __restrict__ wkvG,
    float* __restrict__ decayG, float* __restrict__ qeG, float* __restrict__ oG) {
  __shared__ __align__(16) float smem[4224 + 4224 + 8192 + 1056 + 64];
  float* kwT   = smem;            // [128][33]
  float* qeT   = kwT + 4224;      // [128][33]
  float* vl    = qeT + 4224;      // [32][256]
  float* wcl   = vl;              // [32][128] alias (dead before vl staged)
  float* Al    = vl + 8192;       // [32][33]
  float* diag2 = Al + 1056;       // [32][2]
  const int tid = threadIdx.x;
  const int lane = tid & 63;
  const int wv8 = tid >> 6;       // wave 0..7
  const int bid = blockIdx.x;
  const int nc = bid & 63, h = (bid >> 6) & 3, b = bid >> 8;
  const int tb = b * Lc + nc * 32;

  // front-load r/k into registers (needed for elementwise + diag)
  float rreg[8], kreg[8];
  #pragma unroll
  for (int it = 0; it < 8; ++it) {
    int idx = it * 512 + tid;
    int c = idx >> 7, d = idx & 127;
    rreg[it] = rG[(size_t)(tb + c) * 512 + h * 128 + d];
    kreg[it] = kG[(size_t)(tb + c) * 512 + h * 128 + d];
  }
  const float ureg = bonus[h * 128 + (tid & 127)];

  // stage wfin -> wcl[32][128] via global_load_lds (R9-proven pattern)
  #pragma unroll
  for (int g2 = 0; g2 < 2; ++g2) {
    const int c0 = wv8 * 4 + g2 * 2;
    const int cc = c0 + (lane >> 5);
    __builtin_amdgcn_global_load_lds(
        (gu32*)(const void*)(wfin + (size_t)(tb + cc) * 512 + h * 128 + (lane & 31) * 4),
        (lu32*)(void*)(wcl + c0 * 128), 16, 0, 0);
  }
  __syncthreads();  // B1 (drains wfin staging)
  // cumsum along chunk dim
  if (tid < 128) {
    const int d = tid;
    float wv_[32];
    #pragma unroll
    for (int c = 0; c < 32; ++c) wv_[c] = wcl[c * 128 + d];
    float run = 0.f;
    #pragma unroll
    for (int c = 0; c < 32; ++c) { run += wv_[c]; wcl[c * 128 + d] = run; }
  }
  __syncthreads();  // B2
  // elementwise from regs + wave-parallel diag (R8 numerics)
  #pragma unroll
  for (int it = 0; it < 8; ++it) {
    int idx = it * 512 + tid;
    int c = idx >> 7, d = idx & 127;
    int t = tb + c;
    float q = rreg[it];
    float k = kreg[it];
    float wcc = wcl[c * 128 + d];
    float wcp = (c > 0) ? wcl[(c - 1) * 128 + d] : 0.f;
    float wlast = wcl[31 * 128 + d];
    float qe = q * __expf(wcp);
    qeT[d * 33 + c] = q * __expf(wcp - wlast);
    kwT[d * 33 + c] = k * __expf(wlast - wcc);
    qeG[(size_t)t * 512 + h * 128 + d] = qe;
    if (c == 31) decayG[(size_t)bid * 128 + d] = __expf(wlast);
    float dv = q * k * ureg;
    #pragma unroll
    for (int m = 1; m < 64; m <<= 1) dv += __shfl_xor(dv, m, 64);
    if ((tid & 63) == 0) diag2[c * 2 + ((tid >> 6) & 1)] = dv;
  }
  __syncthreads();  // B3 (wcl reads done; qeT/kwT/diag2 visible)
  // stage v -> vl via global_load_lds (overwrites wcl); hides under A-phase.
  #pragma unroll
  for (int c8 = 0; c8 < 4; ++c8) {
    const int c = wv8 * 4 + c8;
    __builtin_amdgcn_global_load_lds(
        (gu32*)(const void*)(vG + (size_t)(tb + c) * 1024 + h * 256 + lane * 4),
        (lu32*)(void*)(vl + c * 256), 16, 0, 0);
  }
  {  // A[i][j] from qeT/kwT (independent of vl)
    const int j = tid & 31, i2 = tid >> 5;
    float a0 = 0.f, a1 = 0.f;
    for (int d = 0; d < 128; ++d) {
      float kv = kwT[d * 33 + j];
      a0 += qeT[d * 33 + i2] * kv;
      a1 += qeT[d * 33 + i2 + 16] * kv;
    }
    float dg0 = diag2[i2 * 2] + diag2[i2 * 2 + 1];
    float dg1 = diag2[(i2 + 16) * 2] + diag2[(i2 + 16) * 2 + 1];
    Al[i2 * 33 + j] = (j < i2) ? a0 : ((j == i2) ? dg0 : 0.f);
    Al[(i2 + 16) * 33 + j] = (j < i2 + 16) ? a1 : ((j == i2 + 16) ? dg1 : 0.f);
  }
  __syncthreads();  // B4 (vl staged + Al visible)
  const int pid = tid & 63, wvx = tid >> 6;
  const int p4 = pid * 4;
  {  // wkv[d][p] = sum_c kv[c][d]*v[c][p]
    float* wkvB = wkvG + (size_t)bid * (128 * 256);
    #pragma unroll
    for (int pp = 0; pp < 2; ++pp) {
      const int d0 = pp * 64 + wvx * 8;
      float4 acc[8];
      #pragma unroll
      for (int q = 0; q < 8; ++q) acc[q] = make_float4(0, 0, 0, 0);
      for (int c = 0; c < 32; ++c) {
        float4 v4 = ld4(vl + c * 256 + p4);
        #pragma unroll
        for (int q = 0; q < 8; ++q) {
          float s = kwT[(d0 + q) * 33 + c];
          acc[q].x += v4.x * s; acc[q].y += v4.y * s;
          acc[q].z += v4.z * s; acc[q].w += v4.w * s;
        }
      }
      #pragma unroll
      for (int q = 0; q < 8; ++q)
        st4(wkvB + (size_t)(d0 + q) * 256 + p4, acc[q]);
    }
  }
  {  // o_intra = A @ v
    float4 acc[4];
    #pragma unroll
    for (int q = 0; q < 4; ++q) acc[q] = make_float4(0, 0, 0, 0);
    for (int c = 0; c < 32; ++c) {
      float4 v4 = ld4(vl + c * 256 + p4);
      #pragma unroll
      for (int q = 0; q < 4; ++q) {
        float a = Al[(wvx * 4 + q) * 33 + c];
        acc[q].x += v4.x * a; acc[q].y += v4.y * a;
        acc[q].z += v4.z * a; acc[q].w += v4.w * a;
      }
    }
    #pragma unroll
    for (int q = 0; q < 4; ++q)
      st4(oG + (size_t)(tb + wvx * 4 + q) * 1024 + h * 256 + p4, acc[q]);
  }
}

// ---------------------------------------------------------------- kernel D2 (R8)
__global__ __launch_bounds__(256) void kD2(float* __restrict__ wkvG,
                                           const float* __restrict__ decayG) {
  const int wvid = (blockIdx.x * 256 + threadIdx.x) >> 6;  // 0..2047
  const int lane = threadIdx.x & 63;
  const int half = wvid & 1;
  const int d = (wvid >> 1) & 127;
  const int bh = wvid >> 8;
  const int p2 = half * 128 + lane * 2;
  float* base = wkvG + ((size_t)bh * 64 * 128 + d) * 256 + p2;
  const float* dbase = decayG + (size_t)bh * 64 * 128 + d;
  float2 kvb[4];
  float decb[4];
  #pragma unroll
  for (int i = 0; i < 4; ++i) {
    kvb[i] = ld2(base + (size_t)i * 32768);
    decb[i] = dbase[(size_t)i * 128];
  }
  float2 S = make_float2(0.f, 0.f);
  #pragma unroll
  for (int nc = 0; nc < 64; ++nc) {
    const int sl = nc & 3;
    float2 kv = kvb[sl];
    float dec = decb[sl];
    if (nc + 4 < 64) {
      kvb[sl] = ld2(base + (size_t)(nc + 4) * 32768);
      decb[sl] = dbase[(size_t)(nc + 4) * 128];
    }
    st2(base + (size_t)nc * 32768, S);
    S.x = S.x * dec + kv.x;
    S.y = S.y * dec + kv.y;
  }
}

// ---------------------------------------------------------------- kernel D3 (R8)
__global__ __launch_bounds__(256) void kD3(
    const float* __restrict__ qeG, const float* __restrict__ wkvG,
    float* __restrict__ oG) {
  __shared__ float qel[32 * 129];
  const int tid = threadIdx.x;
  const int bid = blockIdx.x;
  const int nc = bid & 63, h = (bid >> 6) & 3, b = bid >> 8;
  const int tb = b * Lc + nc * 32;
  for (int it = 0; it < 16; ++it) {
    int idx = it * 256 + tid;
    int c = idx >> 7, d = idx & 127;
    qel[c * 129 + d] = qeG[(size_t)(tb + c) * 512 + h * 128 + d];
  }
  __syncthreads();
  const int pid = tid & 63, wvx = tid >> 6;
  const int p4 = pid * 4;
  const float* Sb = wkvG + (size_t)bid * (128 * 256);
  float4 acc[8];
  #pragma unroll
  for (int q = 0; q < 8; ++q) acc[q] = make_float4(0, 0, 0, 0);
  for (int d = 0; d < 128; ++d) {
    float4 s4 = ld4(Sb + (size_t)d * 256 + p4);
    #pragma unroll
    for (int q = 0; q < 8; ++q) {
      float qv = qel[(wvx * 8 + q) * 129 + d];
      acc[q].x += s4.x * qv; acc[q].y += s4.y * qv;
      acc[q].z += s4.z * qv; acc[q].w += s4.w * qv;
    }
  }
  #pragma unroll
  for (int q = 0; q < 8; ++q) {
    float* op = oG + (size_t)(tb + wvx * 8 + q) * 1024 + h * 256 + p4;
    float4 cur = ld4(op);
    cur.x += acc[q].x; cur.y += acc[q].y; cur.z += acc[q].z; cur.w += acc[q].w;
    st4(op, cur);
  }
}

// ---------------------------------------------------------------- kernel E (R8)
__global__ __launch_bounds__(256) void kE(
    const float* __restrict__ oG, const u16* __restrict__ gG,
    const float* __restrict__ gn_w, const float* __restrict__ gn_b,
    u16* __restrict__ gate) {
  const int t = blockIdx.x;
  const int h = threadIdx.x >> 6, lane = threadIdx.x & 63;
  const int p4 = lane * 4;
  const int vd = h * 256 + p4;
  float4 v = ld4(oG + (size_t)t * 1024 + vd);
  float s = v.x + v.y + v.z + v.w;
  float ss = v.x * v.x + v.y * v.y + v.z * v.z + v.w * v.w;
  for (int m = 1; m < 64; m <<= 1) {
    s += __shfl_xor(s, m, 64);
    ss += __shfl_xor(ss, m, 64);
  }
  const float mean = s * (1.f / 256.f);
  const float var = ss * (1.f / 256.f) - mean * mean;
  const float rs = rsqrtf(var + 1e-5f);
  float4 gw = ld4(gn_w + vd), gb = ld4(gn_b + vd);
  float4 on;
  on.x = (v.x - mean) * rs * gw.x + gb.x;
  on.y = (v.y - mean) * rs * gw.y + gb.y;
  on.z = (v.z - mean) * rs * gw.z + gb.z;
  on.w = (v.w - mean) * rs * gw.w + gb.w;
  ushort4 g4 = *reinterpret_cast<const ushort4*>(gG + (size_t)t * 1024 + vd);
  float gx = bf2f(g4.x), gy = bf2f(g4.y), gz = bf2f(g4.z), gw_ = bf2f(g4.w);
  float4 sw;
  sw.x = gx / (1.f + __expf(-gx));
  sw.y = gy / (1.f + __expf(-gy));
  sw.z = gz / (1.f + __expf(-gz));
  sw.w = gw_ / (1.f + __expf(-gw_));
  ushort4 ob;
  ob.x = f2bf(on.x * sw.x); ob.y = f2bf(on.y * sw.y);
  ob.z = f2bf(on.z * sw.z); ob.w = f2bf(on.w * sw.w);
  *reinterpret_cast<ushort4*>(gate + (size_t)t * 1024 + vd) = ob;
}

// ---------------------------------------------------------------- kernel F (BM=64)
__global__ __launch_bounds__(256) void kF(
    const u16* __restrict__ gate, const u16* __restrict__ owb,
    float* __restrict__ out) {
  __shared__ __align__(16) u16 Abuf[64 * 64];
  __shared__ __align__(16) u16 Bbuf[128 * 64];
  const int mt = blockIdx.x, nt = blockIdx.y;   // grid (64, 8)
  const u16* A = gate + (size_t)mt * 64 * 1024;
  const u16* W = owb + (size_t)nt * 128 * 1024;
  float* C = out + (size_t)mt * 64 * 1024 + nt * 128;
  const int tid = threadIdx.x;
  const int lane = tid & 63;
  const int wv = tid >> 6;        // 0..3 -> column block wv*32
  f32x4 acc[4][2];
  #pragma unroll
  for (int i = 0; i < 4; ++i)
    #pragma unroll
    for (int j = 0; j < 2; ++j) acc[i][j] = {0.f, 0.f, 0.f, 0.f};
  for (int k0 = 0; k0 < 1024; k0 += 64) {
    #pragma unroll
    for (int c = 0; c < 2; ++c) stage_swz(A, Abuf, wv * 16 + c * 8, k0, lane);
    #pragma unroll
    for (int c = 0; c < 4; ++c) stage_swz(W, Bbuf, wv * 32 + c * 8, k0, lane);
    __syncthreads();
    #pragma unroll
    for (int kk = 0; kk < 2; ++kk) {
      const int sl = kk * 4 + (lane >> 4);
      short8 af[4], bfr[2];
      #pragma unroll
      for (int m = 0; m < 4; ++m)
        af[m] = read_swz(Abuf, m * 16 + (lane & 15), sl);
      #pragma unroll
      for (int j = 0; j < 2; ++j)
        bfr[j] = read_swz(Bbuf, wv * 32 + j * 16 + (lane & 15), sl);
      #pragma unroll
      for (int m = 0; m < 4; ++m)
        #pragma unroll
        for (int j = 0; j < 2; ++j)
          acc[m][j] = __builtin_amdgcn_mfma_f32_16x16x32_bf16(af[m], bfr[j], acc[m][j], 0, 0, 0);
    }
    __syncthreads();
  }
  #pragma unroll
  for (int m = 0; m < 4; ++m)
    #pragma unroll
    for (int r = 0; r < 4; ++r) {
      const int row = m * 16 + (lane >> 4) * 4 + r;
      #pragma unroll
      for (int j = 0; j < 2; ++j) {
        const int col = wv * 32 + j * 16 + (lane & 15);
        C[(size_t)row * 1024 + col] = acc[m][j][r];
      }
    }
}

}  // namespace

extern "C" void kernel_launch(void* const* d_in, const int* in_sizes, int n_in,
                              void* d_out, int out_size, void* d_ws, size_t ws_size,
                              hipStream_t stream) {
  (void)in_sizes; (void)n_in; (void)out_size;
  if (ws_size < WS_NEED) return;

  const float* x      = (const float*)d_in[0];
  const float* x0_mu  = (const float*)d_in[1];
  const float* x0_w   = (const float*)d_in[2];
  const float* x2_w   = (const float*)d_in[3];
  const float* x_bias = (const float*)d_in[4];
  const float* r_w    = (const float*)d_in[5];
  const float* w_w1   = (const float*)d_in[6];
  const float* w_w2   = (const float*)d_in[7];
  const float* w_b2   = (const float*)d_in[8];
  const float* k_w    = (const float*)d_in[9];
  const float* v_w    = (const float*)d_in[10];
  const float* g_w    = (const float*)d_in[11];
  const float* bonus  = (const float*)d_in[12];
  const float* gn_w   = (const float*)d_in[13];
  const float* gn_b   = (const float*)d_in[14];
  const float* o_w    = (const float*)d_in[15];
  float* out = (float*)d_out;
  char* ws = (char*)d_ws;

  float* wkvG   = (float*)(ws + OFF_WKV);
  float* xm0    = (float*)(ws + OFF_XM0);
  float* delta  = (float*)(ws + OFF_DELTA);
  float* t160   = (float*)(ws + OFF_T160);
  float* xmw    = (float*)(ws + OFF_XMW);
  float* yw     = (float*)(ws + OFF_YW);
  u16*   x0whi  = (u16*)(ws + OFF_X0WHI);
  u16*   x0wlo  = (u16*)(ws + OFF_X0WLO);
  u16*   xm0hi  = (u16*)(ws + OFF_XM0HI);
  u16*   xm0lo  = (u16*)(ws + OFF_XM0LO);
  u16*   xmhi   = (u16*)(ws + OFF_XMHI);
  float* wfin   = (float*)(ws + OFF_WFIN);
  u16*   gate   = (u16*)(ws + OFF_GATE);
  u16*   xmlo   = (u16*)(ws + OFF_XMLO);
  float* qeG    = (float*)(ws + OFF_QE);
  float* oG     = (float*)(ws + OFF_OO);
  u16*   Whi    = (u16*)(ws + OFF_WHI);
  u16*   Wlo    = (u16*)(ws + OFF_WLO);
  float* decayG = (float*)(ws + OFF_DECAY);
  u16*   owb    = (u16*)(ws + OFF_OWB);
  float* rG     = (float*)(ws + OFF_RG);
  float* kG     = (float*)(ws + OFF_KG);
  float* vG     = (float*)(ws + OFF_VG);
  u16*   gG     = (u16*)(ws + OFF_GG);

  kW   <<<dim3(4256),        dim3(256), 0, stream>>>(r_w, k_w, v_w, g_w, o_w, x0_w,
                                                     Whi, Wlo, owb, x0whi, x0wlo);
  kA1  <<<dim3(4096),        dim3(256), 0, stream>>>(x, x0_mu, xm0, delta, xm0hi, xm0lo);
  kA2f <<<dim3(32, 2),       dim3(256), 0, stream>>>(xm0hi, xm0lo, x0whi, x0wlo, t160);
  kA2m5<<<dim3(64, 16, 5),   dim3(256), 0, stream>>>(t160, x2_w, x_bias, xm0, delta,
                                                     x0_mu, xmhi, xmlo, xmw);
  kWL  <<<dim3(128),         dim3(256), 0, stream>>>(xmw, w_w1, yw);
  kB   <<<dim3(32, 24),      dim3(256), 0, stream>>>(xmhi, xmlo, Whi, Wlo, rG, kG, vG, gG);
  kC   <<<dim3(128, 2),      dim3(256), 0, stream>>>(yw, w_w2, w_b2, wfin);
  kD1  <<<dim3(512),         dim3(512), 0, stream>>>(rG, kG, vG, wfin, bonus,
                                                     wkvG, decayG, qeG, oG);
  kD2  <<<dim3(512),         dim3(256), 0, stream>>>(wkvG, decayG);
  kD3  <<<dim3(512),         dim3(256), 0, stream>>>(qeG, wkvG, oG);
  kE   <<<dim3(4096),        dim3(256), 0, stream>>>(oG, gG, gn_w, gn_b, gate);
  kF   <<<dim3(64, 8),       dim3(256), 0, stream>>>(gate, owb, out);
}

// Round 12
// 355.394 us; speedup vs baseline: 1.7501x; 1.1415x over previous
//
#include <hip/hip_runtime.h>

// RWKV6Attention forward — round 12: ALL low-precision GEMMs switch to
// single-pass FP16 MFMA (10 mantissa bits -> predicted GEMM error ~5e-3,
// replaces bf16x3's 3xMFMA + 2x staging). kB: 32KB LDS, m97-equivalent
// schedule. kD1/kD2/kD3/kE = proven R8 versions. D-chain stays f32.

#define DEVI __device__ __forceinline__

namespace {

typedef unsigned short u16;
typedef unsigned int u32;
typedef __attribute__((ext_vector_type(8))) _Float16 f16x8;  // 4 VGPRs
typedef __attribute__((ext_vector_type(4))) float f32x4;

typedef __attribute__((address_space(1))) const u32 gu32;
typedef __attribute__((address_space(3))) u32 lu32;

constexpr int Lc = 2048;
constexpr int Tc = 4096;   // B*L

// ---- workspace layout (byte offsets), lifetime-safe aliasing (R8 map; the
// former lo-plane regions are simply unused now).
constexpr size_t OFF_WKV   = 0;
constexpr size_t OFF_XM0   = 0;
constexpr size_t OFF_DELTA = 16777216;
constexpr size_t OFF_T160  = 33554432;
constexpr size_t OFF_XMW   = 36175872;
constexpr size_t OFF_YW    = 52953088;
constexpr size_t OFF_X0WF  = 54001664;     // f16 [160][1024]
constexpr size_t OFF_XMF   = 67108864;     // f16 [4][T][1024] (kA2m5 -> kB)
constexpr size_t OFF_XM0F  = 67108864;     //   f16 [T][1024] (kA1 -> kA2f)
constexpr size_t OFF_WFIN  = 67108864;     //   f32 [T][512]  (kC -> kD1, after kB)
constexpr size_t OFF_GATE  = 75497472;     //   f16 [T][1024] (kE -> kF)
constexpr size_t OFF_QE    = 100663296;
constexpr size_t OFF_OO    = 109051904;
constexpr size_t OFF_WF    = 125829120;    // f16 [3072][1024]
constexpr size_t OFF_DECAY = 132120576;
constexpr size_t OFF_OWB   = 136314880;    // f16 [1024][1024]
constexpr size_t OFF_RG    = 138412032;
constexpr size_t OFF_KG    = 146800640;
constexpr size_t OFF_VG    = 155189248;
constexpr size_t OFF_GG    = 171966464;    // f16 [T][1024]
constexpr size_t WS_NEED   = 180355072;

DEVI float4 ld4(const float* p) { return *reinterpret_cast<const float4*>(p); }
DEVI void   st4(float* p, float4 v) { *reinterpret_cast<float4*>(p) = v; }
DEVI float2 ld2(const float* p) { return *reinterpret_cast<const float2*>(p); }
DEVI void   st2(float* p, float2 v) { *reinterpret_cast<float2*>(p) = v; }
DEVI u16 f2h(float f) { _Float16 h = (_Float16)f; return *(u16*)&h; }
DEVI float h2f(u16 u) { _Float16 h = *(_Float16*)&u; return (float)h; }

// ---- BK=64 swizzled staging (source-side XOR; linear LDS dest)
DEVI void stage_swz(const u16* __restrict__ src, u16* __restrict__ dstBase,
                    int srow8, int k0, int lane) {
  const int rr = srow8 + (lane >> 3);
  const int ss = (lane & 7) ^ ((lane >> 3) & 7);
  __builtin_amdgcn_global_load_lds(
      (gu32*)(const void*)(src + (size_t)rr * 1024 + k0 + ss * 8),
      (lu32*)(void*)(dstBase + srow8 * 64), 16, 0, 0);
}
DEVI f16x8 read_swz(const u16* __restrict__ buf, int row, int slot_lin) {
  return *reinterpret_cast<const f16x8*>(buf + row * 64 + ((slot_lin ^ (row & 7)) * 8));
}

// ---------------------------------------------------------------- kernel W
// r|k|v|g -> Wf f16 [3072][1024]; o_w -> owb f16; x0_w -> x0wf f16.
__global__ void kW(const float* __restrict__ r_w, const float* __restrict__ k_w,
                   const float* __restrict__ v_w, const float* __restrict__ g_w,
                   const float* __restrict__ o_w, const float* __restrict__ x0_w,
                   u16* __restrict__ Wf, u16* __restrict__ owb,
                   u16* __restrict__ x0wf) {
  const size_t i = ((size_t)blockIdx.x * 256 + threadIdx.x) * 4;
  const float* src;
  u16* dst;
  if (i < 3145728) {
    src = (i < 524288)  ? r_w + i
        : (i < 1048576) ? k_w + (i - 524288)
        : (i < 2097152) ? v_w + (i - 1048576)
                        : g_w + (i - 2097152);
    dst = Wf + i;
  } else if (i < 4194304) {
    src = o_w + (i - 3145728);
    dst = owb + (i - 3145728);
  } else {
    src = x0_w + (i - 4194304);
    dst = x0wf + (i - 4194304);
  }
  float4 v = ld4(src);
  ushort4 h;
  h.x = f2h(v.x); h.y = f2h(v.y); h.z = f2h(v.z); h.w = f2h(v.w);
  *reinterpret_cast<ushort4*>(dst) = h;
}

// ---------------------------------------------------------------- kernel A1
__global__ void kA1(const float* __restrict__ x, const float* __restrict__ x0_mu,
                    float* __restrict__ xm0, float* __restrict__ delta,
                    u16* __restrict__ xm0f) {
  const size_t i4 = (size_t)blockIdx.x * 256 + threadIdx.x;
  const int t = (int)(i4 >> 8);
  const int h4 = (int)(i4 & 255) * 4;
  float4 xv = ld4(x + (size_t)t * 1024 + h4);
  float4 xp = make_float4(0.f, 0.f, 0.f, 0.f);
  if (t & (Lc - 1)) xp = ld4(x + (size_t)(t - 1) * 1024 + h4);
  float4 mu = ld4(x0_mu + h4);
  float4 d;
  d.x = xp.x - xv.x; d.y = xp.y - xv.y; d.z = xp.z - xv.z; d.w = xp.w - xv.w;
  st4(delta + (size_t)t * 1024 + h4, d);
  float4 m0;
  m0.x = xv.x + d.x * mu.x; m0.y = xv.y + d.y * mu.y;
  m0.z = xv.z + d.z * mu.z; m0.w = xv.w + d.w * mu.w;
  st4(xm0 + (size_t)t * 1024 + h4, m0);
  ushort4 h;
  h.x = f2h(m0.x); h.y = f2h(m0.y); h.z = f2h(m0.z); h.w = f2h(m0.w);
  *reinterpret_cast<ushort4*>(xm0f + (size_t)t * 1024 + h4) = h;
}

// ---------------------------------------------------------------- kernel A2f
// t160 = tanh(xm0 @ x0_w^T), single-pass f16 MFMA, 32KB LDS.
__global__ __launch_bounds__(256) void kA2f(
    const u16* __restrict__ xm0f, const u16* __restrict__ x0wf,
    float* __restrict__ t160) {
  __shared__ __align__(16) u16 sA[128 * 64];
  __shared__ __align__(16) u16 sB[128 * 64];
  const int mt = blockIdx.x, nt = blockIdx.y;
  const int ncols = nt ? 32 : 128;
  const int wcol0 = nt * 128;
  const u16* A = xm0f + (size_t)mt * 128 * 1024;
  const u16* B = x0wf + (size_t)wcol0 * 1024;
  const int tid = threadIdx.x;
  const int lane = tid & 63;
  const int wv = tid >> 6;
  const int wr = wv >> 1, wc = wv & 1;
  const int srow = wv * 32;
  f32x4 acc[4][4];
  #pragma unroll
  for (int i = 0; i < 4; ++i)
    #pragma unroll
    for (int j = 0; j < 4; ++j) acc[i][j] = {0.f, 0.f, 0.f, 0.f};

  for (int k0 = 0; k0 < 1024; k0 += 64) {
    #pragma unroll
    for (int c = 0; c < 4; ++c) {
      const int s8 = srow + c * 8;
      stage_swz(A, sA, s8, k0, lane);
      {
        const int rr = (s8 + (lane >> 3)) & (ncols - 1);
        const int ss = (lane & 7) ^ ((lane >> 3) & 7);
        __builtin_amdgcn_global_load_lds(
            (gu32*)(const void*)(B + (size_t)rr * 1024 + k0 + ss * 8),
            (lu32*)(void*)(sB + s8 * 64), 16, 0, 0);
      }
    }
    __syncthreads();
    #pragma unroll
    for (int kk = 0; kk < 2; ++kk) {
      const int sl = kk * 4 + (lane >> 4);
      f16x8 af[4], bf[4];
      #pragma unroll
      for (int m = 0; m < 4; ++m)
        af[m] = read_swz(sA, wr * 64 + m * 16 + (lane & 15), sl);
      #pragma unroll
      for (int j = 0; j < 4; ++j)
        bf[j] = read_swz(sB, wc * 64 + j * 16 + (lane & 15), sl);
      #pragma unroll
      for (int m = 0; m < 4; ++m)
        #pragma unroll
        for (int j = 0; j < 4; ++j)
          acc[m][j] = __builtin_amdgcn_mfma_f32_16x16x32_f16(af[m], bf[j], acc[m][j], 0, 0, 0);
    }
    __syncthreads();
  }
  #pragma unroll
  for (int m = 0; m < 4; ++m)
    #pragma unroll
    for (int r = 0; r < 4; ++r) {
      const int row = wr * 64 + m * 16 + (lane >> 4) * 4 + r;
      #pragma unroll
      for (int j = 0; j < 4; ++j) {
        const int col = wc * 64 + j * 16 + (lane & 15);
        if (col < ncols)
          t160[(size_t)(mt * 128 + row) * 160 + wcol0 + col] = tanhf(acc[m][j][r]);
      }
    }
}

// ---------------------------------------------------------------- kernel A2m5
// per plane n: mix = t160slice @ x2_wslice^T + bias; plane = xm0+delta*(mix-mu).
// n==1 -> f32 xmw; else f16 xmf plane.
__global__ __launch_bounds__(256) void kA2m5(
    const float* __restrict__ t160G, const float* __restrict__ x2_w,
    const float* __restrict__ x_bias, const float* __restrict__ xm0,
    const float* __restrict__ delta, const float* __restrict__ x0_mu,
    u16* __restrict__ xmf, float* __restrict__ xmw) {
  __shared__ float As[64 * 33];
  __shared__ float Ws[64 * 33];
  const int tid = threadIdx.x;
  const int m0 = blockIdx.x * 64, h0 = blockIdx.y * 64, n = blockIdx.z;
  #pragma unroll
  for (int c = 0; c < 2; ++c) {
    int r = c * 32 + (tid >> 3);
    int col = (tid & 7) * 4;
    float4 a4 = ld4(t160G + (size_t)(m0 + r) * 160 + n * 32 + col);
    As[r * 33 + col + 0] = a4.x; As[r * 33 + col + 1] = a4.y;
    As[r * 33 + col + 2] = a4.z; As[r * 33 + col + 3] = a4.w;
    float4 w4 = ld4(x2_w + (size_t)(h0 + r) * 160 + n * 32 + col);
    Ws[r * 33 + col + 0] = w4.x; Ws[r * 33 + col + 1] = w4.y;
    Ws[r * 33 + col + 2] = w4.z; Ws[r * 33 + col + 3] = w4.w;
  }
  __syncthreads();
  const int rm = (tid >> 4) * 4, cn = (tid & 15) * 4;
  float acc[4][4] = {};
  #pragma unroll
  for (int kk = 0; kk < 32; ++kk) {
    float a[4], w[4];
    #pragma unroll
    for (int i = 0; i < 4; ++i) a[i] = As[(rm + i) * 33 + kk];
    #pragma unroll
    for (int j = 0; j < 4; ++j) w[j] = Ws[(cn + j) * 33 + kk];
    #pragma unroll
    for (int i = 0; i < 4; ++i)
      #pragma unroll
      for (int j = 0; j < 4; ++j) acc[i][j] += a[i] * w[j];
  }
  const float4 b4 = ld4(x_bias + n * 1024 + h0 + cn);
  const float4 mu4 = ld4(x0_mu + h0 + cn);
  const int pi = (n == 0) ? 0 : (n == 2) ? 1 : (n == 3) ? 2 : 3;
  #pragma unroll
  for (int i = 0; i < 4; ++i) {
    const size_t rowo = (size_t)(m0 + rm + i) * 1024 + h0 + cn;
    float4 xm4 = ld4(xm0 + rowo);
    float4 dv4 = ld4(delta + rowo);
    float4 o;
    o.x = xm4.x + dv4.x * (acc[i][0] + b4.x - mu4.x);
    o.y = xm4.y + dv4.y * (acc[i][1] + b4.y - mu4.y);
    o.z = xm4.z + dv4.z * (acc[i][2] + b4.z - mu4.z);
    o.w = xm4.w + dv4.w * (acc[i][3] + b4.w - mu4.w);
    if (n == 1) {
      st4(xmw + rowo, o);
    } else {
      ushort4 h;
      h.x = f2h(o.x); h.y = f2h(o.y); h.z = f2h(o.z); h.w = f2h(o.w);
      *reinterpret_cast<ushort4*>(xmf + (size_t)pi * Tc * 1024 + rowo) = h;
    }
  }
}

// ---------------------------------------------------------------- kernel WL
__global__ __launch_bounds__(256) void kWL(
    const float* __restrict__ xmw, const float* __restrict__ w_w1,
    float* __restrict__ yw) {
  __shared__ float As[32 * 33];
  __shared__ float Ws[64 * 33];
  const int tid = threadIdx.x;
  const int t0 = blockIdx.x * 32;
  const int rg = tid >> 5;
  const int cg = tid & 31;
  float acc[4][2] = {};
  for (int k0 = 0; k0 < 1024; k0 += 32) {
    __syncthreads();
    {
      int r = tid >> 3, c4 = (tid & 7) * 4;
      float4 a4 = ld4(xmw + (size_t)(t0 + r) * 1024 + k0 + c4);
      As[r * 33 + c4 + 0] = a4.x; As[r * 33 + c4 + 1] = a4.y;
      As[r * 33 + c4 + 2] = a4.z; As[r * 33 + c4 + 3] = a4.w;
    }
    #pragma unroll
    for (int c = 0; c < 2; ++c) {
      int r = c * 32 + (tid >> 3), c4 = (tid & 7) * 4;
      float4 w4 = ld4(w_w1 + (size_t)r * 1024 + k0 + c4);
      Ws[r * 33 + c4 + 0] = w4.x; Ws[r * 33 + c4 + 1] = w4.y;
      Ws[r * 33 + c4 + 2] = w4.z; Ws[r * 33 + c4 + 3] = w4.w;
    }
    __syncthreads();
    #pragma unroll
    for (int kk = 0; kk < 32; ++kk) {
      float a[4];
      #pragma unroll
      for (int i = 0; i < 4; ++i) a[i] = As[(rg * 4 + i) * 33 + kk];
      float w0 = Ws[cg * 33 + kk], w1 = Ws[(cg + 32) * 33 + kk];
      #pragma unroll
      for (int i = 0; i < 4; ++i) { acc[i][0] += a[i] * w0; acc[i][1] += a[i] * w1; }
    }
  }
  #pragma unroll
  for (int i = 0; i < 4; ++i) {
    yw[(size_t)(t0 + rg * 4 + i) * 64 + cg]      = tanhf(acc[i][0]);
    yw[(size_t)(t0 + rg * 4 + i) * 64 + cg + 32] = tanhf(acc[i][1]);
  }
}

// ---------------------- single-pass f16 MFMA GEMM: r|k|v (f32 out) | g (f16 out)
__global__ __launch_bounds__(256) void kB(
    const u16* __restrict__ xmf, const u16* __restrict__ Wf,
    float* __restrict__ rG, float* __restrict__ kG,
    float* __restrict__ vG, u16* __restrict__ gG) {
  __shared__ __align__(16) u16 sA[128 * 64];
  __shared__ __align__(16) u16 sB[128 * 64];
  const int mt = blockIdx.x, nt = blockIdx.y;
  int plane, col0, ldc;
  float* Cf = nullptr;
  u16* Ch = nullptr;
  if (nt < 4)       { plane = 0; Cf = rG; ldc = 512;  col0 = nt * 128; }
  else if (nt < 8)  { plane = 1; Cf = kG; ldc = 512;  col0 = (nt - 4) * 128; }
  else if (nt < 16) { plane = 2; Cf = vG; ldc = 1024; col0 = (nt - 8) * 128; }
  else              { plane = 3; Ch = gG; ldc = 1024; col0 = (nt - 16) * 128; }
  const u16* A = xmf + ((size_t)plane * Tc + (size_t)mt * 128) * 1024;
  const u16* B = Wf + (size_t)nt * 128 * 1024;

  const int tid = threadIdx.x;
  const int lane = tid & 63;
  const int wv = tid >> 6;
  const int wr = wv >> 1, wc = wv & 1;
  const int srow = wv * 32;
  f32x4 acc[4][4];
  #pragma unroll
  for (int i = 0; i < 4; ++i)
    #pragma unroll
    for (int j = 0; j < 4; ++j) acc[i][j] = {0.f, 0.f, 0.f, 0.f};

  for (int k0 = 0; k0 < 1024; k0 += 64) {
    #pragma unroll
    for (int c = 0; c < 4; ++c) {
      const int s8 = srow + c * 8;
      stage_swz(A, sA, s8, k0, lane);
      stage_swz(B, sB, s8, k0, lane);
    }
    __syncthreads();
    #pragma unroll
    for (int kk = 0; kk < 2; ++kk) {
      const int sl = kk * 4 + (lane >> 4);
      f16x8 af[4], bf[4];
      #pragma unroll
      for (int m = 0; m < 4; ++m)
        af[m] = read_swz(sA, wr * 64 + m * 16 + (lane & 15), sl);
      #pragma unroll
      for (int j = 0; j < 4; ++j)
        bf[j] = read_swz(sB, wc * 64 + j * 16 + (lane & 15), sl);
      #pragma unroll
      for (int m = 0; m < 4; ++m)
        #pragma unroll
        for (int j = 0; j < 4; ++j)
          acc[m][j] = __builtin_amdgcn_mfma_f32_16x16x32_f16(af[m], bf[j], acc[m][j], 0, 0, 0);
    }
    __syncthreads();
  }
  #pragma unroll
  for (int m = 0; m < 4; ++m)
    #pragma unroll
    for (int r = 0; r < 4; ++r) {
      const int row = wr * 64 + m * 16 + (lane >> 4) * 4 + r;
      #pragma unroll
      for (int j = 0; j < 4; ++j) {
        const int col = wc * 64 + j * 16 + (lane & 15);
        float v = acc[m][j][r];
        if (Cf) Cf[(size_t)(mt * 128 + row) * ldc + col0 + col] = v;
        else    Ch[(size_t)(mt * 128 + row) * ldc + col0 + col] = f2h(v);
      }
    }
}

// ---------------------------------------------------------------- kernel C
__global__ __launch_bounds__(256) void kC(
    const float* __restrict__ yw, const float* __restrict__ w_w2,
    const float* __restrict__ w_b2, float* __restrict__ wfin) {
  __shared__ float th[32 * 68];
  const int tid = threadIdx.x;
  const int t0 = blockIdx.x * 32;
  for (int idx = tid; idx < 32 * 64; idx += 256) {
    int i = idx >> 6, j = idx & 63;
    th[i * 68 + j] = yw[(size_t)(t0 + i) * 64 + j];
  }
  __syncthreads();
  const int c = blockIdx.y * 256 + tid;
  float acc[32] = {};
  const float* w2 = w_w2 + (size_t)c * 64;
  for (int k = 0; k < 64; k += 4) {
    float4 wv = ld4(w2 + k);
    #pragma unroll
    for (int i = 0; i < 32; ++i) {
      float4 t4 = ld4(th + i * 68 + k);
      acc[i] += t4.x * wv.x + t4.y * wv.y + t4.z * wv.z + t4.w * wv.w;
    }
  }
  const float b = w_b2[c];
  #pragma unroll
  for (int i = 0; i < 32; ++i)
    wfin[(size_t)(t0 + i) * 512 + c] = -__expf(acc[i] + b);
}

// ---------------------------------------------------------------- kernel D1 (R8 v3)
__global__ __launch_bounds__(512) void kD1(
    const float* __restrict__ rG, const float* __restrict__ kG,
    const float* __restrict__ vG, const float* __restrict__ wfin,
    const float* __restrict__ bonus, float* __restrict__ wkvG,
    float* __restrict__ decayG, float* __restrict__ qeG, float* __restrict__ oG) {
  __shared__ float smem[4224 + 4224 + 8192 + 1056 + 64];
  float* kwT   = smem;            // [128][33]
  float* qeT   = kwT + 4224;      // [128][33]
  float* vl    = qeT + 4224;      // [32][256]
  float* wcl   = vl;              // [32][128] alias (dead before vl written)
  float* Al    = vl + 8192;       // [32][33]
  float* diag2 = Al + 1056;       // [32][2]
  const int tid = threadIdx.x;
  const int bid = blockIdx.x;
  const int nc = bid & 63, h = (bid >> 6) & 3, b = bid >> 8;
  const int tb = b * Lc + nc * 32;

  float4 wf[2];
  #pragma unroll
  for (int it = 0; it < 2; ++it) {
    int idx = it * 512 + tid;
    int c = idx >> 5, d4 = (idx & 31) * 4;
    wf[it] = ld4(wfin + (size_t)(tb + c) * 512 + h * 128 + d4);
  }
  float4 vreg[4];
  #pragma unroll
  for (int it = 0; it < 4; ++it) {
    int idx = it * 512 + tid;
    int c = idx >> 6, p4 = (idx & 63) * 4;
    vreg[it] = ld4(vG + (size_t)(tb + c) * 1024 + h * 256 + p4);
  }
  float rreg[8], kreg[8];
  #pragma unroll
  for (int it = 0; it < 8; ++it) {
    int idx = it * 512 + tid;
    int c = idx >> 7, d = idx & 127;
    rreg[it] = rG[(size_t)(tb + c) * 512 + h * 128 + d];
    kreg[it] = kG[(size_t)(tb + c) * 512 + h * 128 + d];
  }
  const float ureg = bonus[h * 128 + (tid & 127)];

  #pragma unroll
  for (int it = 0; it < 2; ++it) {
    int idx = it * 512 + tid;
    int c = idx >> 5, d4 = (idx & 31) * 4;
    st4(wcl + c * 128 + d4, wf[it]);
  }
  __syncthreads();  // B1
  if (tid < 128) {
    const int d = tid;
    float wv_[32];
    #pragma unroll
    for (int c = 0; c < 32; ++c) wv_[c] = wcl[c * 128 + d];
    float run = 0.f;
    #pragma unroll
    for (int c = 0; c < 32; ++c) { run += wv_[c]; wcl[c * 128 + d] = run; }
  }
  __syncthreads();  // B2
  #pragma unroll
  for (int it = 0; it < 8; ++it) {
    int idx = it * 512 + tid;
    int c = idx >> 7, d = idx & 127;
    int t = tb + c;
    float q = rreg[it];
    float k = kreg[it];
    float wcc = wcl[c * 128 + d];
    float wcp = (c > 0) ? wcl[(c - 1) * 128 + d] : 0.f;
    float wlast = wcl[31 * 128 + d];
    float qe = q * __expf(wcp);
    qeT[d * 33 + c] = q * __expf(wcp - wlast);
    kwT[d * 33 + c] = k * __expf(wlast - wcc);
    qeG[(size_t)t * 512 + h * 128 + d] = qe;
    if (c == 31) decayG[(size_t)bid * 128 + d] = __expf(wlast);
    float dv = q * k * ureg;
    #pragma unroll
    for (int m = 1; m < 64; m <<= 1) dv += __shfl_xor(dv, m, 64);
    if ((tid & 63) == 0) diag2[c * 2 + ((tid >> 6) & 1)] = dv;
  }
  __syncthreads();  // B3
  #pragma unroll
  for (int it = 0; it < 4; ++it) {
    int idx = it * 512 + tid;
    int c = idx >> 6, p4 = (idx & 63) * 4;
    st4(vl + c * 256 + p4, vreg[it]);
  }
  {
    const int j = tid & 31, i2 = tid >> 5;
    float a0 = 0.f, a1 = 0.f;
    for (int d = 0; d < 128; ++d) {
      float kv = kwT[d * 33 + j];
      a0 += qeT[d * 33 + i2] * kv;
      a1 += qeT[d * 33 + i2 + 16] * kv;
    }
    float dg0 = diag2[i2 * 2] + diag2[i2 * 2 + 1];
    float dg1 = diag2[(i2 + 16) * 2] + diag2[(i2 + 16) * 2 + 1];
    Al[i2 * 33 + j] = (j < i2) ? a0 : ((j == i2) ? dg0 : 0.f);
    Al[(i2 + 16) * 33 + j] = (j < i2 + 16) ? a1 : ((j == i2 + 16) ? dg1 : 0.f);
  }
  __syncthreads();  // B4
  const int pid = tid & 63, wvx = tid >> 6;
  const int p4 = pid * 4;
  {
    float* wkvB = wkvG + (size_t)bid * (128 * 256);
    #pragma unroll
    for (int pp = 0; pp < 2; ++pp) {
      const int d0 = pp * 64 + wvx * 8;
      float4 acc[8];
      #pragma unroll
      for (int q = 0; q < 8; ++q) acc[q] = make_float4(0, 0, 0, 0);
      for (int c = 0; c < 32; ++c) {
        float4 v4 = ld4(vl + c * 256 + p4);
        #pragma unroll
        for (int q = 0; q < 8; ++q) {
          float s = kwT[(d0 + q) * 33 + c];
          acc[q].x += v4.x * s; acc[q].y += v4.y * s;
          acc[q].z += v4.z * s; acc[q].w += v4.w * s;
        }
      }
      #pragma unroll
      for (int q = 0; q < 8; ++q)
        st4(wkvB + (size_t)(d0 + q) * 256 + p4, acc[q]);
    }
  }
  {
    float4 acc[4];
    #pragma unroll
    for (int q = 0; q < 4; ++q) acc[q] = make_float4(0, 0, 0, 0);
    for (int c = 0; c < 32; ++c) {
      float4 v4 = ld4(vl + c * 256 + p4);
      #pragma unroll
      for (int q = 0; q < 4; ++q) {
        float a = Al[(wvx * 4 + q) * 33 + c];
        acc[q].x += v4.x * a; acc[q].y += v4.y * a;
        acc[q].z += v4.z * a; acc[q].w += v4.w * a;
      }
    }
    #pragma unroll
    for (int q = 0; q < 4; ++q)
      st4(oG + (size_t)(tb + wvx * 4 + q) * 1024 + h * 256 + p4, acc[q]);
  }
}

// ---------------------------------------------------------------- kernel D2 (R8)
__global__ __launch_bounds__(256) void kD2(float* __restrict__ wkvG,
                                           const float* __restrict__ decayG) {
  const int wvid = (blockIdx.x * 256 + threadIdx.x) >> 6;  // 0..2047
  const int lane = threadIdx.x & 63;
  const int half = wvid & 1;
  const int d = (wvid >> 1) & 127;
  const int bh = wvid >> 8;
  const int p2 = half * 128 + lane * 2;
  float* base = wkvG + ((size_t)bh * 64 * 128 + d) * 256 + p2;
  const float* dbase = decayG + (size_t)bh * 64 * 128 + d;
  float2 kvb[4];
  float decb[4];
  #pragma unroll
  for (int i = 0; i < 4; ++i) {
    kvb[i] = ld2(base + (size_t)i * 32768);
    decb[i] = dbase[(size_t)i * 128];
  }
  float2 S = make_float2(0.f, 0.f);
  #pragma unroll
  for (int nc = 0; nc < 64; ++nc) {
    const int sl = nc & 3;
    float2 kv = kvb[sl];
    float dec = decb[sl];
    if (nc + 4 < 64) {
      kvb[sl] = ld2(base + (size_t)(nc + 4) * 32768);
      decb[sl] = dbase[(size_t)(nc + 4) * 128];
    }
    st2(base + (size_t)nc * 32768, S);
    S.x = S.x * dec + kv.x;
    S.y = S.y * dec + kv.y;
  }
}

// ---------------------------------------------------------------- kernel D3 (R8)
__global__ __launch_bounds__(256) void kD3(
    const float* __restrict__ qeG, const float* __restrict__ wkvG,
    float* __restrict__ oG) {
  __shared__ float qel[32 * 129];
  const int tid = threadIdx.x;
  const int bid = blockIdx.x;
  const int nc = bid & 63, h = (bid >> 6) & 3, b = bid >> 8;
  const int tb = b * Lc + nc * 32;
  for (int it = 0; it < 16; ++it) {
    int idx = it * 256 + tid;
    int c = idx >> 7, d = idx & 127;
    qel[c * 129 + d] = qeG[(size_t)(tb + c) * 512 + h * 128 + d];
  }
  __syncthreads();
  const int pid = tid & 63, wvx = tid >> 6;
  const int p4 = pid * 4;
  const float* Sb = wkvG + (size_t)bid * (128 * 256);
  float4 acc[8];
  #pragma unroll
  for (int q = 0; q < 8; ++q) acc[q] = make_float4(0, 0, 0, 0);
  for (int d = 0; d < 128; ++d) {
    float4 s4 = ld4(Sb + (size_t)d * 256 + p4);
    #pragma unroll
    for (int q = 0; q < 8; ++q) {
      float qv = qel[(wvx * 8 + q) * 129 + d];
      acc[q].x += s4.x * qv; acc[q].y += s4.y * qv;
      acc[q].z += s4.z * qv; acc[q].w += s4.w * qv;
    }
  }
  #pragma unroll
  for (int q = 0; q < 8; ++q) {
    float* op = oG + (size_t)(tb + wvx * 8 + q) * 1024 + h * 256 + p4;
    float4 cur = ld4(op);
    cur.x += acc[q].x; cur.y += acc[q].y; cur.z += acc[q].z; cur.w += acc[q].w;
    st4(op, cur);
  }
}

// ---------------------------------------------------------------- kernel E
// GroupNorm + swish gate; g input f16, gate output f16.
__global__ __launch_bounds__(256) void kE(
    const float* __restrict__ oG, const u16* __restrict__ gG,
    const float* __restrict__ gn_w, const float* __restrict__ gn_b,
    u16* __restrict__ gate) {
  const int t = blockIdx.x;
  const int h = threadIdx.x >> 6, lane = threadIdx.x & 63;
  const int p4 = lane * 4;
  const int vd = h * 256 + p4;
  float4 v = ld4(oG + (size_t)t * 1024 + vd);
  float s = v.x + v.y + v.z + v.w;
  float ss = v.x * v.x + v.y * v.y + v.z * v.z + v.w * v.w;
  for (int m = 1; m < 64; m <<= 1) {
    s += __shfl_xor(s, m, 64);
    ss += __shfl_xor(ss, m, 64);
  }
  const float mean = s * (1.f / 256.f);
  const float var = ss * (1.f / 256.f) - mean * mean;
  const float rs = rsqrtf(var + 1e-5f);
  float4 gw = ld4(gn_w + vd), gb = ld4(gn_b + vd);
  float4 on;
  on.x = (v.x - mean) * rs * gw.x + gb.x;
  on.y = (v.y - mean) * rs * gw.y + gb.y;
  on.z = (v.z - mean) * rs * gw.z + gb.z;
  on.w = (v.w - mean) * rs * gw.w + gb.w;
  ushort4 g4 = *reinterpret_cast<const ushort4*>(gG + (size_t)t * 1024 + vd);
  float gx = h2f(g4.x), gy = h2f(g4.y), gz = h2f(g4.z), gw_ = h2f(g4.w);
  float4 sw;
  sw.x = gx / (1.f + __expf(-gx));
  sw.y = gy / (1.f + __expf(-gy));
  sw.z = gz / (1.f + __expf(-gz));
  sw.w = gw_ / (1.f + __expf(-gw_));
  ushort4 ob;
  ob.x = f2h(on.x * sw.x); ob.y = f2h(on.y * sw.y);
  ob.z = f2h(on.z * sw.z); ob.w = f2h(on.w * sw.w);
  *reinterpret_cast<ushort4*>(gate + (size_t)t * 1024 + vd) = ob;
}

// ---------------------------------------------------------------- kernel F (f16)
__global__ __launch_bounds__(256) void kF(
    const u16* __restrict__ gate, const u16* __restrict__ owb,
    float* __restrict__ out) {
  __shared__ __align__(16) u16 Abuf[128 * 64];
  __shared__ __align__(16) u16 Bbuf[128 * 64];
  const int mt = blockIdx.x, nt = blockIdx.y;
  const u16* A = gate + (size_t)mt * 128 * 1024;
  const u16* W = owb + (size_t)nt * 128 * 1024;
  float* C = out + (size_t)mt * 128 * 1024 + nt * 128;
  const int tid = threadIdx.x;
  const int lane = tid & 63;
  const int wv = tid >> 6;
  const int wr = wv >> 1, wc = wv & 1;
  const int srow = wv * 32;
  f32x4 acc[4][4];
  #pragma unroll
  for (int i = 0; i < 4; ++i)
    #pragma unroll
    for (int j = 0; j < 4; ++j) acc[i][j] = {0.f, 0.f, 0.f, 0.f};
  for (int k0 = 0; k0 < 1024; k0 += 64) {
    #pragma unroll
    for (int c = 0; c < 4; ++c) {
      const int s8 = srow + c * 8;
      stage_swz(A, Abuf, s8, k0, lane);
      stage_swz(W, Bbuf, s8, k0, lane);
    }
    __syncthreads();
    #pragma unroll
    for (int kk = 0; kk < 2; ++kk) {
      const int sl = kk * 4 + (lane >> 4);
      f16x8 af[4], bf[4];
      #pragma unroll
      for (int m = 0; m < 4; ++m)
        af[m] = read_swz(Abuf, wr * 64 + m * 16 + (lane & 15), sl);
      #pragma unroll
      for (int j = 0; j < 4; ++j)
        bf[j] = read_swz(Bbuf, wc * 64 + j * 16 + (lane & 15), sl);
      #pragma unroll
      for (int m = 0; m < 4; ++m)
        #pragma unroll
        for (int j = 0; j < 4; ++j)
          acc[m][j] = __builtin_amdgcn_mfma_f32_16x16x32_f16(af[m], bf[j], acc[m][j], 0, 0, 0);
    }
    __syncthreads();
  }
  #pragma unroll
  for (int m = 0; m < 4; ++m)
    #pragma unroll
    for (int r = 0; r < 4; ++r) {
      const int row = wr * 64 + m * 16 + (lane >> 4) * 4 + r;
      #pragma unroll
      for (int j = 0; j < 4; ++j) {
        const int col = wc * 64 + j * 16 + (lane & 15);
        C[(size_t)row * 1024 + col] = acc[m][j][r];
      }
    }
}

}  // namespace

extern "C" void kernel_launch(void* const* d_in, const int* in_sizes, int n_in,
                              void* d_out, int out_size, void* d_ws, size_t ws_size,
                              hipStream_t stream) {
  (void)in_sizes; (void)n_in; (void)out_size;
  if (ws_size < WS_NEED) return;

  const float* x      = (const float*)d_in[0];
  const float* x0_mu  = (const float*)d_in[1];
  const float* x0_w   = (const float*)d_in[2];
  const float* x2_w   = (const float*)d_in[3];
  const float* x_bias = (const float*)d_in[4];
  const float* r_w    = (const float*)d_in[5];
  const float* w_w1   = (const float*)d_in[6];
  const float* w_w2   = (const float*)d_in[7];
  const float* w_b2   = (const float*)d_in[8];
  const float* k_w    = (const float*)d_in[9];
  const float* v_w    = (const float*)d_in[10];
  const float* g_w    = (const float*)d_in[11];
  const float* bonus  = (const float*)d_in[12];
  const float* gn_w   = (const float*)d_in[13];
  const float* gn_b   = (const float*)d_in[14];
  const float* o_w    = (const float*)d_in[15];
  float* out = (float*)d_out;
  char* ws = (char*)d_ws;

  float* wkvG   = (float*)(ws + OFF_WKV);
  float* xm0    = (float*)(ws + OFF_XM0);
  float* delta  = (float*)(ws + OFF_DELTA);
  float* t160   = (float*)(ws + OFF_T160);
  float* xmw    = (float*)(ws + OFF_XMW);
  float* yw     = (float*)(ws + OFF_YW);
  u16*   x0wf   = (u16*)(ws + OFF_X0WF);
  u16*   xm0f   = (u16*)(ws + OFF_XM0F);
  u16*   xmf    = (u16*)(ws + OFF_XMF);
  float* wfin   = (float*)(ws + OFF_WFIN);
  u16*   gate   = (u16*)(ws + OFF_GATE);
  float* qeG    = (float*)(ws + OFF_QE);
  float* oG     = (float*)(ws + OFF_OO);
  u16*   Wf     = (u16*)(ws + OFF_WF);
  float* decayG = (float*)(ws + OFF_DECAY);
  u16*   owb    = (u16*)(ws + OFF_OWB);
  float* rG     = (float*)(ws + OFF_RG);
  float* kG     = (float*)(ws + OFF_KG);
  float* vG     = (float*)(ws + OFF_VG);
  u16*   gG     = (u16*)(ws + OFF_GG);

  kW   <<<dim3(4256),        dim3(256), 0, stream>>>(r_w, k_w, v_w, g_w, o_w, x0_w,
                                                     Wf, owb, x0wf);
  kA1  <<<dim3(4096),        dim3(256), 0, stream>>>(x, x0_mu, xm0, delta, xm0f);
  kA2f <<<dim3(32, 2),       dim3(256), 0, stream>>>(xm0f, x0wf, t160);
  kA2m5<<<dim3(64, 16, 5),   dim3(256), 0, stream>>>(t160, x2_w, x_bias, xm0, delta,
                                                     x0_mu, xmf, xmw);
  kWL  <<<dim3(128),         dim3(256), 0, stream>>>(xmw, w_w1, yw);
  kB   <<<dim3(32, 24),      dim3(256), 0, stream>>>(xmf, Wf, rG, kG, vG, gG);
  kC   <<<dim3(128, 2),      dim3(256), 0, stream>>>(yw, w_w2, w_b2, wfin);
  kD1  <<<dim3(512),         dim3(512), 0, stream>>>(rG, kG, vG, wfin, bonus,
                                                     wkvG, decayG, qeG, oG);
  kD2  <<<dim3(512),         dim3(256), 0, stream>>>(wkvG, decayG);
  kD3  <<<dim3(512),         dim3(256), 0, stream>>>(qeG, wkvG, oG);
  kE   <<<dim3(4096),        dim3(256), 0, stream>>>(oG, gG, gn_w, gn_b, gate);
  kF   <<<dim3(32, 8),       dim3(256), 0, stream>>>(gate, owb, out);
}

// Round 13
// 333.395 us; speedup vs baseline: 1.8656x; 1.0660x over previous
//
#include <hip/hip_runtime.h>

// RWKV6Attention forward — round 13: R12 base (355us) + f16 wkv state
// (f32 scan accumulators; saves ~118MB HBM across kD1/kD2/kD3) + kW/kA1 merged.

#define DEVI __device__ __forceinline__

namespace {

typedef unsigned short u16;
typedef unsigned int u32;
typedef __attribute__((ext_vector_type(8))) _Float16 f16x8;  // 4 VGPRs
typedef __attribute__((ext_vector_type(4))) float f32x4;

typedef __attribute__((address_space(1))) const u32 gu32;
typedef __attribute__((address_space(3))) u32 lu32;

constexpr int Lc = 2048;
constexpr int Tc = 4096;   // B*L

// ---- workspace layout (byte offsets), lifetime-safe aliasing.
constexpr size_t OFF_WKV   = 0;            // f16 [512][128][256] = 33.5MB (kD1+)
constexpr size_t OFF_XM0   = 0;            // f32 [T][1024] dead after kA2m5
constexpr size_t OFF_DELTA = 16777216;     // f32 [T][1024] dead after kA2m5
constexpr size_t OFF_T160  = 33554432;     // f32 [T][160]  dead after kA2m5
constexpr size_t OFF_XMW   = 36175872;
constexpr size_t OFF_YW    = 52953088;
constexpr size_t OFF_X0WF  = 54001664;     // f16 [160][1024]
constexpr size_t OFF_XMF   = 67108864;     // f16 [4][T][1024] (kA2m5 -> kB)
constexpr size_t OFF_XM0F  = 67108864;     //   f16 [T][1024] (kWA -> kA2f)
constexpr size_t OFF_WFIN  = 67108864;     //   f32 [T][512]  (kC -> kD1, after kB)
constexpr size_t OFF_GATE  = 75497472;     //   f16 [T][1024] (kE -> kF)
constexpr size_t OFF_QE    = 100663296;
constexpr size_t OFF_OO    = 109051904;
constexpr size_t OFF_WF    = 125829120;    // f16 [3072][1024]
constexpr size_t OFF_DECAY = 132120576;
constexpr size_t OFF_OWB   = 136314880;    // f16 [1024][1024]
constexpr size_t OFF_RG    = 138412032;
constexpr size_t OFF_KG    = 146800640;
constexpr size_t OFF_VG    = 155189248;
constexpr size_t OFF_GG    = 171966464;    // f16 [T][1024]
constexpr size_t WS_NEED   = 180355072;

DEVI float4 ld4(const float* p) { return *reinterpret_cast<const float4*>(p); }
DEVI void   st4(float* p, float4 v) { *reinterpret_cast<float4*>(p) = v; }
DEVI u16 f2h(float f) { _Float16 h = (_Float16)f; return *(u16*)&h; }
DEVI float h2f(u16 u) { _Float16 h = *(_Float16*)&u; return (float)h; }

// ---- BK=64 swizzled staging (source-side XOR; linear LDS dest)
DEVI void stage_swz(const u16* __restrict__ src, u16* __restrict__ dstBase,
                    int srow8, int k0, int lane) {
  const int rr = srow8 + (lane >> 3);
  const int ss = (lane & 7) ^ ((lane >> 3) & 7);
  __builtin_amdgcn_global_load_lds(
      (gu32*)(const void*)(src + (size_t)rr * 1024 + k0 + ss * 8),
      (lu32*)(void*)(dstBase + srow8 * 64), 16, 0, 0);
}
DEVI f16x8 read_swz(const u16* __restrict__ buf, int row, int slot_lin) {
  return *reinterpret_cast<const f16x8*>(buf + row * 64 + ((slot_lin ^ (row & 7)) * 8));
}

// ---------------------------------------------------------------- kernel WA
// blocks [0,4256): weight conversion; blocks [4256,8352): shift+lerp (kA1).
__global__ void kWA(const float* __restrict__ r_w, const float* __restrict__ k_w,
                    const float* __restrict__ v_w, const float* __restrict__ g_w,
                    const float* __restrict__ o_w, const float* __restrict__ x0_w,
                    const float* __restrict__ x, const float* __restrict__ x0_mu,
                    u16* __restrict__ Wf, u16* __restrict__ owb,
                    u16* __restrict__ x0wf, float* __restrict__ xm0,
                    float* __restrict__ delta, u16* __restrict__ xm0f) {
  if (blockIdx.x < 4256) {
    const size_t i = ((size_t)blockIdx.x * 256 + threadIdx.x) * 4;
    const float* src;
    u16* dst;
    if (i < 3145728) {
      src = (i < 524288)  ? r_w + i
          : (i < 1048576) ? k_w + (i - 524288)
          : (i < 2097152) ? v_w + (i - 1048576)
                          : g_w + (i - 2097152);
      dst = Wf + i;
    } else if (i < 4194304) {
      src = o_w + (i - 3145728);
      dst = owb + (i - 3145728);
    } else {
      src = x0_w + (i - 4194304);
      dst = x0wf + (i - 4194304);
    }
    float4 v = ld4(src);
    ushort4 h;
    h.x = f2h(v.x); h.y = f2h(v.y); h.z = f2h(v.z); h.w = f2h(v.w);
    *reinterpret_cast<ushort4*>(dst) = h;
  } else {
    const size_t i4 = (size_t)(blockIdx.x - 4256) * 256 + threadIdx.x;
    const int t = (int)(i4 >> 8);
    const int h4 = (int)(i4 & 255) * 4;
    float4 xv = ld4(x + (size_t)t * 1024 + h4);
    float4 xp = make_float4(0.f, 0.f, 0.f, 0.f);
    if (t & (Lc - 1)) xp = ld4(x + (size_t)(t - 1) * 1024 + h4);
    float4 mu = ld4(x0_mu + h4);
    float4 d;
    d.x = xp.x - xv.x; d.y = xp.y - xv.y; d.z = xp.z - xv.z; d.w = xp.w - xv.w;
    st4(delta + (size_t)t * 1024 + h4, d);
    float4 m0;
    m0.x = xv.x + d.x * mu.x; m0.y = xv.y + d.y * mu.y;
    m0.z = xv.z + d.z * mu.z; m0.w = xv.w + d.w * mu.w;
    st4(xm0 + (size_t)t * 1024 + h4, m0);
    ushort4 h;
    h.x = f2h(m0.x); h.y = f2h(m0.y); h.z = f2h(m0.z); h.w = f2h(m0.w);
    *reinterpret_cast<ushort4*>(xm0f + (size_t)t * 1024 + h4) = h;
  }
}

// ---------------------------------------------------------------- kernel A2f
__global__ __launch_bounds__(256) void kA2f(
    const u16* __restrict__ xm0f, const u16* __restrict__ x0wf,
    float* __restrict__ t160) {
  __shared__ __align__(16) u16 sA[128 * 64];
  __shared__ __align__(16) u16 sB[128 * 64];
  const int mt = blockIdx.x, nt = blockIdx.y;
  const int ncols = nt ? 32 : 128;
  const int wcol0 = nt * 128;
  const u16* A = xm0f + (size_t)mt * 128 * 1024;
  const u16* B = x0wf + (size_t)wcol0 * 1024;
  const int tid = threadIdx.x;
  const int lane = tid & 63;
  const int wv = tid >> 6;
  const int wr = wv >> 1, wc = wv & 1;
  const int srow = wv * 32;
  f32x4 acc[4][4];
  #pragma unroll
  for (int i = 0; i < 4; ++i)
    #pragma unroll
    for (int j = 0; j < 4; ++j) acc[i][j] = {0.f, 0.f, 0.f, 0.f};

  for (int k0 = 0; k0 < 1024; k0 += 64) {
    #pragma unroll
    for (int c = 0; c < 4; ++c) {
      const int s8 = srow + c * 8;
      stage_swz(A, sA, s8, k0, lane);
      {
        const int rr = (s8 + (lane >> 3)) & (ncols - 1);
        const int ss = (lane & 7) ^ ((lane >> 3) & 7);
        __builtin_amdgcn_global_load_lds(
            (gu32*)(const void*)(B + (size_t)rr * 1024 + k0 + ss * 8),
            (lu32*)(void*)(sB + s8 * 64), 16, 0, 0);
      }
    }
    __syncthreads();
    #pragma unroll
    for (int kk = 0; kk < 2; ++kk) {
      const int sl = kk * 4 + (lane >> 4);
      f16x8 af[4], bf[4];
      #pragma unroll
      for (int m = 0; m < 4; ++m)
        af[m] = read_swz(sA, wr * 64 + m * 16 + (lane & 15), sl);
      #pragma unroll
      for (int j = 0; j < 4; ++j)
        bf[j] = read_swz(sB, wc * 64 + j * 16 + (lane & 15), sl);
      #pragma unroll
      for (int m = 0; m < 4; ++m)
        #pragma unroll
        for (int j = 0; j < 4; ++j)
          acc[m][j] = __builtin_amdgcn_mfma_f32_16x16x32_f16(af[m], bf[j], acc[m][j], 0, 0, 0);
    }
    __syncthreads();
  }
  #pragma unroll
  for (int m = 0; m < 4; ++m)
    #pragma unroll
    for (int r = 0; r < 4; ++r) {
      const int row = wr * 64 + m * 16 + (lane >> 4) * 4 + r;
      #pragma unroll
      for (int j = 0; j < 4; ++j) {
        const int col = wc * 64 + j * 16 + (lane & 15);
        if (col < ncols)
          t160[(size_t)(mt * 128 + row) * 160 + wcol0 + col] = tanhf(acc[m][j][r]);
      }
    }
}

// ---------------------------------------------------------------- kernel A2m5
__global__ __launch_bounds__(256) void kA2m5(
    const float* __restrict__ t160G, const float* __restrict__ x2_w,
    const float* __restrict__ x_bias, const float* __restrict__ xm0,
    const float* __restrict__ delta, const float* __restrict__ x0_mu,
    u16* __restrict__ xmf, float* __restrict__ xmw) {
  __shared__ float As[64 * 33];
  __shared__ float Ws[64 * 33];
  const int tid = threadIdx.x;
  const int m0 = blockIdx.x * 64, h0 = blockIdx.y * 64, n = blockIdx.z;
  #pragma unroll
  for (int c = 0; c < 2; ++c) {
    int r = c * 32 + (tid >> 3);
    int col = (tid & 7) * 4;
    float4 a4 = ld4(t160G + (size_t)(m0 + r) * 160 + n * 32 + col);
    As[r * 33 + col + 0] = a4.x; As[r * 33 + col + 1] = a4.y;
    As[r * 33 + col + 2] = a4.z; As[r * 33 + col + 3] = a4.w;
    float4 w4 = ld4(x2_w + (size_t)(h0 + r) * 160 + n * 32 + col);
    Ws[r * 33 + col + 0] = w4.x; Ws[r * 33 + col + 1] = w4.y;
    Ws[r * 33 + col + 2] = w4.z; Ws[r * 33 + col + 3] = w4.w;
  }
  __syncthreads();
  const int rm = (tid >> 4) * 4, cn = (tid & 15) * 4;
  float acc[4][4] = {};
  #pragma unroll
  for (int kk = 0; kk < 32; ++kk) {
    float a[4], w[4];
    #pragma unroll
    for (int i = 0; i < 4; ++i) a[i] = As[(rm + i) * 33 + kk];
    #pragma unroll
    for (int j = 0; j < 4; ++j) w[j] = Ws[(cn + j) * 33 + kk];
    #pragma unroll
    for (int i = 0; i < 4; ++i)
      #pragma unroll
      for (int j = 0; j < 4; ++j) acc[i][j] += a[i] * w[j];
  }
  const float4 b4 = ld4(x_bias + n * 1024 + h0 + cn);
  const float4 mu4 = ld4(x0_mu + h0 + cn);
  const int pi = (n == 0) ? 0 : (n == 2) ? 1 : (n == 3) ? 2 : 3;
  #pragma unroll
  for (int i = 0; i < 4; ++i) {
    const size_t rowo = (size_t)(m0 + rm + i) * 1024 + h0 + cn;
    float4 xm4 = ld4(xm0 + rowo);
    float4 dv4 = ld4(delta + rowo);
    float4 o;
    o.x = xm4.x + dv4.x * (acc[i][0] + b4.x - mu4.x);
    o.y = xm4.y + dv4.y * (acc[i][1] + b4.y - mu4.y);
    o.z = xm4.z + dv4.z * (acc[i][2] + b4.z - mu4.z);
    o.w = xm4.w + dv4.w * (acc[i][3] + b4.w - mu4.w);
    if (n == 1) {
      st4(xmw + rowo, o);
    } else {
      ushort4 h;
      h.x = f2h(o.x); h.y = f2h(o.y); h.z = f2h(o.z); h.w = f2h(o.w);
      *reinterpret_cast<ushort4*>(xmf + (size_t)pi * Tc * 1024 + rowo) = h;
    }
  }
}

// ---------------------------------------------------------------- kernel WL
__global__ __launch_bounds__(256) void kWL(
    const float* __restrict__ xmw, const float* __restrict__ w_w1,
    float* __restrict__ yw) {
  __shared__ float As[32 * 33];
  __shared__ float Ws[64 * 33];
  const int tid = threadIdx.x;
  const int t0 = blockIdx.x * 32;
  const int rg = tid >> 5;
  const int cg = tid & 31;
  float acc[4][2] = {};
  for (int k0 = 0; k0 < 1024; k0 += 32) {
    __syncthreads();
    {
      int r = tid >> 3, c4 = (tid & 7) * 4;
      float4 a4 = ld4(xmw + (size_t)(t0 + r) * 1024 + k0 + c4);
      As[r * 33 + c4 + 0] = a4.x; As[r * 33 + c4 + 1] = a4.y;
      As[r * 33 + c4 + 2] = a4.z; As[r * 33 + c4 + 3] = a4.w;
    }
    #pragma unroll
    for (int c = 0; c < 2; ++c) {
      int r = c * 32 + (tid >> 3), c4 = (tid & 7) * 4;
      float4 w4 = ld4(w_w1 + (size_t)r * 1024 + k0 + c4);
      Ws[r * 33 + c4 + 0] = w4.x; Ws[r * 33 + c4 + 1] = w4.y;
      Ws[r * 33 + c4 + 2] = w4.z; Ws[r * 33 + c4 + 3] = w4.w;
    }
    __syncthreads();
    #pragma unroll
    for (int kk = 0; kk < 32; ++kk) {
      float a[4];
      #pragma unroll
      for (int i = 0; i < 4; ++i) a[i] = As[(rg * 4 + i) * 33 + kk];
      float w0 = Ws[cg * 33 + kk], w1 = Ws[(cg + 32) * 33 + kk];
      #pragma unroll
      for (int i = 0; i < 4; ++i) { acc[i][0] += a[i] * w0; acc[i][1] += a[i] * w1; }
    }
  }
  #pragma unroll
  for (int i = 0; i < 4; ++i) {
    yw[(size_t)(t0 + rg * 4 + i) * 64 + cg]      = tanhf(acc[i][0]);
    yw[(size_t)(t0 + rg * 4 + i) * 64 + cg + 32] = tanhf(acc[i][1]);
  }
}

// ---------------------- single-pass f16 MFMA GEMM: r|k|v (f32 out) | g (f16 out)
__global__ __launch_bounds__(256) void kB(
    const u16* __restrict__ xmf, const u16* __restrict__ Wf,
    float* __restrict__ rG, float* __restrict__ kG,
    float* __restrict__ vG, u16* __restrict__ gG) {
  __shared__ __align__(16) u16 sA[128 * 64];
  __shared__ __align__(16) u16 sB[128 * 64];
  const int mt = blockIdx.x, nt = blockIdx.y;
  int plane, col0, ldc;
  float* Cf = nullptr;
  u16* Ch = nullptr;
  if (nt < 4)       { plane = 0; Cf = rG; ldc = 512;  col0 = nt * 128; }
  else if (nt < 8)  { plane = 1; Cf = kG; ldc = 512;  col0 = (nt - 4) * 128; }
  else if (nt < 16) { plane = 2; Cf = vG; ldc = 1024; col0 = (nt - 8) * 128; }
  else              { plane = 3; Ch = gG; ldc = 1024; col0 = (nt - 16) * 128; }
  const u16* A = xmf + ((size_t)plane * Tc + (size_t)mt * 128) * 1024;
  const u16* B = Wf + (size_t)nt * 128 * 1024;

  const int tid = threadIdx.x;
  const int lane = tid & 63;
  const int wv = tid >> 6;
  const int wr = wv >> 1, wc = wv & 1;
  const int srow = wv * 32;
  f32x4 acc[4][4];
  #pragma unroll
  for (int i = 0; i < 4; ++i)
    #pragma unroll
    for (int j = 0; j < 4; ++j) acc[i][j] = {0.f, 0.f, 0.f, 0.f};

  for (int k0 = 0; k0 < 1024; k0 += 64) {
    #pragma unroll
    for (int c = 0; c < 4; ++c) {
      const int s8 = srow + c * 8;
      stage_swz(A, sA, s8, k0, lane);
      stage_swz(B, sB, s8, k0, lane);
    }
    __syncthreads();
    #pragma unroll
    for (int kk = 0; kk < 2; ++kk) {
      const int sl = kk * 4 + (lane >> 4);
      f16x8 af[4], bf[4];
      #pragma unroll
      for (int m = 0; m < 4; ++m)
        af[m] = read_swz(sA, wr * 64 + m * 16 + (lane & 15), sl);
      #pragma unroll
      for (int j = 0; j < 4; ++j)
        bf[j] = read_swz(sB, wc * 64 + j * 16 + (lane & 15), sl);
      #pragma unroll
      for (int m = 0; m < 4; ++m)
        #pragma unroll
        for (int j = 0; j < 4; ++j)
          acc[m][j] = __builtin_amdgcn_mfma_f32_16x16x32_f16(af[m], bf[j], acc[m][j], 0, 0, 0);
    }
    __syncthreads();
  }
  #pragma unroll
  for (int m = 0; m < 4; ++m)
    #pragma unroll
    for (int r = 0; r < 4; ++r) {
      const int row = wr * 64 + m * 16 + (lane >> 4) * 4 + r;
      #pragma unroll
      for (int j = 0; j < 4; ++j) {
        const int col = wc * 64 + j * 16 + (lane & 15);
        float v = acc[m][j][r];
        if (Cf) Cf[(size_t)(mt * 128 + row) * ldc + col0 + col] = v;
        else    Ch[(size_t)(mt * 128 + row) * ldc + col0 + col] = f2h(v);
      }
    }
}

// ---------------------------------------------------------------- kernel C
__global__ __launch_bounds__(256) void kC(
    const float* __restrict__ yw, const float* __restrict__ w_w2,
    const float* __restrict__ w_b2, float* __restrict__ wfin) {
  __shared__ float th[32 * 68];
  const int tid = threadIdx.x;
  const int t0 = blockIdx.x * 32;
  for (int idx = tid; idx < 32 * 64; idx += 256) {
    int i = idx >> 6, j = idx & 63;
    th[i * 68 + j] = yw[(size_t)(t0 + i) * 64 + j];
  }
  __syncthreads();
  const int c = blockIdx.y * 256 + tid;
  float acc[32] = {};
  const float* w2 = w_w2 + (size_t)c * 64;
  for (int k = 0; k < 64; k += 4) {
    float4 wv = ld4(w2 + k);
    #pragma unroll
    for (int i = 0; i < 32; ++i) {
      float4 t4 = ld4(th + i * 68 + k);
      acc[i] += t4.x * wv.x + t4.y * wv.y + t4.z * wv.z + t4.w * wv.w;
    }
  }
  const float b = w_b2[c];
  #pragma unroll
  for (int i = 0; i < 32; ++i)
    wfin[(size_t)(t0 + i) * 512 + c] = -__expf(acc[i] + b);
}

// ---------------------------------------------------------------- kernel D1
// R8/R12 structure; phase-5 wkv stores are f16.
__global__ __launch_bounds__(512) void kD1(
    const float* __restrict__ rG, const float* __restrict__ kG,
    const float* __restrict__ vG, const float* __restrict__ wfin,
    const float* __restrict__ bonus, u16* __restrict__ wkvG,
    float* __restrict__ decayG, float* __restrict__ qeG, float* __restrict__ oG) {
  __shared__ float smem[4224 + 4224 + 8192 + 1056 + 64];
  float* kwT   = smem;            // [128][33]
  float* qeT   = kwT + 4224;      // [128][33]
  float* vl    = qeT + 4224;      // [32][256]
  float* wcl   = vl;              // [32][128] alias (dead before vl written)
  float* Al    = vl + 8192;       // [32][33]
  float* diag2 = Al + 1056;       // [32][2]
  const int tid = threadIdx.x;
  const int bid = blockIdx.x;
  const int nc = bid & 63, h = (bid >> 6) & 3, b = bid >> 8;
  const int tb = b * Lc + nc * 32;

  float4 wf[2];
  #pragma unroll
  for (int it = 0; it < 2; ++it) {
    int idx = it * 512 + tid;
    int c = idx >> 5, d4 = (idx & 31) * 4;
    wf[it] = ld4(wfin + (size_t)(tb + c) * 512 + h * 128 + d4);
  }
  float4 vreg[4];
  #pragma unroll
  for (int it = 0; it < 4; ++it) {
    int idx = it * 512 + tid;
    int c = idx >> 6, p4 = (idx & 63) * 4;
    vreg[it] = ld4(vG + (size_t)(tb + c) * 1024 + h * 256 + p4);
  }
  float rreg[8], kreg[8];
  #pragma unroll
  for (int it = 0; it < 8; ++it) {
    int idx = it * 512 + tid;
    int c = idx >> 7, d = idx & 127;
    rreg[it] = rG[(size_t)(tb + c) * 512 + h * 128 + d];
    kreg[it] = kG[(size_t)(tb + c) * 512 + h * 128 + d];
  }
  const float ureg = bonus[h * 128 + (tid & 127)];

  #pragma unroll
  for (int it = 0; it < 2; ++it) {
    int idx = it * 512 + tid;
    int c = idx >> 5, d4 = (idx & 31) * 4;
    st4(wcl + c * 128 + d4, wf[it]);
  }
  __syncthreads();  // B1
  if (tid < 128) {
    const int d = tid;
    float wv_[32];
    #pragma unroll
    for (int c = 0; c < 32; ++c) wv_[c] = wcl[c * 128 + d];
    float run = 0.f;
    #pragma unroll
    for (int c = 0; c < 32; ++c) { run += wv_[c]; wcl[c * 128 + d] = run; }
  }
  __syncthreads();  // B2
  #pragma unroll
  for (int it = 0; it < 8; ++it) {
    int idx = it * 512 + tid;
    int c = idx >> 7, d = idx & 127;
    int t = tb + c;
    float q = rreg[it];
    float k = kreg[it];
    float wcc = wcl[c * 128 + d];
    float wcp = (c > 0) ? wcl[(c - 1) * 128 + d] : 0.f;
    float wlast = wcl[31 * 128 + d];
    float qe = q * __expf(wcp);
    qeT[d * 33 + c] = q * __expf(wcp - wlast);
    kwT[d * 33 + c] = k * __expf(wlast - wcc);
    qeG[(size_t)t * 512 + h * 128 + d] = qe;
    if (c == 31) decayG[(size_t)bid * 128 + d] = __expf(wlast);
    float dv = q * k * ureg;
    #pragma unroll
    for (int m = 1; m < 64; m <<= 1) dv += __shfl_xor(dv, m, 64);
    if ((tid & 63) == 0) diag2[c * 2 + ((tid >> 6) & 1)] = dv;
  }
  __syncthreads();  // B3
  #pragma unroll
  for (int it = 0; it < 4; ++it) {
    int idx = it * 512 + tid;
    int c = idx >> 6, p4 = (idx & 63) * 4;
    st4(vl + c * 256 + p4, vreg[it]);
  }
  {
    const int j = tid & 31, i2 = tid >> 5;
    float a0 = 0.f, a1 = 0.f;
    for (int d = 0; d < 128; ++d) {
      float kv = kwT[d * 33 + j];
      a0 += qeT[d * 33 + i2] * kv;
      a1 += qeT[d * 33 + i2 + 16] * kv;
    }
    float dg0 = diag2[i2 * 2] + diag2[i2 * 2 + 1];
    float dg1 = diag2[(i2 + 16) * 2] + diag2[(i2 + 16) * 2 + 1];
    Al[i2 * 33 + j] = (j < i2) ? a0 : ((j == i2) ? dg0 : 0.f);
    Al[(i2 + 16) * 33 + j] = (j < i2 + 16) ? a1 : ((j == i2 + 16) ? dg1 : 0.f);
  }
  __syncthreads();  // B4
  const int pid = tid & 63, wvx = tid >> 6;
  const int p4 = pid * 4;
  {  // wkv[d][p] = sum_c kv[c][d]*v[c][p] -> f16 store
    u16* wkvB = wkvG + (size_t)bid * (128 * 256);
    #pragma unroll
    for (int pp = 0; pp < 2; ++pp) {
      const int d0 = pp * 64 + wvx * 8;
      float4 acc[8];
      #pragma unroll
      for (int q = 0; q < 8; ++q) acc[q] = make_float4(0, 0, 0, 0);
      for (int c = 0; c < 32; ++c) {
        float4 v4 = ld4(vl + c * 256 + p4);
        #pragma unroll
        for (int q = 0; q < 8; ++q) {
          float s = kwT[(d0 + q) * 33 + c];
          acc[q].x += v4.x * s; acc[q].y += v4.y * s;
          acc[q].z += v4.z * s; acc[q].w += v4.w * s;
        }
      }
      #pragma unroll
      for (int q = 0; q < 8; ++q) {
        ushort4 ob;
        ob.x = f2h(acc[q].x); ob.y = f2h(acc[q].y);
        ob.z = f2h(acc[q].z); ob.w = f2h(acc[q].w);
        *reinterpret_cast<ushort4*>(wkvB + (size_t)(d0 + q) * 256 + p4) = ob;
      }
    }
  }
  {  // o_intra = A @ v
    float4 acc[4];
    #pragma unroll
    for (int q = 0; q < 4; ++q) acc[q] = make_float4(0, 0, 0, 0);
    for (int c = 0; c < 32; ++c) {
      float4 v4 = ld4(vl + c * 256 + p4);
      #pragma unroll
      for (int q = 0; q < 4; ++q) {
        float a = Al[(wvx * 4 + q) * 33 + c];
        acc[q].x += v4.x * a; acc[q].y += v4.y * a;
        acc[q].z += v4.z * a; acc[q].w += v4.w * a;
      }
    }
    #pragma unroll
    for (int q = 0; q < 4; ++q)
      st4(oG + (size_t)(tb + wvx * 4 + q) * 1024 + h * 256 + p4, acc[q]);
  }
}

// ---------------------------------------------------------------- kernel D2
// f16 state scan: 1 wave per (bh,d)-row, lane covers 4 p (ushort4); f32 regs.
__global__ __launch_bounds__(256) void kD2(u16* __restrict__ wkvG,
                                           const float* __restrict__ decayG) {
  const int wvid = (blockIdx.x * 256 + threadIdx.x) >> 6;  // 0..1023
  const int lane = threadIdx.x & 63;
  const int p4 = lane * 4;
  const int d = wvid & 127;
  const int bh = wvid >> 7;
  u16* base = wkvG + ((size_t)bh * 64 * 128 + d) * 256 + p4;
  const float* dbase = decayG + (size_t)bh * 64 * 128 + d;
  ushort4 kvb[4];
  float decb[4];
  #pragma unroll
  for (int i = 0; i < 4; ++i) {
    kvb[i] = *reinterpret_cast<const ushort4*>(base + (size_t)i * 32768);
    decb[i] = dbase[(size_t)i * 128];
  }
  float4 S = make_float4(0.f, 0.f, 0.f, 0.f);
  #pragma unroll
  for (int nc = 0; nc < 64; ++nc) {
    const int sl = nc & 3;
    ushort4 kv = kvb[sl];
    float dec = decb[sl];
    if (nc + 4 < 64) {
      kvb[sl] = *reinterpret_cast<const ushort4*>(base + (size_t)(nc + 4) * 32768);
      decb[sl] = dbase[(size_t)(nc + 4) * 128];
    }
    ushort4 ob;
    ob.x = f2h(S.x); ob.y = f2h(S.y); ob.z = f2h(S.z); ob.w = f2h(S.w);
    *reinterpret_cast<ushort4*>(base + (size_t)nc * 32768) = ob;
    S.x = S.x * dec + h2f(kv.x);
    S.y = S.y * dec + h2f(kv.y);
    S.z = S.z * dec + h2f(kv.z);
    S.w = S.w * dec + h2f(kv.w);
  }
}

// ---------------------------------------------------------------- kernel D3
// o += qe @ S_before per chunk (S f16)
__global__ __launch_bounds__(256) void kD3(
    const float* __restrict__ qeG, const u16* __restrict__ wkvG,
    float* __restrict__ oG) {
  __shared__ float qel[32 * 129];
  const int tid = threadIdx.x;
  const int bid = blockIdx.x;
  const int nc = bid & 63, h = (bid >> 6) & 3, b = bid >> 8;
  const int tb = b * Lc + nc * 32;
  for (int it = 0; it < 16; ++it) {
    int idx = it * 256 + tid;
    int c = idx >> 7, d = idx & 127;
    qel[c * 129 + d] = qeG[(size_t)(tb + c) * 512 + h * 128 + d];
  }
  __syncthreads();
  const int pid = tid & 63, wvx = tid >> 6;
  const int p4 = pid * 4;
  const u16* Sb = wkvG + (size_t)bid * (128 * 256);
  float4 acc[8];
  #pragma unroll
  for (int q = 0; q < 8; ++q) acc[q] = make_float4(0, 0, 0, 0);
  for (int d = 0; d < 128; ++d) {
    ushort4 s4 = *reinterpret_cast<const ushort4*>(Sb + (size_t)d * 256 + p4);
    float sx = h2f(s4.x), sy = h2f(s4.y), sz = h2f(s4.z), sw = h2f(s4.w);
    #pragma unroll
    for (int q = 0; q < 8; ++q) {
      float qv = qel[(wvx * 8 + q) * 129 + d];
      acc[q].x += sx * qv; acc[q].y += sy * qv;
      acc[q].z += sz * qv; acc[q].w += sw * qv;
    }
  }
  #pragma unroll
  for (int q = 0; q < 8; ++q) {
    float* op = oG + (size_t)(tb + wvx * 8 + q) * 1024 + h * 256 + p4;
    float4 cur = ld4(op);
    cur.x += acc[q].x; cur.y += acc[q].y; cur.z += acc[q].z; cur.w += acc[q].w;
    st4(op, cur);
  }
}

// ---------------------------------------------------------------- kernel E
__global__ __launch_bounds__(256) void kE(
    const float* __restrict__ oG, const u16* __restrict__ gG,
    const float* __restrict__ gn_w, const float* __restrict__ gn_b,
    u16* __restrict__ gate) {
  const int t = blockIdx.x;
  const int h = threadIdx.x >> 6, lane = threadIdx.x & 63;
  const int p4 = lane * 4;
  const int vd = h * 256 + p4;
  float4 v = ld4(oG + (size_t)t * 1024 + vd);
  float s = v.x + v.y + v.z + v.w;
  float ss = v.x * v.x + v.y * v.y + v.z * v.z + v.w * v.w;
  for (int m = 1; m < 64; m <<= 1) {
    s += __shfl_xor(s, m, 64);
    ss += __shfl_xor(ss, m, 64);
  }
  const float mean = s * (1.f / 256.f);
  const float var = ss * (1.f / 256.f) - mean * mean;
  const float rs = rsqrtf(var + 1e-5f);
  float4 gw = ld4(gn_w + vd), gb = ld4(gn_b + vd);
  float4 on;
  on.x = (v.x - mean) * rs * gw.x + gb.x;
  on.y = (v.y - mean) * rs * gw.y + gb.y;
  on.z = (v.z - mean) * rs * gw.z + gb.z;
  on.w = (v.w - mean) * rs * gw.w + gb.w;
  ushort4 g4 = *reinterpret_cast<const ushort4*>(gG + (size_t)t * 1024 + vd);
  float gx = h2f(g4.x), gy = h2f(g4.y), gz = h2f(g4.z), gw_ = h2f(g4.w);
  float4 sw;
  sw.x = gx / (1.f + __expf(-gx));
  sw.y = gy / (1.f + __expf(-gy));
  sw.z = gz / (1.f + __expf(-gz));
  sw.w = gw_ / (1.f + __expf(-gw_));
  ushort4 ob;
  ob.x = f2h(on.x * sw.x); ob.y = f2h(on.y * sw.y);
  ob.z = f2h(on.z * sw.z); ob.w = f2h(on.w * sw.w);
  *reinterpret_cast<ushort4*>(gate + (size_t)t * 1024 + vd) = ob;
}

// ---------------------------------------------------------------- kernel F (f16)
__global__ __launch_bounds__(256) void kF(
    const u16* __restrict__ gate, const u16* __restrict__ owb,
    float* __restrict__ out) {
  __shared__ __align__(16) u16 Abuf[128 * 64];
  __shared__ __align__(16) u16 Bbuf[128 * 64];
  const int mt = blockIdx.x, nt = blockIdx.y;
  const u16* A = gate + (size_t)mt * 128 * 1024;
  const u16* W = owb + (size_t)nt * 128 * 1024;
  float* C = out + (size_t)mt * 128 * 1024 + nt * 128;
  const int tid = threadIdx.x;
  const int lane = tid & 63;
  const int wv = tid >> 6;
  const int wr = wv >> 1, wc = wv & 1;
  const int srow = wv * 32;
  f32x4 acc[4][4];
  #pragma unroll
  for (int i = 0; i < 4; ++i)
    #pragma unroll
    for (int j = 0; j < 4; ++j) acc[i][j] = {0.f, 0.f, 0.f, 0.f};
  for (int k0 = 0; k0 < 1024; k0 += 64) {
    #pragma unroll
    for (int c = 0; c < 4; ++c) {
      const int s8 = srow + c * 8;
      stage_swz(A, Abuf, s8, k0, lane);
      stage_swz(W, Bbuf, s8, k0, lane);
    }
    __syncthreads();
    #pragma unroll
    for (int kk = 0; kk < 2; ++kk) {
      const int sl = kk * 4 + (lane >> 4);
      f16x8 af[4], bf[4];
      #pragma unroll
      for (int m = 0; m < 4; ++m)
        af[m] = read_swz(Abuf, wr * 64 + m * 16 + (lane & 15), sl);
      #pragma unroll
      for (int j = 0; j < 4; ++j)
        bf[j] = read_swz(Bbuf, wc * 64 + j * 16 + (lane & 15), sl);
      #pragma unroll
      for (int m = 0; m < 4; ++m)
        #pragma unroll
        for (int j = 0; j < 4; ++j)
          acc[m][j] = __builtin_amdgcn_mfma_f32_16x16x32_f16(af[m], bf[j], acc[m][j], 0, 0, 0);
    }
    __syncthreads();
  }
  #pragma unroll
  for (int m = 0; m < 4; ++m)
    #pragma unroll
    for (int r = 0; r < 4; ++r) {
      const int row = wr * 64 + m * 16 + (lane >> 4) * 4 + r;
      #pragma unroll
      for (int j = 0; j < 4; ++j) {
        const int col = wc * 64 + j * 16 + (lane & 15);
        C[(size_t)row * 1024 + col] = acc[m][j][r];
      }
    }
}

}  // namespace

extern "C" void kernel_launch(void* const* d_in, const int* in_sizes, int n_in,
                              void* d_out, int out_size, void* d_ws, size_t ws_size,
                              hipStream_t stream) {
  (void)in_sizes; (void)n_in; (void)out_size;
  if (ws_size < WS_NEED) return;

  const float* x      = (const float*)d_in[0];
  const float* x0_mu  = (const float*)d_in[1];
  const float* x0_w   = (const float*)d_in[2];
  const float* x2_w   = (const float*)d_in[3];
  const float* x_bias = (const float*)d_in[4];
  const float* r_w    = (const float*)d_in[5];
  const float* w_w1   = (const float*)d_in[6];
  const float* w_w2   = (const float*)d_in[7];
  const float* w_b2   = (const float*)d_in[8];
  const float* k_w    = (const float*)d_in[9];
  const float* v_w    = (const float*)d_in[10];
  const float* g_w    = (const float*)d_in[11];
  const float* bonus  = (const float*)d_in[12];
  const float* gn_w   = (const float*)d_in[13];
  const float* gn_b   = (const float*)d_in[14];
  const float* o_w    = (const float*)d_in[15];
  float* out = (float*)d_out;
  char* ws = (char*)d_ws;

  u16*   wkvG   = (u16*)(ws + OFF_WKV);
  float* xm0    = (float*)(ws + OFF_XM0);
  float* delta  = (float*)(ws + OFF_DELTA);
  float* t160   = (float*)(ws + OFF_T160);
  float* xmw    = (float*)(ws + OFF_XMW);
  float* yw     = (float*)(ws + OFF_YW);
  u16*   x0wf   = (u16*)(ws + OFF_X0WF);
  u16*   xm0f   = (u16*)(ws + OFF_XM0F);
  u16*   xmf    = (u16*)(ws + OFF_XMF);
  float* wfin   = (float*)(ws + OFF_WFIN);
  u16*   gate   = (u16*)(ws + OFF_GATE);
  float* qeG    = (float*)(ws + OFF_QE);
  float* oG     = (float*)(ws + OFF_OO);
  u16*   Wf     = (u16*)(ws + OFF_WF);
  float* decayG = (float*)(ws + OFF_DECAY);
  u16*   owb    = (u16*)(ws + OFF_OWB);
  float* rG     = (float*)(ws + OFF_RG);
  float* kG     = (float*)(ws + OFF_KG);
  float* vG     = (float*)(ws + OFF_VG);
  u16*   gG     = (u16*)(ws + OFF_GG);

  kWA  <<<dim3(8352),        dim3(256), 0, stream>>>(r_w, k_w, v_w, g_w, o_w, x0_w,
                                                     x, x0_mu, Wf, owb, x0wf,
                                                     xm0, delta, xm0f);
  kA2f <<<dim3(32, 2),       dim3(256), 0, stream>>>(xm0f, x0wf, t160);
  kA2m5<<<dim3(64, 16, 5),   dim3(256), 0, stream>>>(t160, x2_w, x_bias, xm0, delta,
                                                     x0_mu, xmf, xmw);
  kWL  <<<dim3(128),         dim3(256), 0, stream>>>(xmw, w_w1, yw);
  kB   <<<dim3(32, 24),      dim3(256), 0, stream>>>(xmf, Wf, rG, kG, vG, gG);
  kC   <<<dim3(128, 2),      dim3(256), 0, stream>>>(yw, w_w2, w_b2, wfin);
  kD1  <<<dim3(512),         dim3(512), 0, stream>>>(rG, kG, vG, wfin, bonus,
                                                     wkvG, decayG, qeG, oG);
  kD2  <<<dim3(256),         dim3(256), 0, stream>>>(wkvG, decayG);
  kD3  <<<dim3(512),         dim3(256), 0, stream>>>(qeG, wkvG, oG);
  kE   <<<dim3(4096),        dim3(256), 0, stream>>>(oG, gG, gn_w, gn_b, gate);
  kF   <<<dim3(32, 8),       dim3(256), 0, stream>>>(gate, owb, out);
}